// Round 2
// baseline (1994.571 us; speedup 1.0000x reference)
//
#include <hip/hip_runtime.h>

#define LDT 68  // 64 + 4 pad; keeps 16B alignment for float4, breaks pow2 bank strides

// ---------------------------------------------------------------------------
// C[m][n] = bias[n] + sum_k A[m][k] * Bw[n][k]   (A: MxK row-major, Bw: NxK row-major)
// tile 128x128, block 256 threads, 8x8 per thread, K-step 8
// ---------------------------------------------------------------------------
__global__ __launch_bounds__(256) void gemm_nt(const float* __restrict__ A,
                                               const float* __restrict__ Bw,
                                               const float* __restrict__ bias,
                                               float* __restrict__ C,
                                               int M, int N, int K) {
  __shared__ float As[8][132];
  __shared__ float Bs[8][132];
  const int tid = threadIdx.x;
  const int bm = blockIdx.x * 128;
  const int bn = blockIdx.y * 128;
  const int tmi = tid & 15;   // row group
  const int tni = tid >> 4;   // col group
  const int ar = tid >> 1;          // 0..127
  const int ak = (tid & 1) * 4;     // 0 or 4
  const float* Ap = A + (size_t)(bm + ar) * K + ak;
  const float* Bp = Bw + (size_t)(bn + ar) * K + ak;

  float acc[8][8];
#pragma unroll
  for (int i = 0; i < 8; ++i)
#pragma unroll
    for (int j = 0; j < 8; ++j) acc[i][j] = 0.f;

  for (int k0 = 0; k0 < K; k0 += 8) {
    float4 av = *(const float4*)(Ap + k0);
    float4 bv = *(const float4*)(Bp + k0);
    __syncthreads();
    As[ak + 0][ar] = av.x; As[ak + 1][ar] = av.y; As[ak + 2][ar] = av.z; As[ak + 3][ar] = av.w;
    Bs[ak + 0][ar] = bv.x; Bs[ak + 1][ar] = bv.y; Bs[ak + 2][ar] = bv.z; Bs[ak + 3][ar] = bv.w;
    __syncthreads();
#pragma unroll
    for (int kk = 0; kk < 8; ++kk) {
      float a[8], b[8];
      *(float4*)&a[0] = *(const float4*)&As[kk][8 * tmi];
      *(float4*)&a[4] = *(const float4*)&As[kk][8 * tmi + 4];
      *(float4*)&b[0] = *(const float4*)&Bs[kk][8 * tni];
      *(float4*)&b[4] = *(const float4*)&Bs[kk][8 * tni + 4];
#pragma unroll
      for (int i = 0; i < 8; ++i)
#pragma unroll
        for (int j = 0; j < 8; ++j) acc[i][j] += a[i] * b[j];
    }
  }
#pragma unroll
  for (int i = 0; i < 8; ++i) {
    const int row = bm + 8 * tmi + i;
    float* Crow = C + (size_t)row * N + bn + 8 * tni;
#pragma unroll
    for (int j = 0; j < 8; ++j) Crow[j] = acc[i][j] + bias[bn + 8 * tni + j];
  }
}

// ---------------------------------------------------------------------------
// beta[m][h] = sigmoid( sum_k x[m][k]*Wb[h][k] + bb[h] ),  m = b*L + l, 16 heads
// one block per row; 16 threads per head, shuffle reduce
// ---------------------------------------------------------------------------
__global__ __launch_bounds__(256) void beta_kernel(const float* __restrict__ x,
                                                   const float* __restrict__ Wb,
                                                   const float* __restrict__ bb,
                                                   float* __restrict__ beta) {
  const int m = blockIdx.x;
  const int tid = threadIdx.x;
  const int h = tid >> 4;
  const int l = tid & 15;
  const float4* x4 = (const float4*)(x + (size_t)m * 1024);
  const float4* w4 = (const float4*)(Wb + (size_t)h * 1024);
  float acc = 0.f;
#pragma unroll 4
  for (int jj = 0; jj < 16; ++jj) {
    float4 xv = x4[l + 16 * jj];
    float4 wv = w4[l + 16 * jj];
    acc += xv.x * wv.x + xv.y * wv.y + xv.z * wv.z + xv.w * wv.w;
  }
  acc += __shfl_xor(acc, 1);
  acc += __shfl_xor(acc, 2);
  acc += __shfl_xor(acc, 4);
  acc += __shfl_xor(acc, 8);
  if (l == 0) {
    const float s = acc + bb[h];
    beta[(size_t)m * 16 + h] = 1.f / (1.f + expf(-s));
  }
}

// ---------------------------------------------------------------------------
// Delta-rule scan: one block per (b,h). 256 threads.
// Applies conv/silu/norm/eta on the fly while staging chunk tiles into LDS.
// ---------------------------------------------------------------------------
__global__ __launch_bounds__(256) void scan_kernel(
    const float* __restrict__ kpre, const float* __restrict__ qpre,
    const float* __restrict__ vpre, const float* __restrict__ beta,
    const float* __restrict__ convk, const float* __restrict__ convq,
    const float* __restrict__ convv, float* __restrict__ O) {
  __shared__ float Ws[64 * LDT], Was[64 * LDT], Ks[64 * LDT], Kt[64 * LDT],
      Qs[64 * LDT], Vs[64 * LDT], Ts[64 * LDT];
  __shared__ float wkT[4][64], wqT[4][64], wvT[4][64];
  __shared__ float etas[64];

  const int tid = threadIdx.x;
  const int bh = blockIdx.x;
  const int b = bh >> 4, h = bh & 15;

  if (tid < 64) {
    float4 wk = *(const float4*)(convk + (size_t)(h * 64 + tid) * 4);
    wkT[0][tid] = wk.x; wkT[1][tid] = wk.y; wkT[2][tid] = wk.z; wkT[3][tid] = wk.w;
    float4 wq = *(const float4*)(convq + (size_t)(h * 64 + tid) * 4);
    wqT[0][tid] = wq.x; wqT[1][tid] = wq.y; wqT[2][tid] = wq.z; wqT[3][tid] = wq.w;
    float4 wv = *(const float4*)(convv + (size_t)(h * 64 + tid) * 4);
    wvT[0][tid] = wv.x; wvT[1][tid] = wv.y; wvT[2][tid] = wv.z; wvT[3][tid] = wv.w;
  }
  for (int i = tid; i < 64 * LDT; i += 256) { Ws[i] = 0.f; Was[i] = 0.f; }
  __syncthreads();

  const size_t preoff = ((size_t)b * 2048) * 1024 + (size_t)h * 64;
  const float* kp = kpre + preoff;
  const float* qp = qpre + preoff;
  const float* vp = vpre + preoff;
  const float* betap = beta + (size_t)b * 2048 * 16 + h;
  float* Op = O + (size_t)bh * 2048 * 64;

  const int tr = tid >> 4, tc = tid & 15;  // matmul mapping: rows 4tr+i, cols 4tc+j
  const int sc = tid >> 2, sp = tid & 3;   // substitution: column sc, quarter sp

#pragma unroll 1
  for (int ic = 0; ic < 32; ++ic) {
    const float ts = (float)(ic * 64);

    // ---- phase 1: global load + causal conv (+ silu*eta for V) ----
#pragma unroll
    for (int s = 0; s < 4; ++s) {
      const int f = tid + 256 * s;
      const int r = f >> 4;
      const int c4 = (f & 15) * 4;
      const int l = ic * 64 + r;
      float4 aK = {0, 0, 0, 0}, aQ = {0, 0, 0, 0}, aV = {0, 0, 0, 0};
#pragma unroll
      for (int j = 0; j < 4; ++j) {
        const int lj = l - 3 + j;
        if (lj >= 0) {
          float4 xk = *(const float4*)(kp + (size_t)lj * 1024 + c4);
          float4 wj = *(const float4*)&wkT[j][c4];
          aK.x += xk.x * wj.x; aK.y += xk.y * wj.y; aK.z += xk.z * wj.z; aK.w += xk.w * wj.w;
          float4 xq = *(const float4*)(qp + (size_t)lj * 1024 + c4);
          float4 wjq = *(const float4*)&wqT[j][c4];
          aQ.x += xq.x * wjq.x; aQ.y += xq.y * wjq.y; aQ.z += xq.z * wjq.z; aQ.w += xq.w * wjq.w;
          float4 xv = *(const float4*)(vp + (size_t)lj * 1024 + c4);
          float4 wjv = *(const float4*)&wvT[j][c4];
          aV.x += xv.x * wjv.x; aV.y += xv.y * wjv.y; aV.z += xv.z * wjv.z; aV.w += xv.w * wjv.w;
        }
      }
      const float eta = betap[(size_t)l * 16];
      aV.x = eta * (aV.x / (1.f + expf(-aV.x)));
      aV.y = eta * (aV.y / (1.f + expf(-aV.y)));
      aV.z = eta * (aV.z / (1.f + expf(-aV.z)));
      aV.w = eta * (aV.w / (1.f + expf(-aV.w)));
      *(float4*)&Ks[r * LDT + c4] = aK;
      *(float4*)&Qs[r * LDT + c4] = aQ;
      *(float4*)&Vs[r * LDT + c4] = aV;
    }
    __syncthreads();

    // ---- phase 2: per-row L2 norm of K and Q, build Kt, stash eta ----
    {
      const int r = tid >> 2;
      const int q0 = (tid & 3) * 16;
      float kv[16], qv[16];
#pragma unroll
      for (int m = 0; m < 4; ++m) {
        *(float4*)&kv[4 * m] = *(const float4*)&Ks[r * LDT + q0 + 4 * m];
        *(float4*)&qv[4 * m] = *(const float4*)&Qs[r * LDT + q0 + 4 * m];
      }
      float ssk = 0.f, ssq = 0.f;
#pragma unroll
      for (int m = 0; m < 16; ++m) { ssk += kv[m] * kv[m]; ssq += qv[m] * qv[m]; }
      ssk += __shfl_xor(ssk, 1); ssk += __shfl_xor(ssk, 2);
      ssq += __shfl_xor(ssq, 1); ssq += __shfl_xor(ssq, 2);
      const float sk = 1.f / (sqrtf(ssk) + 1e-6f);
      const float sq = 1.f / (sqrtf(ssq) + 1e-6f);
      if ((tid & 3) == 0) etas[r] = betap[(size_t)(ic * 64 + r) * 16];
#pragma unroll
      for (int m = 0; m < 16; ++m) { kv[m] *= sk; qv[m] *= sq; }
#pragma unroll
      for (int m = 0; m < 4; ++m) {
        *(float4*)&Ks[r * LDT + q0 + 4 * m] = *(float4*)&kv[4 * m];
        *(float4*)&Qs[r * LDT + q0 + 4 * m] = *(float4*)&qv[4 * m];
      }
#pragma unroll
      for (int m = 0; m < 16; ++m) Kt[(q0 + m) * LDT + r] = kv[m];
    }
    __syncthreads();

    // ---- phase 3: T = tril(diag(eta) K K^T, -1) ; RHS = V - diag(eta) K W ----
    {
      float aT[4][4] = {}, aR[4][4] = {};
#pragma unroll 4
      for (int e = 0; e < 64; ++e) {
        float kr[4], kt4[4], w4[4];
#pragma unroll
        for (int i = 0; i < 4; ++i) kr[i] = Ks[(4 * tr + i) * LDT + e];
        *(float4*)kt4 = *(const float4*)&Kt[e * LDT + 4 * tc];
        *(float4*)w4 = *(const float4*)&Ws[e * LDT + 4 * tc];
#pragma unroll
        for (int i = 0; i < 4; ++i)
#pragma unroll
          for (int j = 0; j < 4; ++j) {
            aT[i][j] += kr[i] * kt4[j];
            aR[i][j] += kr[i] * w4[j];
          }
      }
#pragma unroll
      for (int i = 0; i < 4; ++i) {
        const int row = 4 * tr + i;
        const float et = etas[row];
#pragma unroll
        for (int j = 0; j < 4; ++j) {
          const int col = 4 * tc + j;
          Ts[row * LDT + col] = (col < row) ? et * aT[i][j] : 0.f;
        }
        float4 v = *(const float4*)&Vs[row * LDT + 4 * tc];
        v.x -= et * aR[i][0]; v.y -= et * aR[i][1]; v.z -= et * aR[i][2]; v.w -= et * aR[i][3];
        *(float4*)&Vs[row * LDT + 4 * tc] = v;
      }
    }
    __syncthreads();

    // ---- phase 4: forward substitution (I+T) U = RHS, U in place of Vs ----
    {
      float ureg[16];
#pragma unroll
      for (int m = 0; m < 16; ++m) ureg[m] = 0.f;
#pragma unroll
      for (int r = 0; r < 64; ++r) {
        float acc = 0.f;
#pragma unroll
        for (int m = 0; m < 4; ++m) {
          float4 t4 = *(const float4*)&Ts[r * LDT + 16 * sp + 4 * m];
          acc += t4.x * ureg[4 * m + 0] + t4.y * ureg[4 * m + 1] +
                 t4.z * ureg[4 * m + 2] + t4.w * ureg[4 * m + 3];
        }
        acc += __shfl_xor(acc, 1);
        acc += __shfl_xor(acc, 2);
        const float u = Vs[r * LDT + sc] - acc;
        if ((r >> 4) == sp) ureg[r & 15] = u;
        if (sp == 0) Vs[r * LDT + sc] = u;
      }
    }
    __syncthreads();

    // ---- phase 5: fused Q@Wavg, Q@W, Q@K^T (old W, old Wavg); S into Ts ----
    float aA[4][4] = {}, aC[4][4] = {};
    {
      float aS[4][4] = {};
#pragma unroll 4
      for (int e = 0; e < 64; ++e) {
        float qr[4], wa4[4], w4[4], kt4[4];
#pragma unroll
        for (int i = 0; i < 4; ++i) qr[i] = Qs[(4 * tr + i) * LDT + e];
        *(float4*)wa4 = *(const float4*)&Was[e * LDT + 4 * tc];
        *(float4*)w4 = *(const float4*)&Ws[e * LDT + 4 * tc];
        *(float4*)kt4 = *(const float4*)&Kt[e * LDT + 4 * tc];
#pragma unroll
        for (int i = 0; i < 4; ++i)
#pragma unroll
          for (int j = 0; j < 4; ++j) {
            aA[i][j] += qr[i] * wa4[j];
            aC[i][j] += qr[i] * w4[j];
            aS[i][j] += qr[i] * kt4[j];
          }
      }
      const float tri0 = 0.5f * ts * (ts + 1.f);
#pragma unroll
      for (int i = 0; i < 4; ++i) {
        const int row = 4 * tr + i;
        const float csr = (row + 1) * ts + 0.5f * (row + 1) * (row + 2);
        const float rinv = 1.f / (tri0 + csr);
#pragma unroll
        for (int j = 0; j < 4; ++j) {
          const int col = 4 * tc + j;
          const float jidx = col * ts + 0.5f * col * (col + 1);
          Ts[row * LDT + col] = (csr >= jidx) ? (csr - jidx) * rinv * aS[i][j] : 0.f;
        }
      }
    }
    __syncthreads();

    // ---- phase 6: O = a*QWavg + c*QW + S@U ; dW = K^T U ; dWavg; update W,Wavg ----
    {
      float aO[4][4];
      const float tri0 = 0.5f * ts * (ts + 1.f);
#pragma unroll
      for (int i = 0; i < 4; ++i) {
        const int row = 4 * tr + i;
        const float csr = (row + 1) * ts + 0.5f * (row + 1) * (row + 2);
        const float av = tri0 / (tri0 + csr);
        const float cv = 1.f - av;
#pragma unroll
        for (int j = 0; j < 4; ++j) aO[i][j] = aA[i][j] * av + aC[i][j] * cv;
      }
#pragma unroll 4
      for (int e = 0; e < 64; ++e) {
        float sr[4], u4[4];
#pragma unroll
        for (int i = 0; i < 4; ++i) sr[i] = Ts[(4 * tr + i) * LDT + e];
        *(float4*)u4 = *(const float4*)&Vs[e * LDT + 4 * tc];
#pragma unroll
        for (int i = 0; i < 4; ++i)
#pragma unroll
          for (int j = 0; j < 4; ++j) aO[i][j] += sr[i] * u4[j];
      }
#pragma unroll
      for (int i = 0; i < 4; ++i) {
        float4 o4 = {aO[i][0], aO[i][1], aO[i][2], aO[i][3]};
        *(float4*)(Op + (size_t)(ic * 64 + 4 * tr + i) * 64 + 4 * tc) = o4;
      }
      // dW = K^T U ; dWavg = K^T (U * w_row)
      float aW[4][4] = {}, aV2[4][4] = {};
      const float invden = 1.f / (0.5f * (ts + 65.f) * (ts + 64.f));
#pragma unroll 4
      for (int r = 0; r < 64; ++r) {
        float kk[4], uu[4];
        *(float4*)kk = *(const float4*)&Ks[r * LDT + 4 * tr];
        *(float4*)uu = *(const float4*)&Vs[r * LDT + 4 * tc];
        const float wr =
            (ts * (float)(64 - r) +
             ((float)(r + 1) + 2080.f - 0.5f * (float)(r + 1) * (float)(r + 2))) * invden;
        float uw[4] = {uu[0] * wr, uu[1] * wr, uu[2] * wr, uu[3] * wr};
#pragma unroll
        for (int i = 0; i < 4; ++i)
#pragma unroll
          for (int j = 0; j < 4; ++j) {
            aW[i][j] += kk[i] * uu[j];
            aV2[i][j] += kk[i] * uw[j];
          }
      }
      const float den = (ts + 64.f) * (ts + 65.f);
      const float c1 = ts * (ts + 1.f) / den;
      const float c2 = 64.f * (2.f * ts + 65.f) / den;
#pragma unroll
      for (int i = 0; i < 4; ++i) {
        float4 wold = *(const float4*)&Ws[(4 * tr + i) * LDT + 4 * tc];
        float4 wav = *(const float4*)&Was[(4 * tr + i) * LDT + 4 * tc];
        float4 nav = {c1 * wav.x + c2 * wold.x + aV2[i][0],
                      c1 * wav.y + c2 * wold.y + aV2[i][1],
                      c1 * wav.z + c2 * wold.z + aV2[i][2],
                      c1 * wav.w + c2 * wold.w + aV2[i][3]};
        float4 nw = {wold.x + aW[i][0], wold.y + aW[i][1],
                     wold.z + aW[i][2], wold.w + aW[i][3]};
        *(float4*)&Was[(4 * tr + i) * LDT + 4 * tc] = nav;
        *(float4*)&Ws[(4 * tr + i) * LDT + 4 * tc] = nw;
      }
    }
    __syncthreads();
  }
}

// ---------------------------------------------------------------------------
// RMS norm over head dim + relayout (B,H,L,D) -> (B,L,Dm)
// ---------------------------------------------------------------------------
__global__ __launch_bounds__(256) void rms_kernel(const float* __restrict__ O,
                                                  const float* __restrict__ rmsw,
                                                  float* __restrict__ out) {
  const int m = blockIdx.x;  // b*2048 + l
  const int b = m >> 11, l = m & 2047;
  const int wv = threadIdx.x >> 6, lane = threadIdx.x & 63;
  const float rw = rmsw[lane];
#pragma unroll
  for (int hh = 0; hh < 4; ++hh) {
    const int h = wv * 4 + hh;
    const float v = O[(((size_t)(b * 16 + h)) * 2048 + l) * 64 + lane];
    float ss = v * v;
    ss += __shfl_xor(ss, 1); ss += __shfl_xor(ss, 2); ss += __shfl_xor(ss, 4);
    ss += __shfl_xor(ss, 8); ss += __shfl_xor(ss, 16); ss += __shfl_xor(ss, 32);
    const float sc = rsqrtf(ss * (1.f / 64.f) + 1e-6f);
    out[(size_t)m * 1024 + h * 64 + lane] = v * sc * rw;
  }
}

// ---------------------------------------------------------------------------
extern "C" void kernel_launch(void* const* d_in, const int* in_sizes, int n_in,
                              void* d_out, int out_size, void* d_ws, size_t ws_size,
                              hipStream_t stream) {
  (void)in_sizes; (void)n_in; (void)out_size; (void)ws_size;
  const float* x     = (const float*)d_in[0];
  const float* Wk    = (const float*)d_in[1];
  const float* bk    = (const float*)d_in[2];
  const float* Wq    = (const float*)d_in[3];
  const float* bq    = (const float*)d_in[4];
  const float* Wv    = (const float*)d_in[5];
  const float* bv    = (const float*)d_in[6];
  const float* Wbeta = (const float*)d_in[7];
  const float* bbeta = (const float*)d_in[8];
  const float* convk = (const float*)d_in[9];
  const float* convq = (const float*)d_in[10];
  const float* convv = (const float*)d_in[11];
  const float* rmsw  = (const float*)d_in[12];
  const float* Wout  = (const float*)d_in[13];
  const float* bout  = (const float*)d_in[14];
  float* out = (float*)d_out;
  float* ws = (float*)d_ws;

  const size_t SZ = (size_t)8192 * 1024;
  float* kpre  = ws;
  float* qpre  = ws + SZ;
  float* vpre  = ws + 2 * SZ;
  float* Obuf  = ws + 3 * SZ;
  float* betab = ws + 4 * SZ;
  float* normed = kpre;  // k_pre dead after scan; reuse

  dim3 g(64, 8), blk(256);
  hipLaunchKernelGGL(gemm_nt, g, blk, 0, stream, x, Wk, bk, kpre, 8192, 1024, 1024);
  hipLaunchKernelGGL(gemm_nt, g, blk, 0, stream, x, Wq, bq, qpre, 8192, 1024, 1024);
  hipLaunchKernelGGL(gemm_nt, g, blk, 0, stream, x, Wv, bv, vpre, 8192, 1024, 1024);
  hipLaunchKernelGGL(beta_kernel, dim3(8192), blk, 0, stream, x, Wbeta, bbeta, betab);
  hipLaunchKernelGGL(scan_kernel, dim3(64), blk, 0, stream, kpre, qpre, vpre, betab,
                     convk, convq, convv, Obuf);
  hipLaunchKernelGGL(rms_kernel, dim3(8192), blk, 0, stream, Obuf, rmsw, normed);
  hipLaunchKernelGGL(gemm_nt, g, blk, 0, stream, normed, Wout, bout, out, 8192, 1024, 1024);
}

// Round 3
// 1827.120 us; speedup vs baseline: 1.0916x; 1.0916x over previous
//
#include <hip/hip_runtime.h>

#define LDK 68  // K/Q/Kt/Ts row stride (64 + 4 pad)
#define LDW 20  // W/Wavg/U slice row stride (16 + 4 pad)

// ---------------------------------------------------------------------------
// C[m][n] = bias[n] + sum_k A[m][k] * Bw[n][k]   (A: MxK row-major, Bw: NxK row-major)
// tile 128x128, block 256 threads, 8x8 per thread, K-step 8
// ---------------------------------------------------------------------------
__global__ __launch_bounds__(256) void gemm_nt(const float* __restrict__ A,
                                               const float* __restrict__ Bw,
                                               const float* __restrict__ bias,
                                               float* __restrict__ C,
                                               int M, int N, int K) {
  __shared__ float As[8][132];
  __shared__ float Bs[8][132];
  const int tid = threadIdx.x;
  const int bm = blockIdx.x * 128;
  const int bn = blockIdx.y * 128;
  const int tmi = tid & 15;   // row group
  const int tni = tid >> 4;   // col group
  const int ar = tid >> 1;          // 0..127
  const int ak = (tid & 1) * 4;     // 0 or 4
  const float* Ap = A + (size_t)(bm + ar) * K + ak;
  const float* Bp = Bw + (size_t)(bn + ar) * K + ak;

  float acc[8][8];
#pragma unroll
  for (int i = 0; i < 8; ++i)
#pragma unroll
    for (int j = 0; j < 8; ++j) acc[i][j] = 0.f;

  for (int k0 = 0; k0 < K; k0 += 8) {
    float4 av = *(const float4*)(Ap + k0);
    float4 bv = *(const float4*)(Bp + k0);
    __syncthreads();
    As[ak + 0][ar] = av.x; As[ak + 1][ar] = av.y; As[ak + 2][ar] = av.z; As[ak + 3][ar] = av.w;
    Bs[ak + 0][ar] = bv.x; Bs[ak + 1][ar] = bv.y; Bs[ak + 2][ar] = bv.z; Bs[ak + 3][ar] = bv.w;
    __syncthreads();
#pragma unroll
    for (int kk = 0; kk < 8; ++kk) {
      float a[8], b[8];
      *(float4*)&a[0] = *(const float4*)&As[kk][8 * tmi];
      *(float4*)&a[4] = *(const float4*)&As[kk][8 * tmi + 4];
      *(float4*)&b[0] = *(const float4*)&Bs[kk][8 * tni];
      *(float4*)&b[4] = *(const float4*)&Bs[kk][8 * tni + 4];
#pragma unroll
      for (int i = 0; i < 8; ++i)
#pragma unroll
        for (int j = 0; j < 8; ++j) acc[i][j] += a[i] * b[j];
    }
  }
#pragma unroll
  for (int i = 0; i < 8; ++i) {
    const int row = bm + 8 * tmi + i;
    float* Crow = C + (size_t)row * N + bn + 8 * tni;
#pragma unroll
    for (int j = 0; j < 8; ++j) Crow[j] = acc[i][j] + bias[bn + 8 * tni + j];
  }
}

// ---------------------------------------------------------------------------
// beta[m][h] = sigmoid( sum_k x[m][k]*Wb[h][k] + bb[h] )
// ---------------------------------------------------------------------------
__global__ __launch_bounds__(256) void beta_kernel(const float* __restrict__ x,
                                                   const float* __restrict__ Wb,
                                                   const float* __restrict__ bb,
                                                   float* __restrict__ beta) {
  const int m = blockIdx.x;
  const int tid = threadIdx.x;
  const int h = tid >> 4;
  const int l = tid & 15;
  const float4* x4 = (const float4*)(x + (size_t)m * 1024);
  const float4* w4 = (const float4*)(Wb + (size_t)h * 1024);
  float acc = 0.f;
#pragma unroll 4
  for (int jj = 0; jj < 16; ++jj) {
    float4 xv = x4[l + 16 * jj];
    float4 wv = w4[l + 16 * jj];
    acc += xv.x * wv.x + xv.y * wv.y + xv.z * wv.z + xv.w * wv.w;
  }
  acc += __shfl_xor(acc, 1);
  acc += __shfl_xor(acc, 2);
  acc += __shfl_xor(acc, 4);
  acc += __shfl_xor(acc, 8);
  if (l == 0) {
    const float s = acc + bb[h];
    beta[(size_t)m * 16 + h] = 1.f / (1.f + expf(-s));
  }
}

// ---------------------------------------------------------------------------
// prep: causal conv (K=4) on k/q/v projections + L2-norm(k,q per head) +
// eta*silu(v). One block per (b,l); wave w + iter s handles head 4s+w, lane=d.
// ---------------------------------------------------------------------------
__global__ __launch_bounds__(256) void prep_kernel(
    const float* __restrict__ kpre, const float* __restrict__ qpre,
    const float* __restrict__ vpre, const float* __restrict__ betab,
    const float* __restrict__ convk, const float* __restrict__ convq,
    const float* __restrict__ convv,
    float* __restrict__ kn, float* __restrict__ qn, float* __restrict__ vz) {
  const int m = blockIdx.x;          // b*2048 + l
  const int l = m & 2047;
  const int lane = threadIdx.x & 63;
  const int wvi = threadIdx.x >> 6;  // 0..3
#pragma unroll
  for (int s = 0; s < 4; ++s) {
    const int h = 4 * s + wvi;
    const int c = h * 64 + lane;
    const float4 wk4 = *(const float4*)(convk + (size_t)c * 4);
    const float4 wq4 = *(const float4*)(convq + (size_t)c * 4);
    const float4 wv4 = *(const float4*)(convv + (size_t)c * 4);
    const float wk[4] = {wk4.x, wk4.y, wk4.z, wk4.w};
    const float wq[4] = {wq4.x, wq4.y, wq4.z, wq4.w};
    const float wvv[4] = {wv4.x, wv4.y, wv4.z, wv4.w};
    float kc = 0.f, qc = 0.f, vc = 0.f;
#pragma unroll
    for (int j = 0; j < 4; ++j) {
      const int lj = l - 3 + j;
      if (lj >= 0) {
        const size_t base = ((size_t)(m - l + lj)) * 1024 + c;
        kc += wk[j] * kpre[base];
        qc += wq[j] * qpre[base];
        vc += wvv[j] * vpre[base];
      }
    }
    float ssk = kc * kc, ssq = qc * qc;
    ssk += __shfl_xor(ssk, 1); ssq += __shfl_xor(ssq, 1);
    ssk += __shfl_xor(ssk, 2); ssq += __shfl_xor(ssq, 2);
    ssk += __shfl_xor(ssk, 4); ssq += __shfl_xor(ssq, 4);
    ssk += __shfl_xor(ssk, 8); ssq += __shfl_xor(ssq, 8);
    ssk += __shfl_xor(ssk, 16); ssq += __shfl_xor(ssq, 16);
    ssk += __shfl_xor(ssk, 32); ssq += __shfl_xor(ssq, 32);
    const float eta = betab[(size_t)m * 16 + h];
    const size_t o = (size_t)m * 1024 + c;
    kn[o] = kc / (sqrtf(ssk) + 1e-6f);
    qn[o] = qc / (sqrtf(ssq) + 1e-6f);
    vz[o] = eta * vc / (1.f + expf(-vc));
  }
}

// ---------------------------------------------------------------------------
// Delta-rule scan v2: 256 blocks = (b,h) x 4 column-groups of 16; 512 threads.
// K/Q/T full 64x64 per block (duplicated); W/Wavg/U/O sliced by 16 cols.
// ---------------------------------------------------------------------------
__global__ __launch_bounds__(512) void scan_kernel(
    const float* __restrict__ kn, const float* __restrict__ qn,
    const float* __restrict__ vz, const float* __restrict__ betab,
    float* __restrict__ O) {
  __shared__ float Ks[64 * LDK], Qs[64 * LDK], Kt[64 * LDK], Ts[64 * LDK];
  __shared__ float Ws[64 * LDW], Was[64 * LDW], Us[64 * LDW];
  __shared__ float etas[64];

  const int tid = threadIdx.x;
  const int bh = blockIdx.x >> 2;
  const int g = blockIdx.x & 3;
  const int b = bh >> 4, h = bh & 15;
  const int c0 = g * 16;

  for (int i = tid; i < 64 * LDW; i += 512) { Ws[i] = 0.f; Was[i] = 0.f; }

  const size_t base = ((size_t)b * 2048) * 1024 + (size_t)h * 64;
  const float* kp = kn + base;
  const float* qp = qn + base;
  const float* vp = vz + base + c0;
  const float* etap = betab + (size_t)b * 2048 * 16 + h;
  float* Op = O + (size_t)bh * 2048 * 64 + c0;

  const int row = tid >> 3;        // 0..63
  const int j0 = (tid & 7) * 8;    // 0..56 (8-col strip for full 64-wide outputs)
  const int c2 = (tid & 7) * 2;    // 0..14 (2-col strip for 16-wide slices)
  const int lane = tid & 63, wvi = tid >> 6;
  const int colw = lane >> 5;      // 0/1
  const int scol = wvi * 2 + colw; // substitution column 0..15
  const int p = lane & 31;         // substitution partial lane (owns rows 2p,2p+1)

  __syncthreads();

#pragma unroll 1
  for (int ic = 0; ic < 32; ++ic) {
    const float ts = (float)(ic * 64);

    // ---- P1: load K,Q full (+ K transpose), V slice, etas ----
#pragma unroll
    for (int s = 0; s < 2; ++s) {
      const int f = tid + 512 * s;
      const int r = f >> 4, c4 = (f & 15) * 4;
      const float4 kv = *(const float4*)(kp + (size_t)(ic * 64 + r) * 1024 + c4);
      const float4 qv = *(const float4*)(qp + (size_t)(ic * 64 + r) * 1024 + c4);
      *(float4*)&Ks[r * LDK + c4] = kv;
      *(float4*)&Qs[r * LDK + c4] = qv;
      Kt[(c4 + 0) * LDK + r] = kv.x;
      Kt[(c4 + 1) * LDK + r] = kv.y;
      Kt[(c4 + 2) * LDK + r] = kv.z;
      Kt[(c4 + 3) * LDK + r] = kv.w;
    }
    {
      const float2 vv = *(const float2*)(vp + (size_t)(ic * 64 + row) * 1024 + c2);
      *(float2*)&Us[row * LDW + c2] = vv;
    }
    if (tid < 64) etas[tid] = etap[(size_t)(ic * 64 + tid) * 16];
    __syncthreads();

    // ---- P2: T = tril(eta_r * K K^T, -1) full; RHS = V - eta_r*(K W) slice ----
    {
      float aT[8] = {0, 0, 0, 0, 0, 0, 0, 0};
      float aR0 = 0.f, aR1 = 0.f;
      for (int e = 0; e < 64; ++e) {
        const float kr = Ks[row * LDK + e];
        const float4 t0 = *(const float4*)&Kt[e * LDK + j0];
        const float4 t1 = *(const float4*)&Kt[e * LDK + j0 + 4];
        aT[0] += kr * t0.x; aT[1] += kr * t0.y; aT[2] += kr * t0.z; aT[3] += kr * t0.w;
        aT[4] += kr * t1.x; aT[5] += kr * t1.y; aT[6] += kr * t1.z; aT[7] += kr * t1.w;
        const float2 w = *(const float2*)&Ws[e * LDW + c2];
        aR0 += kr * w.x; aR1 += kr * w.y;
      }
      const float et = etas[row];
#pragma unroll
      for (int mm = 0; mm < 8; ++mm) {
        const int col = j0 + mm;
        Ts[row * LDK + col] = (col < row) ? et * aT[mm] : 0.f;
      }
      float2 v = *(float2*)&Us[row * LDW + c2];
      v.x -= et * aR0; v.y -= et * aR1;
      *(float2*)&Us[row * LDW + c2] = v;
    }
    __syncthreads();

    // ---- P3: forward substitution (I+T) U = RHS on 16 cols (2 cols/wave) ----
    {
      float u0 = 0.f, u1 = 0.f;
      for (int rb = 0; rb < 64; rb += 8) {
        float2 tp[8];
        float rr[8];
#pragma unroll
        for (int i = 0; i < 8; ++i) tp[i] = *(const float2*)&Ts[(rb + i) * LDK + 2 * p];
#pragma unroll
        for (int i = 0; i < 8; ++i) rr[i] = Us[(rb + i) * LDW + scol];
#pragma unroll
        for (int i = 0; i < 8; ++i) {
          const int r = rb + i;
          float acc = tp[i].x * u0 + tp[i].y * u1;
          acc += __shfl_xor(acc, 1);
          acc += __shfl_xor(acc, 2);
          acc += __shfl_xor(acc, 4);
          acc += __shfl_xor(acc, 8);
          acc += __shfl_xor(acc, 16);
          const float u = rr[i] - acc;
          if (p == (r >> 1)) { if (r & 1) u1 = u; else u0 = u; }
          if (p == 31) Us[r * LDW + scol] = u;
        }
      }
    }
    __syncthreads();

    // ---- P4: S = T_mat .* (Q K^T) full; aA = Q@Wavg, aC = Q@W (2 cols) ----
    float aA0, aA1, aC0, aC1;
    {
      float aS[8] = {0, 0, 0, 0, 0, 0, 0, 0};
      aA0 = aA1 = aC0 = aC1 = 0.f;
      for (int e = 0; e < 64; ++e) {
        const float qr = Qs[row * LDK + e];
        const float4 t0 = *(const float4*)&Kt[e * LDK + j0];
        const float4 t1 = *(const float4*)&Kt[e * LDK + j0 + 4];
        aS[0] += qr * t0.x; aS[1] += qr * t0.y; aS[2] += qr * t0.z; aS[3] += qr * t0.w;
        aS[4] += qr * t1.x; aS[5] += qr * t1.y; aS[6] += qr * t1.z; aS[7] += qr * t1.w;
        const float2 wa = *(const float2*)&Was[e * LDW + c2];
        const float2 w = *(const float2*)&Ws[e * LDW + c2];
        aA0 += qr * wa.x; aA1 += qr * wa.y;
        aC0 += qr * w.x;  aC1 += qr * w.y;
      }
      const float tri0 = 0.5f * ts * (ts + 1.f);
      const float csr = (row + 1) * ts + 0.5f * (row + 1) * (row + 2);
      const float rinv = 1.f / (tri0 + csr);
#pragma unroll
      for (int mm = 0; mm < 8; ++mm) {
        const int col = j0 + mm;
        const float jidx = col * ts + 0.5f * col * (col + 1);
        Ts[row * LDK + col] = (csr >= jidx) ? (csr - jidx) * rinv * aS[mm] : 0.f;
      }
    }
    __syncthreads();

    // ---- P5: O slice out; dW = K^T U, dWavg = K^T (U.*w); update W, Wavg ----
    {
      const float tri0 = 0.5f * ts * (ts + 1.f);
      const float csr = (row + 1) * ts + 0.5f * (row + 1) * (row + 2);
      const float av = tri0 / (tri0 + csr);
      const float cv = 1.f - av;
      float o0 = aA0 * av + aC0 * cv;
      float o1 = aA1 * av + aC1 * cv;
      for (int e = 0; e < 64; ++e) {
        const float sr = Ts[row * LDK + e];
        const float2 u = *(const float2*)&Us[e * LDW + c2];
        o0 += sr * u.x; o1 += sr * u.y;
      }
      float2 o2v = {o0, o1};
      *(float2*)(Op + (size_t)(ic * 64 + row) * 64 + c2) = o2v;

      float w0 = 0.f, w1 = 0.f, v0 = 0.f, v1 = 0.f;
      const float invden = 1.f / (0.5f * (ts + 65.f) * (ts + 64.f));
      for (int r = 0; r < 64; ++r) {
        const float ktd = Kt[row * LDK + r];  // K[r][row] — row is key-dim here
        const float2 u = *(const float2*)&Us[r * LDW + c2];
        const float wr =
            (ts * (float)(64 - r) +
             ((float)(r + 1) + 2080.f - 0.5f * (float)(r + 1) * (float)(r + 2))) * invden;
        w0 += ktd * u.x; w1 += ktd * u.y;
        v0 += ktd * u.x * wr; v1 += ktd * u.y * wr;
      }
      const float den = (ts + 64.f) * (ts + 65.f);
      const float cc1 = ts * (ts + 1.f) / den;
      const float cc2 = 64.f * (2.f * ts + 65.f) / den;
      const float2 wold = *(const float2*)&Ws[row * LDW + c2];
      const float2 wavo = *(const float2*)&Was[row * LDW + c2];
      float2 nav = {cc1 * wavo.x + cc2 * wold.x + v0, cc1 * wavo.y + cc2 * wold.y + v1};
      float2 nw = {wold.x + w0, wold.y + w1};
      *(float2*)&Was[row * LDW + c2] = nav;
      *(float2*)&Ws[row * LDW + c2] = nw;
    }
    __syncthreads();
  }
}

// ---------------------------------------------------------------------------
// RMS norm over head dim + relayout (B,H,L,D) -> (B,L,Dm)
// ---------------------------------------------------------------------------
__global__ __launch_bounds__(256) void rms_kernel(const float* __restrict__ O,
                                                  const float* __restrict__ rmsw,
                                                  float* __restrict__ out) {
  const int m = blockIdx.x;  // b*2048 + l
  const int b = m >> 11, l = m & 2047;
  const int wv = threadIdx.x >> 6, lane = threadIdx.x & 63;
  const float rw = rmsw[lane];
#pragma unroll
  for (int hh = 0; hh < 4; ++hh) {
    const int h = wv * 4 + hh;
    const float v = O[(((size_t)(b * 16 + h)) * 2048 + l) * 64 + lane];
    float ss = v * v;
    ss += __shfl_xor(ss, 1); ss += __shfl_xor(ss, 2); ss += __shfl_xor(ss, 4);
    ss += __shfl_xor(ss, 8); ss += __shfl_xor(ss, 16); ss += __shfl_xor(ss, 32);
    const float sc = rsqrtf(ss * (1.f / 64.f) + 1e-6f);
    out[(size_t)m * 1024 + h * 64 + lane] = v * sc * rw;
  }
}

// ---------------------------------------------------------------------------
extern "C" void kernel_launch(void* const* d_in, const int* in_sizes, int n_in,
                              void* d_out, int out_size, void* d_ws, size_t ws_size,
                              hipStream_t stream) {
  (void)in_sizes; (void)n_in; (void)out_size; (void)ws_size;
  const float* x     = (const float*)d_in[0];
  const float* Wk    = (const float*)d_in[1];
  const float* bk    = (const float*)d_in[2];
  const float* Wq    = (const float*)d_in[3];
  const float* bq    = (const float*)d_in[4];
  const float* Wv    = (const float*)d_in[5];
  const float* bv    = (const float*)d_in[6];
  const float* Wbeta = (const float*)d_in[7];
  const float* bbeta = (const float*)d_in[8];
  const float* convk = (const float*)d_in[9];
  const float* convq = (const float*)d_in[10];
  const float* convv = (const float*)d_in[11];
  const float* rmsw  = (const float*)d_in[12];
  const float* Wout  = (const float*)d_in[13];
  const float* bout  = (const float*)d_in[14];
  float* out = (float*)d_out;
  float* ws = (float*)d_ws;

  const size_t SZ = (size_t)8192 * 1024;
  float* kpre = ws;            // dead after prep -> reused as Obuf
  float* qpre = ws + SZ;       // dead after prep -> reused as normed
  float* vpre = ws + 2 * SZ;
  float* knb  = ws + 3 * SZ;
  float* qnb  = ws + 4 * SZ;
  float* betab = ws + 5 * SZ;
  float* vzb  = out;           // d_out doubles as eta*silu(v) scratch (re-poisoned
                               // each launch; fully rewritten by final GEMM)
  float* Obuf = kpre;
  float* normed = qpre;

  dim3 g(64, 8), blk(256);
  hipLaunchKernelGGL(gemm_nt, g, blk, 0, stream, x, Wk, bk, kpre, 8192, 1024, 1024);
  hipLaunchKernelGGL(gemm_nt, g, blk, 0, stream, x, Wq, bq, qpre, 8192, 1024, 1024);
  hipLaunchKernelGGL(gemm_nt, g, blk, 0, stream, x, Wv, bv, vpre, 8192, 1024, 1024);
  hipLaunchKernelGGL(beta_kernel, dim3(8192), blk, 0, stream, x, Wbeta, bbeta, betab);
  hipLaunchKernelGGL(prep_kernel, dim3(8192), blk, 0, stream, kpre, qpre, vpre, betab,
                     convk, convq, convv, knb, qnb, vzb);
  hipLaunchKernelGGL(scan_kernel, dim3(256), dim3(512), 0, stream, knb, qnb, vzb,
                     betab, Obuf);
  hipLaunchKernelGGL(rms_kernel, dim3(8192), blk, 0, stream, Obuf, rmsw, normed);
  hipLaunchKernelGGL(gemm_nt, g, blk, 0, stream, normed, Wout, bout, out, 8192, 1024, 1024);
}

// Round 4
// 1145.091 us; speedup vs baseline: 1.7418x; 1.5956x over previous
//
#include <hip/hip_runtime.h>

#define LDK 68  // K/Q/Kt/Ts row stride (64 + 4 pad)
#define LDW 20  // W/Wavg/U slice row stride (16 + 4 pad)

typedef __attribute__((ext_vector_type(8))) short bf16x8;
typedef __attribute__((ext_vector_type(4))) float f32x4;

__device__ inline unsigned short f2bf_rne(float f) {
  unsigned int u = __float_as_uint(f);
  u += 0x7FFFu + ((u >> 16) & 1u);
  return (unsigned short)(u >> 16);
}

// ---------------------------------------------------------------------------
// cast f32 -> bf16 (RNE), vectorized x4
// ---------------------------------------------------------------------------
__global__ __launch_bounds__(256) void cast_bf16_kernel(const float* __restrict__ in,
                                                        unsigned short* __restrict__ out,
                                                        int n4) {
  const int i = blockIdx.x * 256 + threadIdx.x;
  if (i >= n4) return;
  const float4 v = ((const float4*)in)[i];
  ushort4 o;
  o.x = f2bf_rne(v.x); o.y = f2bf_rne(v.y); o.z = f2bf_rne(v.z); o.w = f2bf_rne(v.w);
  ((ushort4*)out)[i] = o;
}

// ---------------------------------------------------------------------------
// bf16 MFMA GEMM (NT): C[m][n] = bias[n] + sum_k A[m][k]*Bw[n][k]
// A: MxK bf16 row-major, Bw: NxK bf16 row-major, C f32.
// 128x128 tile, BK=32, 256 threads (4 waves, each 64x64), global_load_lds.
// ---------------------------------------------------------------------------
__global__ __launch_bounds__(256) void gemm_bf16_nt(
    const unsigned short* __restrict__ A, const unsigned short* __restrict__ Bw,
    const float* __restrict__ bias, float* __restrict__ C, int M, int N, int K) {
  __shared__ unsigned short Asl[128 * 32];
  __shared__ unsigned short Bsl[128 * 32];
  const int tid = threadIdx.x;
  const int lane = tid & 63, w = tid >> 6;
  const int bm = blockIdx.x * 128, bn = blockIdx.y * 128;
  const int wr = (w >> 1) * 64, wc = (w & 1) * 64;

  // staging mapping: 16B chunk li covers tile row li>>2, bf16-col (li&3)*8
  const int li0 = tid, li1 = tid + 256;
  const int ar0 = li0 >> 2, ak0 = (li0 & 3) * 8;
  const int ar1 = li1 >> 2, ak1 = (li1 & 3) * 8;
  const unsigned short* gA0 = A + (size_t)(bm + ar0) * K + ak0;
  const unsigned short* gA1 = A + (size_t)(bm + ar1) * K + ak1;
  const unsigned short* gB0 = Bw + (size_t)(bn + ar0) * K + ak0;
  const unsigned short* gB1 = Bw + (size_t)(bn + ar1) * K + ak1;
  // wave-uniform LDS bases (dest = base + lane*16)
  unsigned short* lA0 = &Asl[(size_t)(w * 64) * 8];
  unsigned short* lA1 = &Asl[(size_t)(w * 64 + 256) * 8];
  unsigned short* lB0 = &Bsl[(size_t)(w * 64) * 8];
  unsigned short* lB1 = &Bsl[(size_t)(w * 64 + 256) * 8];

  f32x4 acc[4][4];
#pragma unroll
  for (int i = 0; i < 4; ++i)
#pragma unroll
    for (int j = 0; j < 4; ++j) acc[i][j] = (f32x4){0.f, 0.f, 0.f, 0.f};

  const int fr = lane & 15, kg = lane >> 4;

  for (int k0 = 0; k0 < K; k0 += 32) {
    __syncthreads();  // previous iteration's frag reads complete
    __builtin_amdgcn_global_load_lds((const __attribute__((address_space(1))) unsigned int*)(gA0 + k0),
                                     (__attribute__((address_space(3))) unsigned int*)lA0, 16, 0, 0);
    __builtin_amdgcn_global_load_lds((const __attribute__((address_space(1))) unsigned int*)(gA1 + k0),
                                     (__attribute__((address_space(3))) unsigned int*)lA1, 16, 0, 0);
    __builtin_amdgcn_global_load_lds((const __attribute__((address_space(1))) unsigned int*)(gB0 + k0),
                                     (__attribute__((address_space(3))) unsigned int*)lB0, 16, 0, 0);
    __builtin_amdgcn_global_load_lds((const __attribute__((address_space(1))) unsigned int*)(gB1 + k0),
                                     (__attribute__((address_space(3))) unsigned int*)lB1, 16, 0, 0);
    __syncthreads();  // vmcnt drained by barrier semantics

    bf16x8 af[4], bfr[4];
#pragma unroll
    for (int i = 0; i < 4; ++i) {
      af[i] = *(const bf16x8*)&Asl[(size_t)(wr + i * 16 + fr) * 32 + kg * 8];
      bfr[i] = *(const bf16x8*)&Bsl[(size_t)(wc + i * 16 + fr) * 32 + kg * 8];
    }
#pragma unroll
    for (int i = 0; i < 4; ++i)
#pragma unroll
      for (int j = 0; j < 4; ++j)
        acc[i][j] = __builtin_amdgcn_mfma_f32_16x16x32_bf16(af[i], bfr[j], acc[i][j], 0, 0, 0);
  }

  const int og = lane >> 4;
#pragma unroll
  for (int j = 0; j < 4; ++j) {
    const int col = bn + wc + j * 16 + fr;
    const float bs = bias[col];
#pragma unroll
    for (int i = 0; i < 4; ++i) {
#pragma unroll
      for (int r = 0; r < 4; ++r) {
        const int row = bm + wr + i * 16 + og * 4 + r;
        C[(size_t)row * N + col] = acc[i][j][r] + bs;
      }
    }
  }
}

// ---------------------------------------------------------------------------
// beta[m][h] = sigmoid( sum_k x[m][k]*Wb[h][k] + bb[h] )
// ---------------------------------------------------------------------------
__global__ __launch_bounds__(256) void beta_kernel(const float* __restrict__ x,
                                                   const float* __restrict__ Wb,
                                                   const float* __restrict__ bb,
                                                   float* __restrict__ beta) {
  const int m = blockIdx.x;
  const int tid = threadIdx.x;
  const int h = tid >> 4;
  const int l = tid & 15;
  const float4* x4 = (const float4*)(x + (size_t)m * 1024);
  const float4* w4 = (const float4*)(Wb + (size_t)h * 1024);
  float acc = 0.f;
#pragma unroll 4
  for (int jj = 0; jj < 16; ++jj) {
    float4 xv = x4[l + 16 * jj];
    float4 wv = w4[l + 16 * jj];
    acc += xv.x * wv.x + xv.y * wv.y + xv.z * wv.z + xv.w * wv.w;
  }
  acc += __shfl_xor(acc, 1);
  acc += __shfl_xor(acc, 2);
  acc += __shfl_xor(acc, 4);
  acc += __shfl_xor(acc, 8);
  if (l == 0) {
    const float s = acc + bb[h];
    beta[(size_t)m * 16 + h] = 1.f / (1.f + expf(-s));
  }
}

// ---------------------------------------------------------------------------
// prep: causal conv (K=4) on k/q/v projections + L2-norm(k,q per head) +
// eta*silu(v). One block per (b,l); wave w + iter s handles head 4s+w, lane=d.
// ---------------------------------------------------------------------------
__global__ __launch_bounds__(256) void prep_kernel(
    const float* __restrict__ kpre, const float* __restrict__ qpre,
    const float* __restrict__ vpre, const float* __restrict__ betab,
    const float* __restrict__ convk, const float* __restrict__ convq,
    const float* __restrict__ convv,
    float* __restrict__ kn, float* __restrict__ qn, float* __restrict__ vz) {
  const int m = blockIdx.x;          // b*2048 + l
  const int l = m & 2047;
  const int lane = threadIdx.x & 63;
  const int wvi = threadIdx.x >> 6;  // 0..3
#pragma unroll
  for (int s = 0; s < 4; ++s) {
    const int h = 4 * s + wvi;
    const int c = h * 64 + lane;
    const float4 wk4 = *(const float4*)(convk + (size_t)c * 4);
    const float4 wq4 = *(const float4*)(convq + (size_t)c * 4);
    const float4 wv4 = *(const float4*)(convv + (size_t)c * 4);
    const float wk[4] = {wk4.x, wk4.y, wk4.z, wk4.w};
    const float wq[4] = {wq4.x, wq4.y, wq4.z, wq4.w};
    const float wvv[4] = {wv4.x, wv4.y, wv4.z, wv4.w};
    float kc = 0.f, qc = 0.f, vc = 0.f;
#pragma unroll
    for (int j = 0; j < 4; ++j) {
      const int lj = l - 3 + j;
      if (lj >= 0) {
        const size_t base = ((size_t)(m - l + lj)) * 1024 + c;
        kc += wk[j] * kpre[base];
        qc += wq[j] * qpre[base];
        vc += wvv[j] * vpre[base];
      }
    }
    float ssk = kc * kc, ssq = qc * qc;
    ssk += __shfl_xor(ssk, 1); ssq += __shfl_xor(ssq, 1);
    ssk += __shfl_xor(ssk, 2); ssq += __shfl_xor(ssq, 2);
    ssk += __shfl_xor(ssk, 4); ssq += __shfl_xor(ssq, 4);
    ssk += __shfl_xor(ssk, 8); ssq += __shfl_xor(ssq, 8);
    ssk += __shfl_xor(ssk, 16); ssq += __shfl_xor(ssq, 16);
    ssk += __shfl_xor(ssk, 32); ssq += __shfl_xor(ssq, 32);
    const float eta = betab[(size_t)m * 16 + h];
    const size_t o = (size_t)m * 1024 + c;
    kn[o] = kc / (sqrtf(ssk) + 1e-6f);
    qn[o] = qc / (sqrtf(ssq) + 1e-6f);
    vz[o] = eta * vc / (1.f + expf(-vc));
  }
}

// ---------------------------------------------------------------------------
// Delta-rule scan v2: 256 blocks = (b,h) x 4 column-groups of 16; 512 threads.
// ---------------------------------------------------------------------------
__global__ __launch_bounds__(512) void scan_kernel(
    const float* __restrict__ kn, const float* __restrict__ qn,
    const float* __restrict__ vz, const float* __restrict__ betab,
    float* __restrict__ O) {
  __shared__ float Ks[64 * LDK], Qs[64 * LDK], Kt[64 * LDK], Ts[64 * LDK];
  __shared__ float Ws[64 * LDW], Was[64 * LDW], Us[64 * LDW];
  __shared__ float etas[64];

  const int tid = threadIdx.x;
  const int bh = blockIdx.x >> 2;
  const int g = blockIdx.x & 3;
  const int b = bh >> 4, h = bh & 15;
  const int c0 = g * 16;

  for (int i = tid; i < 64 * LDW; i += 512) { Ws[i] = 0.f; Was[i] = 0.f; }

  const size_t base = ((size_t)b * 2048) * 1024 + (size_t)h * 64;
  const float* kp = kn + base;
  const float* qp = qn + base;
  const float* vp = vz + base + c0;
  const float* etap = betab + (size_t)b * 2048 * 16 + h;
  float* Op = O + (size_t)bh * 2048 * 64 + c0;

  const int row = tid >> 3;        // 0..63
  const int j0 = (tid & 7) * 8;    // 8-col strip for full 64-wide outputs
  const int c2 = (tid & 7) * 2;    // 2-col strip for 16-wide slices
  const int lane = tid & 63, wvi = tid >> 6;
  const int colw = lane >> 5;
  const int scol = wvi * 2 + colw;
  const int p = lane & 31;

  __syncthreads();

#pragma unroll 1
  for (int ic = 0; ic < 32; ++ic) {
    const float ts = (float)(ic * 64);

    // ---- P1: load K,Q full (+ K transpose), V slice, etas ----
#pragma unroll
    for (int s = 0; s < 2; ++s) {
      const int f = tid + 512 * s;
      const int r = f >> 4, c4 = (f & 15) * 4;
      const float4 kv = *(const float4*)(kp + (size_t)(ic * 64 + r) * 1024 + c4);
      const float4 qv = *(const float4*)(qp + (size_t)(ic * 64 + r) * 1024 + c4);
      *(float4*)&Ks[r * LDK + c4] = kv;
      *(float4*)&Qs[r * LDK + c4] = qv;
      Kt[(c4 + 0) * LDK + r] = kv.x;
      Kt[(c4 + 1) * LDK + r] = kv.y;
      Kt[(c4 + 2) * LDK + r] = kv.z;
      Kt[(c4 + 3) * LDK + r] = kv.w;
    }
    {
      const float2 vv = *(const float2*)(vp + (size_t)(ic * 64 + row) * 1024 + c2);
      *(float2*)&Us[row * LDW + c2] = vv;
    }
    if (tid < 64) etas[tid] = etap[(size_t)(ic * 64 + tid) * 16];
    __syncthreads();

    // ---- P2: T = tril(eta_r * K K^T, -1) full; RHS = V - eta_r*(K W) slice ----
    {
      float aT[8] = {0, 0, 0, 0, 0, 0, 0, 0};
      float aR0 = 0.f, aR1 = 0.f;
      for (int e = 0; e < 64; ++e) {
        const float kr = Ks[row * LDK + e];
        const float4 t0 = *(const float4*)&Kt[e * LDK + j0];
        const float4 t1 = *(const float4*)&Kt[e * LDK + j0 + 4];
        aT[0] += kr * t0.x; aT[1] += kr * t0.y; aT[2] += kr * t0.z; aT[3] += kr * t0.w;
        aT[4] += kr * t1.x; aT[5] += kr * t1.y; aT[6] += kr * t1.z; aT[7] += kr * t1.w;
        const float2 w = *(const float2*)&Ws[e * LDW + c2];
        aR0 += kr * w.x; aR1 += kr * w.y;
      }
      const float et = etas[row];
#pragma unroll
      for (int mm = 0; mm < 8; ++mm) {
        const int col = j0 + mm;
        Ts[row * LDK + col] = (col < row) ? et * aT[mm] : 0.f;
      }
      float2 v = *(float2*)&Us[row * LDW + c2];
      v.x -= et * aR0; v.y -= et * aR1;
      *(float2*)&Us[row * LDW + c2] = v;
    }
    __syncthreads();

    // ---- P3: forward substitution (I+T) U = RHS on 16 cols (2 cols/wave) ----
    {
      float u0 = 0.f, u1 = 0.f;
      for (int rb = 0; rb < 64; rb += 8) {
        float2 tp[8];
        float rr[8];
#pragma unroll
        for (int i = 0; i < 8; ++i) tp[i] = *(const float2*)&Ts[(rb + i) * LDK + 2 * p];
#pragma unroll
        for (int i = 0; i < 8; ++i) rr[i] = Us[(rb + i) * LDW + scol];
#pragma unroll
        for (int i = 0; i < 8; ++i) {
          const int r = rb + i;
          float acc = tp[i].x * u0 + tp[i].y * u1;
          acc += __shfl_xor(acc, 1);
          acc += __shfl_xor(acc, 2);
          acc += __shfl_xor(acc, 4);
          acc += __shfl_xor(acc, 8);
          acc += __shfl_xor(acc, 16);
          const float u = rr[i] - acc;
          if (p == (r >> 1)) { if (r & 1) u1 = u; else u0 = u; }
          if (p == 31) Us[r * LDW + scol] = u;
        }
      }
    }
    __syncthreads();

    // ---- P4: S = T_mat .* (Q K^T) full; aA = Q@Wavg, aC = Q@W (2 cols) ----
    float aA0, aA1, aC0, aC1;
    {
      float aS[8] = {0, 0, 0, 0, 0, 0, 0, 0};
      aA0 = aA1 = aC0 = aC1 = 0.f;
      for (int e = 0; e < 64; ++e) {
        const float qr = Qs[row * LDK + e];
        const float4 t0 = *(const float4*)&Kt[e * LDK + j0];
        const float4 t1 = *(const float4*)&Kt[e * LDK + j0 + 4];
        aS[0] += qr * t0.x; aS[1] += qr * t0.y; aS[2] += qr * t0.z; aS[3] += qr * t0.w;
        aS[4] += qr * t1.x; aS[5] += qr * t1.y; aS[6] += qr * t1.z; aS[7] += qr * t1.w;
        const float2 wa = *(const float2*)&Was[e * LDW + c2];
        const float2 w = *(const float2*)&Ws[e * LDW + c2];
        aA0 += qr * wa.x; aA1 += qr * wa.y;
        aC0 += qr * w.x;  aC1 += qr * w.y;
      }
      const float tri0 = 0.5f * ts * (ts + 1.f);
      const float csr = (row + 1) * ts + 0.5f * (row + 1) * (row + 2);
      const float rinv = 1.f / (tri0 + csr);
#pragma unroll
      for (int mm = 0; mm < 8; ++mm) {
        const int col = j0 + mm;
        const float jidx = col * ts + 0.5f * col * (col + 1);
        Ts[row * LDK + col] = (csr >= jidx) ? (csr - jidx) * rinv * aS[mm] : 0.f;
      }
    }
    __syncthreads();

    // ---- P5: O slice out; dW = K^T U, dWavg = K^T (U.*w); update W, Wavg ----
    {
      const float tri0 = 0.5f * ts * (ts + 1.f);
      const float csr = (row + 1) * ts + 0.5f * (row + 1) * (row + 2);
      const float av = tri0 / (tri0 + csr);
      const float cv = 1.f - av;
      float o0 = aA0 * av + aC0 * cv;
      float o1 = aA1 * av + aC1 * cv;
      for (int e = 0; e < 64; ++e) {
        const float sr = Ts[row * LDK + e];
        const float2 u = *(const float2*)&Us[e * LDW + c2];
        o0 += sr * u.x; o1 += sr * u.y;
      }
      float2 o2v = {o0, o1};
      *(float2*)(Op + (size_t)(ic * 64 + row) * 64 + c2) = o2v;

      float w0 = 0.f, w1 = 0.f, v0 = 0.f, v1 = 0.f;
      const float invden = 1.f / (0.5f * (ts + 65.f) * (ts + 64.f));
      for (int r = 0; r < 64; ++r) {
        const float ktd = Kt[row * LDK + r];
        const float2 u = *(const float2*)&Us[r * LDW + c2];
        const float wr =
            (ts * (float)(64 - r) +
             ((float)(r + 1) + 2080.f - 0.5f * (float)(r + 1) * (float)(r + 2))) * invden;
        w0 += ktd * u.x; w1 += ktd * u.y;
        v0 += ktd * u.x * wr; v1 += ktd * u.y * wr;
      }
      const float den = (ts + 64.f) * (ts + 65.f);
      const float cc1 = ts * (ts + 1.f) / den;
      const float cc2 = 64.f * (2.f * ts + 65.f) / den;
      const float2 wold = *(const float2*)&Ws[row * LDW + c2];
      const float2 wavo = *(const float2*)&Was[row * LDW + c2];
      float2 nav = {cc1 * wavo.x + cc2 * wold.x + v0, cc1 * wavo.y + cc2 * wold.y + v1};
      float2 nw = {wold.x + w0, wold.y + w1};
      *(float2*)&Was[row * LDW + c2] = nav;
      *(float2*)&Ws[row * LDW + c2] = nw;
    }
    __syncthreads();
  }
}

// ---------------------------------------------------------------------------
// RMS norm over head dim + relayout (B,H,L,D) -> (B,L,Dm), bf16 output
// ---------------------------------------------------------------------------
__global__ __launch_bounds__(256) void rms_kernel(const float* __restrict__ O,
                                                  const float* __restrict__ rmsw,
                                                  unsigned short* __restrict__ out16) {
  const int m = blockIdx.x;  // b*2048 + l
  const int b = m >> 11, l = m & 2047;
  const int wv = threadIdx.x >> 6, lane = threadIdx.x & 63;
  const float rw = rmsw[lane];
#pragma unroll
  for (int hh = 0; hh < 4; ++hh) {
    const int h = wv * 4 + hh;
    const float v = O[(((size_t)(b * 16 + h)) * 2048 + l) * 64 + lane];
    float ss = v * v;
    ss += __shfl_xor(ss, 1); ss += __shfl_xor(ss, 2); ss += __shfl_xor(ss, 4);
    ss += __shfl_xor(ss, 8); ss += __shfl_xor(ss, 16); ss += __shfl_xor(ss, 32);
    const float sc = rsqrtf(ss * (1.f / 64.f) + 1e-6f);
    out16[(size_t)m * 1024 + h * 64 + lane] = f2bf_rne(v * sc * rw);
  }
}

// ---------------------------------------------------------------------------
extern "C" void kernel_launch(void* const* d_in, const int* in_sizes, int n_in,
                              void* d_out, int out_size, void* d_ws, size_t ws_size,
                              hipStream_t stream) {
  (void)in_sizes; (void)n_in; (void)out_size; (void)ws_size;
  const float* x     = (const float*)d_in[0];
  const float* Wk    = (const float*)d_in[1];
  const float* bk    = (const float*)d_in[2];
  const float* Wq    = (const float*)d_in[3];
  const float* bq    = (const float*)d_in[4];
  const float* Wv    = (const float*)d_in[5];
  const float* bv    = (const float*)d_in[6];
  const float* Wbeta = (const float*)d_in[7];
  const float* bbeta = (const float*)d_in[8];
  const float* convk = (const float*)d_in[9];
  const float* convq = (const float*)d_in[10];
  const float* convv = (const float*)d_in[11];
  const float* rmsw  = (const float*)d_in[12];
  const float* Wout  = (const float*)d_in[13];
  const float* bout  = (const float*)d_in[14];
  float* out = (float*)d_out;
  float* ws = (float*)d_ws;

  const size_t SZ = (size_t)8192 * 1024;
  float* kpre = ws;            // dead after prep -> Obuf
  float* qpre = ws + SZ;       // dead after prep -> normed16 (bf16, aliased)
  float* vpre = ws + 2 * SZ;
  float* knb  = ws + 3 * SZ;
  float* qnb  = ws + 4 * SZ;
  float* betab = ws + 5 * SZ;                       // 131072 floats
  unsigned short* x16 = (unsigned short*)(ws + 5 * SZ + 131072);   // 8.4M bf16
  unsigned short* wk16 = x16 + SZ;                  // SZ bf16 elems = 8.4M
  unsigned short* wq16 = wk16 + 1048576;
  unsigned short* wv16 = wq16 + 1048576;
  unsigned short* wo16 = wv16 + 1048576;
  float* vzb  = out;           // d_out doubles as eta*silu(v) scratch
  float* Obuf = kpre;
  unsigned short* normed16 = (unsigned short*)qpre;

  dim3 blk(256);
  // casts
  hipLaunchKernelGGL(cast_bf16_kernel, dim3(8192), blk, 0, stream, x, x16, (int)(SZ / 4));
  hipLaunchKernelGGL(cast_bf16_kernel, dim3(1024), blk, 0, stream, Wk, wk16, 262144);
  hipLaunchKernelGGL(cast_bf16_kernel, dim3(1024), blk, 0, stream, Wq, wq16, 262144);
  hipLaunchKernelGGL(cast_bf16_kernel, dim3(1024), blk, 0, stream, Wv, wv16, 262144);
  hipLaunchKernelGGL(cast_bf16_kernel, dim3(1024), blk, 0, stream, Wout, wo16, 262144);

  dim3 g(64, 8);
  hipLaunchKernelGGL(gemm_bf16_nt, g, blk, 0, stream, x16, wk16, bk, kpre, 8192, 1024, 1024);
  hipLaunchKernelGGL(gemm_bf16_nt, g, blk, 0, stream, x16, wq16, bq, qpre, 8192, 1024, 1024);
  hipLaunchKernelGGL(gemm_bf16_nt, g, blk, 0, stream, x16, wv16, bv, vpre, 8192, 1024, 1024);
  hipLaunchKernelGGL(beta_kernel, dim3(8192), blk, 0, stream, x, Wbeta, bbeta, betab);
  hipLaunchKernelGGL(prep_kernel, dim3(8192), blk, 0, stream, kpre, qpre, vpre, betab,
                     convk, convq, convv, knb, qnb, vzb);
  hipLaunchKernelGGL(scan_kernel, dim3(256), dim3(512), 0, stream, knb, qnb, vzb,
                     betab, Obuf);
  hipLaunchKernelGGL(rms_kernel, dim3(8192), blk, 0, stream, Obuf, rmsw, normed16);
  hipLaunchKernelGGL(gemm_bf16_nt, g, blk, 0, stream, normed16, wo16, bout, out,
                     8192, 1024, 1024);
}

// Round 5
// 626.502 us; speedup vs baseline: 3.1837x; 1.8278x over previous
//
#include <hip/hip_runtime.h>

typedef __attribute__((ext_vector_type(8))) short bf16x8;
typedef __attribute__((ext_vector_type(4))) float f32x4;

#define MFMA(a, b, c) __builtin_amdgcn_mfma_f32_16x16x32_bf16((a), (b), (c), 0, 0, 0)

__device__ inline unsigned short f2bf_rne(float f) {
  unsigned int u = __float_as_uint(f);
  u += 0x7FFFu + ((u >> 16) & 1u);
  return (unsigned short)(u >> 16);
}

// ---------------------------------------------------------------------------
// cast f32 -> bf16 (RNE), vectorized x4
// ---------------------------------------------------------------------------
__global__ __launch_bounds__(256) void cast_bf16_kernel(const float* __restrict__ in,
                                                        unsigned short* __restrict__ out,
                                                        int n4) {
  const int i = blockIdx.x * 256 + threadIdx.x;
  if (i >= n4) return;
  const float4 v = ((const float4*)in)[i];
  ushort4 o;
  o.x = f2bf_rne(v.x); o.y = f2bf_rne(v.y); o.z = f2bf_rne(v.z); o.w = f2bf_rne(v.w);
  ((ushort4*)out)[i] = o;
}

// ---------------------------------------------------------------------------
// bf16 MFMA GEMM (NT): C[m][n] = bias[n] + sum_k A[m][k]*Bw[n][k]
// ---------------------------------------------------------------------------
__global__ __launch_bounds__(256) void gemm_bf16_nt(
    const unsigned short* __restrict__ A, const unsigned short* __restrict__ Bw,
    const float* __restrict__ bias, float* __restrict__ C, int M, int N, int K) {
  __shared__ unsigned short Asl[128 * 32];
  __shared__ unsigned short Bsl[128 * 32];
  const int tid = threadIdx.x;
  const int lane = tid & 63, w = tid >> 6;
  const int bm = blockIdx.x * 128, bn = blockIdx.y * 128;
  const int wr = (w >> 1) * 64, wc = (w & 1) * 64;

  const int li0 = tid, li1 = tid + 256;
  const int ar0 = li0 >> 2, ak0 = (li0 & 3) * 8;
  const int ar1 = li1 >> 2, ak1 = (li1 & 3) * 8;
  const unsigned short* gA0 = A + (size_t)(bm + ar0) * K + ak0;
  const unsigned short* gA1 = A + (size_t)(bm + ar1) * K + ak1;
  const unsigned short* gB0 = Bw + (size_t)(bn + ar0) * K + ak0;
  const unsigned short* gB1 = Bw + (size_t)(bn + ar1) * K + ak1;
  unsigned short* lA0 = &Asl[(size_t)(w * 64) * 8];
  unsigned short* lA1 = &Asl[(size_t)(w * 64 + 256) * 8];
  unsigned short* lB0 = &Bsl[(size_t)(w * 64) * 8];
  unsigned short* lB1 = &Bsl[(size_t)(w * 64 + 256) * 8];

  f32x4 acc[4][4];
#pragma unroll
  for (int i = 0; i < 4; ++i)
#pragma unroll
    for (int j = 0; j < 4; ++j) acc[i][j] = (f32x4){0.f, 0.f, 0.f, 0.f};

  const int fr = lane & 15, kg = lane >> 4;

  for (int k0 = 0; k0 < K; k0 += 32) {
    __syncthreads();
    __builtin_amdgcn_global_load_lds((const __attribute__((address_space(1))) unsigned int*)(gA0 + k0),
                                     (__attribute__((address_space(3))) unsigned int*)lA0, 16, 0, 0);
    __builtin_amdgcn_global_load_lds((const __attribute__((address_space(1))) unsigned int*)(gA1 + k0),
                                     (__attribute__((address_space(3))) unsigned int*)lA1, 16, 0, 0);
    __builtin_amdgcn_global_load_lds((const __attribute__((address_space(1))) unsigned int*)(gB0 + k0),
                                     (__attribute__((address_space(3))) unsigned int*)lB0, 16, 0, 0);
    __builtin_amdgcn_global_load_lds((const __attribute__((address_space(1))) unsigned int*)(gB1 + k0),
                                     (__attribute__((address_space(3))) unsigned int*)lB1, 16, 0, 0);
    __syncthreads();

    bf16x8 af[4], bfr[4];
#pragma unroll
    for (int i = 0; i < 4; ++i) {
      af[i] = *(const bf16x8*)&Asl[(size_t)(wr + i * 16 + fr) * 32 + kg * 8];
      bfr[i] = *(const bf16x8*)&Bsl[(size_t)(wc + i * 16 + fr) * 32 + kg * 8];
    }
#pragma unroll
    for (int i = 0; i < 4; ++i)
#pragma unroll
      for (int j = 0; j < 4; ++j)
        acc[i][j] = MFMA(af[i], bfr[j], acc[i][j]);
  }

  const int og = lane >> 4;
#pragma unroll
  for (int j = 0; j < 4; ++j) {
    const int col = bn + wc + j * 16 + fr;
    const float bs = bias[col];
#pragma unroll
    for (int i = 0; i < 4; ++i) {
#pragma unroll
      for (int r = 0; r < 4; ++r) {
        const int row = bm + wr + i * 16 + og * 4 + r;
        C[(size_t)row * N + col] = acc[i][j][r] + bs;
      }
    }
  }
}

// ---------------------------------------------------------------------------
// beta[m][h] = sigmoid( sum_k x[m][k]*Wb[h][k] + bb[h] )
// ---------------------------------------------------------------------------
__global__ __launch_bounds__(256) void beta_kernel(const float* __restrict__ x,
                                                   const float* __restrict__ Wb,
                                                   const float* __restrict__ bb,
                                                   float* __restrict__ beta) {
  const int m = blockIdx.x;
  const int tid = threadIdx.x;
  const int h = tid >> 4;
  const int l = tid & 15;
  const float4* x4 = (const float4*)(x + (size_t)m * 1024);
  const float4* w4 = (const float4*)(Wb + (size_t)h * 1024);
  float acc = 0.f;
#pragma unroll 4
  for (int jj = 0; jj < 16; ++jj) {
    float4 xv = x4[l + 16 * jj];
    float4 wv = w4[l + 16 * jj];
    acc += xv.x * wv.x + xv.y * wv.y + xv.z * wv.z + xv.w * wv.w;
  }
  acc += __shfl_xor(acc, 1);
  acc += __shfl_xor(acc, 2);
  acc += __shfl_xor(acc, 4);
  acc += __shfl_xor(acc, 8);
  if (l == 0) {
    const float s = acc + bb[h];
    beta[(size_t)m * 16 + h] = 1.f / (1.f + expf(-s));
  }
}

// ---------------------------------------------------------------------------
// prep: conv + norms + eta*silu; outputs bf16 k,q and f32 eta*silu(v)
// ---------------------------------------------------------------------------
__global__ __launch_bounds__(256) void prep_kernel(
    const float* __restrict__ kpre, const float* __restrict__ qpre,
    const float* __restrict__ vpre, const float* __restrict__ betab,
    const float* __restrict__ convk, const float* __restrict__ convq,
    const float* __restrict__ convv,
    unsigned short* __restrict__ kn16, unsigned short* __restrict__ qn16,
    float* __restrict__ vz) {
  const int m = blockIdx.x;          // b*2048 + l
  const int l = m & 2047;
  const int lane = threadIdx.x & 63;
  const int wvi = threadIdx.x >> 6;  // 0..3
#pragma unroll
  for (int s = 0; s < 4; ++s) {
    const int h = 4 * s + wvi;
    const int c = h * 64 + lane;
    const float4 wk4 = *(const float4*)(convk + (size_t)c * 4);
    const float4 wq4 = *(const float4*)(convq + (size_t)c * 4);
    const float4 wv4 = *(const float4*)(convv + (size_t)c * 4);
    const float wk[4] = {wk4.x, wk4.y, wk4.z, wk4.w};
    const float wq[4] = {wq4.x, wq4.y, wq4.z, wq4.w};
    const float wvv[4] = {wv4.x, wv4.y, wv4.z, wv4.w};
    float kc = 0.f, qc = 0.f, vc = 0.f;
#pragma unroll
    for (int j = 0; j < 4; ++j) {
      const int lj = l - 3 + j;
      if (lj >= 0) {
        const size_t base = ((size_t)(m - l + lj)) * 1024 + c;
        kc += wk[j] * kpre[base];
        qc += wq[j] * qpre[base];
        vc += wvv[j] * vpre[base];
      }
    }
    float ssk = kc * kc, ssq = qc * qc;
    ssk += __shfl_xor(ssk, 1); ssq += __shfl_xor(ssq, 1);
    ssk += __shfl_xor(ssk, 2); ssq += __shfl_xor(ssq, 2);
    ssk += __shfl_xor(ssk, 4); ssq += __shfl_xor(ssq, 4);
    ssk += __shfl_xor(ssk, 8); ssq += __shfl_xor(ssq, 8);
    ssk += __shfl_xor(ssk, 16); ssq += __shfl_xor(ssq, 16);
    ssk += __shfl_xor(ssk, 32); ssq += __shfl_xor(ssq, 32);
    const float eta = betab[(size_t)m * 16 + h];
    const size_t o = (size_t)m * 1024 + c;
    kn16[o] = f2bf_rne(kc / (sqrtf(ssk) + 1e-6f));
    qn16[o] = f2bf_rne(qc / (sqrtf(ssq) + 1e-6f));
    vz[o] = eta * vc / (1.f + expf(-vc));
  }
}

// ---------------------------------------------------------------------------
// MFMA delta-rule scan: 1 block per (b,h), 512 threads (8 waves).
// All 64^3 products on matrix cores; inv(I+T) via nilpotent doubling
// U = prod_k (I + P^{2^k}) RHS, P = -T, + one f32 refinement pass.
// State W^T, Wavg^T kept f32 in registers (2 C-tiles/wave).
// ---------------------------------------------------------------------------
#define LDB 72  // bf16 row stride (+8 pad: 2-way banks, 16B-aligned rows)
#define LDV 68  // f32 row stride

__global__ __launch_bounds__(512, 1) void scan_kernel(
    const unsigned short* __restrict__ kn16, const unsigned short* __restrict__ qn16,
    const float* __restrict__ vz, const float* __restrict__ betab,
    float* __restrict__ O) {
  __shared__ unsigned short Kb[64 * LDB], Qb[64 * LDB], Ktb[64 * LDB];
  __shared__ unsigned short Wtb[64 * LDB], Wavgtb[64 * LDB];
  __shared__ unsigned short Pb[64 * LDB], Ptb[64 * LDB], P1b[64 * LDB];
  __shared__ unsigned short Ztb[64 * LDB], Utwb[64 * LDB], Sbf[64 * LDB];
  __shared__ float Vs[64 * LDV];
  __shared__ float etas[64];

  const int tid = threadIdx.x;
  const int bh = blockIdx.x;
  const int b = bh >> 4, h = bh & 15;
  const int wv = tid >> 6, lane = tid & 63;
  const int fr = lane & 15, og = lane >> 4;
  const int i0 = (wv >> 2) * 2, i1 = i0 + 1, j = wv & 3;
  const int gcol = j * 16 + fr;
  const int row0 = i0 * 16 + og * 4;
  const int row1 = i1 * 16 + og * 4;

  for (int t = tid; t < 64 * LDB; t += 512) { Wtb[t] = 0; Wavgtb[t] = 0; }

  const size_t base = ((size_t)b * 2048) * 1024 + (size_t)h * 64;
  const unsigned short* kp = kn16 + base;
  const unsigned short* qp = qn16 + base;
  const float* vp = vz + base;
  const float* etap = betab + (size_t)b * 2048 * 16 + h;
  float* Op = O + (size_t)bh * 2048 * 64;

  f32x4 Wt[2], Wav[2];
  Wt[0] = Wt[1] = Wav[0] = Wav[1] = (f32x4){0.f, 0.f, 0.f, 0.f};

  const int sr = tid >> 3, sc8 = (tid & 7) * 8;
  __syncthreads();

#pragma unroll 1
  for (int ic = 0; ic < 32; ++ic) {
    const float ts = (float)(ic * 64);

    // ---- A: stage K,Q bf16 (+K^T), V f32, etas ----
    {
      const size_t g = (size_t)(ic * 64 + sr) * 1024 + sc8;
      *(ushort4*)&Kb[sr * LDB + sc8] = *(const ushort4*)(kp + g);
      *(ushort4*)&Kb[sr * LDB + sc8 + 4] = *(const ushort4*)(kp + g + 4);
      *(ushort4*)&Qb[sr * LDB + sc8] = *(const ushort4*)(qp + g);
      *(ushort4*)&Qb[sr * LDB + sc8 + 4] = *(const ushort4*)(qp + g + 4);
      *(float4*)&Vs[sr * LDV + sc8] = *(const float4*)(vp + g);
      *(float4*)&Vs[sr * LDV + sc8 + 4] = *(const float4*)(vp + g + 4);
      unsigned short tv[8];
#pragma unroll
      for (int i = 0; i < 8; ++i)
        tv[i] = kp[(size_t)(ic * 64 + sc8 + i) * 1024 + sr];
      ushort4 t0v = {tv[0], tv[1], tv[2], tv[3]}, t1v = {tv[4], tv[5], tv[6], tv[7]};
      *(ushort4*)&Ktb[sr * LDB + sc8] = t0v;
      *(ushort4*)&Ktb[sr * LDB + sc8 + 4] = t1v;
      if (tid < 64) etas[tid] = etap[(size_t)(ic * 64 + tid) * 16];
    }
    __syncthreads();

    // ---- B: T = tril(eta KK^T,-1) -> P=-T ; RHS = V - eta*(K W) ----
    f32x4 Zacc[2], RHSs[2];
    {
      bf16x8 aK0[2], aK1[2], bK[2], bW[2];
#pragma unroll
      for (int t = 0; t < 2; ++t) {
        aK0[t] = *(const bf16x8*)&Kb[(i0 * 16 + fr) * LDB + t * 32 + og * 8];
        aK1[t] = *(const bf16x8*)&Kb[(i1 * 16 + fr) * LDB + t * 32 + og * 8];
        bK[t] = *(const bf16x8*)&Kb[(j * 16 + fr) * LDB + t * 32 + og * 8];
        bW[t] = *(const bf16x8*)&Wtb[(j * 16 + fr) * LDB + t * 32 + og * 8];
      }
      f32x4 accT0 = {0, 0, 0, 0}, accT1 = {0, 0, 0, 0};
      f32x4 accR0 = {0, 0, 0, 0}, accR1 = {0, 0, 0, 0};
#pragma unroll
      for (int t = 0; t < 2; ++t) {
        accT0 = MFMA(aK0[t], bK[t], accT0);
        accT1 = MFMA(aK1[t], bK[t], accT1);
        accR0 = MFMA(aK0[t], bW[t], accR0);
        accR1 = MFMA(aK1[t], bW[t], accR1);
      }
#pragma unroll
      for (int s = 0; s < 2; ++s) {
        const int rb = s ? row1 : row0;
        const f32x4 aT = s ? accT1 : accT0;
        const f32x4 aR = s ? accR1 : accR0;
        unsigned short us[4];
        float zv[4];
#pragma unroll
        for (int r = 0; r < 4; ++r) {
          const int grow = rb + r;
          const float eta = etas[grow];
          const float tvv = (gcol < grow) ? -eta * aT[r] : 0.f;
          us[r] = f2bf_rne(tvv);
          zv[r] = Vs[grow * LDV + gcol] - eta * aR[r];
          Pb[grow * LDB + gcol] = us[r];
          P1b[grow * LDB + gcol] = us[r];
        }
        ushort4 pp = {us[0], us[1], us[2], us[3]};
        *(ushort4*)&Ptb[gcol * LDB + rb] = pp;
        ushort4 zp = {f2bf_rne(zv[0]), f2bf_rne(zv[1]), f2bf_rne(zv[2]), f2bf_rne(zv[3])};
        *(ushort4*)&Ztb[gcol * LDB + rb] = zp;
        Zacc[s] = (f32x4){zv[0], zv[1], zv[2], zv[3]};
        RHSs[s] = Zacc[s];
      }
    }
    __syncthreads();

    // ---- C: doubling chain Z <- (I+P^{2^k}) Z, square P ----
    for (int k = 0; k < 6; ++k) {
      bf16x8 aP0[2], aP1[2], bZ[2];
#pragma unroll
      for (int t = 0; t < 2; ++t) {
        aP0[t] = *(const bf16x8*)&Pb[(i0 * 16 + fr) * LDB + t * 32 + og * 8];
        aP1[t] = *(const bf16x8*)&Pb[(i1 * 16 + fr) * LDB + t * 32 + og * 8];
        bZ[t] = *(const bf16x8*)&Ztb[(j * 16 + fr) * LDB + t * 32 + og * 8];
      }
      f32x4 sq0 = {0, 0, 0, 0}, sq1 = {0, 0, 0, 0};
      if (k < 5) {
#pragma unroll
        for (int t = 0; t < 2; ++t) {
          bf16x8 bPt = *(const bf16x8*)&Ptb[(j * 16 + fr) * LDB + t * 32 + og * 8];
          sq0 = MFMA(aP0[t], bPt, sq0);
          sq1 = MFMA(aP1[t], bPt, sq1);
        }
      }
#pragma unroll
      for (int t = 0; t < 2; ++t) {
        Zacc[0] = MFMA(aP0[t], bZ[t], Zacc[0]);
        Zacc[1] = MFMA(aP1[t], bZ[t], Zacc[1]);
      }
      __syncthreads();
#pragma unroll
      for (int s = 0; s < 2; ++s) {
        const int rb = s ? row1 : row0;
        const f32x4 zz = Zacc[s];
        ushort4 zp = {f2bf_rne(zz[0]), f2bf_rne(zz[1]), f2bf_rne(zz[2]), f2bf_rne(zz[3])};
        *(ushort4*)&Ztb[gcol * LDB + rb] = zp;
        if (k < 5) {
          const f32x4 sv = s ? sq1 : sq0;
          unsigned short u0 = f2bf_rne(sv[0]), u1 = f2bf_rne(sv[1]);
          unsigned short u2 = f2bf_rne(sv[2]), u3 = f2bf_rne(sv[3]);
          Pb[(rb + 0) * LDB + gcol] = u0;
          Pb[(rb + 1) * LDB + gcol] = u1;
          Pb[(rb + 2) * LDB + gcol] = u2;
          Pb[(rb + 3) * LDB + gcol] = u3;
          ushort4 pp = {u0, u1, u2, u3};
          *(ushort4*)&Ptb[gcol * LDB + rb] = pp;
        }
      }
      __syncthreads();
    }

    // ---- refinement: R = RHS - U + P1*U ; U += R + P1*R ; final U stores ----
    {
      bf16x8 a0[2], a1[2];
#pragma unroll
      for (int t = 0; t < 2; ++t) {
        a0[t] = *(const bf16x8*)&P1b[(i0 * 16 + fr) * LDB + t * 32 + og * 8];
        a1[t] = *(const bf16x8*)&P1b[(i1 * 16 + fr) * LDB + t * 32 + og * 8];
      }
      f32x4 R0 = RHSs[0] - Zacc[0];
      f32x4 R1 = RHSs[1] - Zacc[1];
#pragma unroll
      for (int t = 0; t < 2; ++t) {
        bf16x8 bU = *(const bf16x8*)&Ztb[(j * 16 + fr) * LDB + t * 32 + og * 8];
        R0 = MFMA(a0[t], bU, R0);
        R1 = MFMA(a1[t], bU, R1);
      }
      ushort4 r0p = {f2bf_rne(R0[0]), f2bf_rne(R0[1]), f2bf_rne(R0[2]), f2bf_rne(R0[3])};
      ushort4 r1p = {f2bf_rne(R1[0]), f2bf_rne(R1[1]), f2bf_rne(R1[2]), f2bf_rne(R1[3])};
      *(ushort4*)&Sbf[gcol * LDB + row0] = r0p;
      *(ushort4*)&Sbf[gcol * LDB + row1] = r1p;
      __syncthreads();
      f32x4 dU0 = R0, dU1 = R1;
#pragma unroll
      for (int t = 0; t < 2; ++t) {
        bf16x8 bR = *(const bf16x8*)&Sbf[(j * 16 + fr) * LDB + t * 32 + og * 8];
        dU0 = MFMA(a0[t], bR, dU0);
        dU1 = MFMA(a1[t], bR, dU1);
      }
      Zacc[0] += dU0;
      Zacc[1] += dU1;
      const float invden = 1.f / (0.5f * (ts + 65.f) * (ts + 64.f));
#pragma unroll
      for (int s = 0; s < 2; ++s) {
        const int rb = s ? row1 : row0;
        const f32x4 uu = Zacc[s];
        ushort4 up = {f2bf_rne(uu[0]), f2bf_rne(uu[1]), f2bf_rne(uu[2]), f2bf_rne(uu[3])};
        *(ushort4*)&Ztb[gcol * LDB + rb] = up;
        unsigned short uw[4];
#pragma unroll
        for (int r = 0; r < 4; ++r) {
          const float rr = (float)(rb + r);
          const float wr = (ts * (64.f - rr) + (rr + 1.f) + 2080.f -
                            0.5f * (rr + 1.f) * (rr + 2.f)) * invden;
          uw[r] = f2bf_rne(uu[r] * wr);
        }
        ushort4 uwp = {uw[0], uw[1], uw[2], uw[3]};
        *(ushort4*)&Utwb[gcol * LDB + rb] = uwp;
      }
      __syncthreads();
    }

    // ---- E: S = Tmat.*(QK^T) ; Oacc = a*QWavg + c*QW ----
    f32x4 Oacc[2];
    {
      bf16x8 aQ0[2], aQ1[2], bKj[2], bWt2[2], bWa2[2];
#pragma unroll
      for (int t = 0; t < 2; ++t) {
        aQ0[t] = *(const bf16x8*)&Qb[(i0 * 16 + fr) * LDB + t * 32 + og * 8];
        aQ1[t] = *(const bf16x8*)&Qb[(i1 * 16 + fr) * LDB + t * 32 + og * 8];
        bKj[t] = *(const bf16x8*)&Kb[(j * 16 + fr) * LDB + t * 32 + og * 8];
        bWt2[t] = *(const bf16x8*)&Wtb[(j * 16 + fr) * LDB + t * 32 + og * 8];
        bWa2[t] = *(const bf16x8*)&Wavgtb[(j * 16 + fr) * LDB + t * 32 + og * 8];
      }
      f32x4 aS0 = {0, 0, 0, 0}, aS1 = {0, 0, 0, 0};
      f32x4 aA0 = {0, 0, 0, 0}, aA1 = {0, 0, 0, 0};
      f32x4 aC0 = {0, 0, 0, 0}, aC1 = {0, 0, 0, 0};
#pragma unroll
      for (int t = 0; t < 2; ++t) {
        aS0 = MFMA(aQ0[t], bKj[t], aS0);
        aS1 = MFMA(aQ1[t], bKj[t], aS1);
        aA0 = MFMA(aQ0[t], bWa2[t], aA0);
        aA1 = MFMA(aQ1[t], bWa2[t], aA1);
        aC0 = MFMA(aQ0[t], bWt2[t], aC0);
        aC1 = MFMA(aQ1[t], bWt2[t], aC1);
      }
      const float tri0 = 0.5f * ts * (ts + 1.f);
      const float jidx = gcol * ts + 0.5f * gcol * (gcol + 1.f);
#pragma unroll
      for (int s = 0; s < 2; ++s) {
        const int rb = s ? row1 : row0;
        const f32x4 sS = s ? aS1 : aS0;
        const f32x4 sA = s ? aA1 : aA0;
        const f32x4 sC = s ? aC1 : aC0;
        f32x4 oo;
#pragma unroll
        for (int r = 0; r < 4; ++r) {
          const float grow = (float)(rb + r);
          const float csr = (grow + 1.f) * ts + 0.5f * (grow + 1.f) * (grow + 2.f);
          const float rinv = 1.f / (tri0 + csr);
          const float av = tri0 * rinv;
          oo[r] = av * sA[r] + (1.f - av) * sC[r];
          const float svv = (csr >= jidx) ? (csr - jidx) * rinv * sS[r] : 0.f;
          Sbf[(rb + r) * LDB + gcol] = f2bf_rne(svv);
        }
        Oacc[s] = oo;
      }
    }
    __syncthreads();

    // ---- F: O += S U ; global store ----
    {
      bf16x8 aS0[2], aS1[2], bU2[2];
#pragma unroll
      for (int t = 0; t < 2; ++t) {
        aS0[t] = *(const bf16x8*)&Sbf[(i0 * 16 + fr) * LDB + t * 32 + og * 8];
        aS1[t] = *(const bf16x8*)&Sbf[(i1 * 16 + fr) * LDB + t * 32 + og * 8];
        bU2[t] = *(const bf16x8*)&Ztb[(j * 16 + fr) * LDB + t * 32 + og * 8];
      }
#pragma unroll
      for (int t = 0; t < 2; ++t) {
        Oacc[0] = MFMA(aS0[t], bU2[t], Oacc[0]);
        Oacc[1] = MFMA(aS1[t], bU2[t], Oacc[1]);
      }
#pragma unroll
      for (int s = 0; s < 2; ++s) {
        const int rb = s ? row1 : row0;
#pragma unroll
        for (int r = 0; r < 4; ++r)
          Op[(size_t)(ic * 64 + rb + r) * 64 + gcol] = Oacc[s][r];
      }
    }

    // ---- G: Wavg = cc1*Wavg + cc2*W + Utw^T K ; W += U^T K ; refresh LDS ----
    {
      bf16x8 aU0[2], aU1[2], aW0[2], aW1[2], bKt2[2];
#pragma unroll
      for (int t = 0; t < 2; ++t) {
        aU0[t] = *(const bf16x8*)&Ztb[(i0 * 16 + fr) * LDB + t * 32 + og * 8];
        aU1[t] = *(const bf16x8*)&Ztb[(i1 * 16 + fr) * LDB + t * 32 + og * 8];
        aW0[t] = *(const bf16x8*)&Utwb[(i0 * 16 + fr) * LDB + t * 32 + og * 8];
        aW1[t] = *(const bf16x8*)&Utwb[(i1 * 16 + fr) * LDB + t * 32 + og * 8];
        bKt2[t] = *(const bf16x8*)&Ktb[(j * 16 + fr) * LDB + t * 32 + og * 8];
      }
      const float den = (ts + 64.f) * (ts + 65.f);
      const float cc1 = ts * (ts + 1.f) / den;
      const float cc2 = 64.f * (2.f * ts + 65.f) / den;
      f32x4 wn0 = cc1 * Wav[0] + cc2 * Wt[0];
      f32x4 wn1 = cc1 * Wav[1] + cc2 * Wt[1];
#pragma unroll
      for (int t = 0; t < 2; ++t) {
        wn0 = MFMA(aW0[t], bKt2[t], wn0);
        wn1 = MFMA(aW1[t], bKt2[t], wn1);
        Wt[0] = MFMA(aU0[t], bKt2[t], Wt[0]);
        Wt[1] = MFMA(aU1[t], bKt2[t], Wt[1]);
      }
      Wav[0] = wn0;
      Wav[1] = wn1;
#pragma unroll
      for (int s = 0; s < 2; ++s) {
        const int rb = s ? row1 : row0;
        const f32x4 wtv = Wt[s];
        const f32x4 wav2 = Wav[s];
#pragma unroll
        for (int r = 0; r < 4; ++r) {
          Wtb[(rb + r) * LDB + gcol] = f2bf_rne(wtv[r]);
          Wavgtb[(rb + r) * LDB + gcol] = f2bf_rne(wav2[r]);
        }
      }
    }
    __syncthreads();
  }
}

// ---------------------------------------------------------------------------
// RMS norm over head dim + relayout (B,H,L,D) -> (B,L,Dm), bf16 output
// ---------------------------------------------------------------------------
__global__ __launch_bounds__(256) void rms_kernel(const float* __restrict__ O,
                                                  const float* __restrict__ rmsw,
                                                  unsigned short* __restrict__ out16) {
  const int m = blockIdx.x;  // b*2048 + l
  const int b = m >> 11, l = m & 2047;
  const int wv = threadIdx.x >> 6, lane = threadIdx.x & 63;
  const float rw = rmsw[lane];
#pragma unroll
  for (int hh = 0; hh < 4; ++hh) {
    const int h = wv * 4 + hh;
    const float v = O[(((size_t)(b * 16 + h)) * 2048 + l) * 64 + lane];
    float ss = v * v;
    ss += __shfl_xor(ss, 1); ss += __shfl_xor(ss, 2); ss += __shfl_xor(ss, 4);
    ss += __shfl_xor(ss, 8); ss += __shfl_xor(ss, 16); ss += __shfl_xor(ss, 32);
    const float sc = rsqrtf(ss * (1.f / 64.f) + 1e-6f);
    out16[(size_t)m * 1024 + h * 64 + lane] = f2bf_rne(v * sc * rw);
  }
}

// ---------------------------------------------------------------------------
extern "C" void kernel_launch(void* const* d_in, const int* in_sizes, int n_in,
                              void* d_out, int out_size, void* d_ws, size_t ws_size,
                              hipStream_t stream) {
  (void)in_sizes; (void)n_in; (void)out_size; (void)ws_size;
  const float* x     = (const float*)d_in[0];
  const float* Wk    = (const float*)d_in[1];
  const float* bk    = (const float*)d_in[2];
  const float* Wq    = (const float*)d_in[3];
  const float* bq    = (const float*)d_in[4];
  const float* Wv    = (const float*)d_in[5];
  const float* bv    = (const float*)d_in[6];
  const float* Wbeta = (const float*)d_in[7];
  const float* bbeta = (const float*)d_in[8];
  const float* convk = (const float*)d_in[9];
  const float* convq = (const float*)d_in[10];
  const float* convv = (const float*)d_in[11];
  const float* rmsw  = (const float*)d_in[12];
  const float* Wout  = (const float*)d_in[13];
  const float* bout  = (const float*)d_in[14];
  float* out = (float*)d_out;
  float* ws = (float*)d_ws;

  const size_t SZ = (size_t)8192 * 1024;
  float* kpre = ws;            // dead after prep -> Obuf
  float* qpre = ws + SZ;       // dead after prep -> normed16
  float* vpre = ws + 2 * SZ;
  float* betab = ws + 3 * SZ;                                      // 131072 f32
  unsigned short* x16 = (unsigned short*)(ws + 3 * SZ + 131072);   // SZ bf16
  unsigned short* wk16 = x16 + SZ;
  unsigned short* wq16 = wk16 + 1048576;
  unsigned short* wv16 = wq16 + 1048576;
  unsigned short* wo16 = wv16 + 1048576;
  unsigned short* kn16 = wo16 + 1048576;                           // SZ bf16
  unsigned short* qn16 = kn16 + SZ;                                // SZ bf16
  float* vzb = out;            // d_out doubles as eta*silu(v) scratch
  float* Obuf = kpre;
  unsigned short* normed16 = (unsigned short*)qpre;

  dim3 blk(256);
  hipLaunchKernelGGL(cast_bf16_kernel, dim3(8192), blk, 0, stream, x, x16, (int)(SZ / 4));
  hipLaunchKernelGGL(cast_bf16_kernel, dim3(1024), blk, 0, stream, Wk, wk16, 262144);
  hipLaunchKernelGGL(cast_bf16_kernel, dim3(1024), blk, 0, stream, Wq, wq16, 262144);
  hipLaunchKernelGGL(cast_bf16_kernel, dim3(1024), blk, 0, stream, Wv, wv16, 262144);
  hipLaunchKernelGGL(cast_bf16_kernel, dim3(1024), blk, 0, stream, Wout, wo16, 262144);

  dim3 g(64, 8);
  hipLaunchKernelGGL(gemm_bf16_nt, g, blk, 0, stream, x16, wk16, bk, kpre, 8192, 1024, 1024);
  hipLaunchKernelGGL(gemm_bf16_nt, g, blk, 0, stream, x16, wq16, bq, qpre, 8192, 1024, 1024);
  hipLaunchKernelGGL(gemm_bf16_nt, g, blk, 0, stream, x16, wv16, bv, vpre, 8192, 1024, 1024);
  hipLaunchKernelGGL(beta_kernel, dim3(8192), blk, 0, stream, x, Wbeta, bbeta, betab);
  hipLaunchKernelGGL(prep_kernel, dim3(8192), blk, 0, stream, kpre, qpre, vpre, betab,
                     convk, convq, convv, kn16, qn16, vzb);
  hipLaunchKernelGGL(scan_kernel, dim3(64), dim3(512), 0, stream, kn16, qn16, vzb,
                     betab, Obuf);
  hipLaunchKernelGGL(rms_kernel, dim3(8192), blk, 0, stream, Obuf, rmsw, normed16);
  hipLaunchKernelGGL(gemm_bf16_nt, g, blk, 0, stream, normed16, wo16, bout, out,
                     8192, 1024, 1024);
}

// Round 6
// 586.064 us; speedup vs baseline: 3.4033x; 1.0690x over previous
//
#include <hip/hip_runtime.h>

typedef __attribute__((ext_vector_type(8))) short bf16x8;
typedef __attribute__((ext_vector_type(4))) float f32x4;

#define MFMA(a, b, c) __builtin_amdgcn_mfma_f32_16x16x32_bf16((a), (b), (c), 0, 0, 0)

__device__ inline unsigned short f2bf_rne(float f) {
  unsigned int u = __float_as_uint(f);
  u += 0x7FFFu + ((u >> 16) & 1u);
  return (unsigned short)(u >> 16);
}

// ---------------------------------------------------------------------------
// cast f32 -> bf16 (RNE), vectorized x4
// ---------------------------------------------------------------------------
__global__ __launch_bounds__(256) void cast_bf16_kernel(const float* __restrict__ in,
                                                        unsigned short* __restrict__ out,
                                                        int n4) {
  const int i = blockIdx.x * 256 + threadIdx.x;
  if (i >= n4) return;
  const float4 v = ((const float4*)in)[i];
  ushort4 o;
  o.x = f2bf_rne(v.x); o.y = f2bf_rne(v.y); o.z = f2bf_rne(v.z); o.w = f2bf_rne(v.w);
  ((ushort4*)out)[i] = o;
}

// ---------------------------------------------------------------------------
// concat 3 bias vectors (1024 each) into one 3072 buffer
// ---------------------------------------------------------------------------
__global__ __launch_bounds__(256) void concat_bias_kernel(const float* __restrict__ bk,
                                                          const float* __restrict__ bq,
                                                          const float* __restrict__ bv,
                                                          float* __restrict__ b3) {
  const int i = blockIdx.x * 256 + threadIdx.x;
  if (i < 1024) b3[i] = bk[i];
  else if (i < 2048) b3[i] = bq[i - 1024];
  else if (i < 3072) b3[i] = bv[i - 2048];
}

// ---------------------------------------------------------------------------
// bf16 MFMA GEMM (NT): C[m][n] = bias[n] + sum_k A[m][k]*Bw[n][k]
// 128x128 tile, BK=32, 256 threads (4 waves), global_load_lds staging.
// ---------------------------------------------------------------------------
__global__ __launch_bounds__(256) void gemm_bf16_nt(
    const unsigned short* __restrict__ A, const unsigned short* __restrict__ Bw,
    const float* __restrict__ bias, float* __restrict__ C, int M, int N, int K) {
  __shared__ unsigned short Asl[128 * 32];
  __shared__ unsigned short Bsl[128 * 32];
  const int tid = threadIdx.x;
  const int lane = tid & 63, w = tid >> 6;
  const int bm = blockIdx.x * 128, bn = blockIdx.y * 128;
  const int wr = (w >> 1) * 64, wc = (w & 1) * 64;

  const int li0 = tid, li1 = tid + 256;
  const int ar0 = li0 >> 2, ak0 = (li0 & 3) * 8;
  const int ar1 = li1 >> 2, ak1 = (li1 & 3) * 8;
  const unsigned short* gA0 = A + (size_t)(bm + ar0) * K + ak0;
  const unsigned short* gA1 = A + (size_t)(bm + ar1) * K + ak1;
  const unsigned short* gB0 = Bw + (size_t)(bn + ar0) * K + ak0;
  const unsigned short* gB1 = Bw + (size_t)(bn + ar1) * K + ak1;
  unsigned short* lA0 = &Asl[(size_t)(w * 64) * 8];
  unsigned short* lA1 = &Asl[(size_t)(w * 64 + 256) * 8];
  unsigned short* lB0 = &Bsl[(size_t)(w * 64) * 8];
  unsigned short* lB1 = &Bsl[(size_t)(w * 64 + 256) * 8];

  f32x4 acc[4][4];
#pragma unroll
  for (int i = 0; i < 4; ++i)
#pragma unroll
    for (int j = 0; j < 4; ++j) acc[i][j] = (f32x4){0.f, 0.f, 0.f, 0.f};

  const int fr = lane & 15, kg = lane >> 4;

  for (int k0 = 0; k0 < K; k0 += 32) {
    __syncthreads();
    __builtin_amdgcn_global_load_lds((const __attribute__((address_space(1))) unsigned int*)(gA0 + k0),
                                     (__attribute__((address_space(3))) unsigned int*)lA0, 16, 0, 0);
    __builtin_amdgcn_global_load_lds((const __attribute__((address_space(1))) unsigned int*)(gA1 + k0),
                                     (__attribute__((address_space(3))) unsigned int*)lA1, 16, 0, 0);
    __builtin_amdgcn_global_load_lds((const __attribute__((address_space(1))) unsigned int*)(gB0 + k0),
                                     (__attribute__((address_space(3))) unsigned int*)lB0, 16, 0, 0);
    __builtin_amdgcn_global_load_lds((const __attribute__((address_space(1))) unsigned int*)(gB1 + k0),
                                     (__attribute__((address_space(3))) unsigned int*)lB1, 16, 0, 0);
    __syncthreads();

    bf16x8 af[4], bfr[4];
#pragma unroll
    for (int i = 0; i < 4; ++i) {
      af[i] = *(const bf16x8*)&Asl[(size_t)(wr + i * 16 + fr) * 32 + kg * 8];
      bfr[i] = *(const bf16x8*)&Bsl[(size_t)(wc + i * 16 + fr) * 32 + kg * 8];
    }
#pragma unroll
    for (int i = 0; i < 4; ++i)
#pragma unroll
      for (int j = 0; j < 4; ++j)
        acc[i][j] = MFMA(af[i], bfr[j], acc[i][j]);
  }

  const int og = lane >> 4;
#pragma unroll
  for (int j = 0; j < 4; ++j) {
    const int col = bn + wc + j * 16 + fr;
    const float bs = bias[col];
#pragma unroll
    for (int i = 0; i < 4; ++i) {
#pragma unroll
      for (int r = 0; r < 4; ++r) {
        const int row = bm + wr + i * 16 + og * 4 + r;
        C[(size_t)row * N + col] = acc[i][j][r] + bs;
      }
    }
  }
}

// ---------------------------------------------------------------------------
// beta[m][h] = sigmoid( sum_k x[m][k]*Wb[h][k] + bb[h] )
// ---------------------------------------------------------------------------
__global__ __launch_bounds__(256) void beta_kernel(const float* __restrict__ x,
                                                   const float* __restrict__ Wb,
                                                   const float* __restrict__ bb,
                                                   float* __restrict__ beta) {
  const int m = blockIdx.x;
  const int tid = threadIdx.x;
  const int h = tid >> 4;
  const int l = tid & 15;
  const float4* x4 = (const float4*)(x + (size_t)m * 1024);
  const float4* w4 = (const float4*)(Wb + (size_t)h * 1024);
  float acc = 0.f;
#pragma unroll 4
  for (int jj = 0; jj < 16; ++jj) {
    float4 xv = x4[l + 16 * jj];
    float4 wv = w4[l + 16 * jj];
    acc += xv.x * wv.x + xv.y * wv.y + xv.z * wv.z + xv.w * wv.w;
  }
  acc += __shfl_xor(acc, 1);
  acc += __shfl_xor(acc, 2);
  acc += __shfl_xor(acc, 4);
  acc += __shfl_xor(acc, 8);
  if (l == 0) {
    const float s = acc + bb[h];
    beta[(size_t)m * 16 + h] = 1.f / (1.f + expf(-s));
  }
}

// ---------------------------------------------------------------------------
// prep: conv + norms + eta*silu, reading fused qkv (stride 3072).
// outputs bf16 k,q and f32 eta*silu(v)
// ---------------------------------------------------------------------------
__global__ __launch_bounds__(256) void prep_kernel(
    const float* __restrict__ qkv, const float* __restrict__ betab,
    const float* __restrict__ convk, const float* __restrict__ convq,
    const float* __restrict__ convv,
    unsigned short* __restrict__ kn16, unsigned short* __restrict__ qn16,
    float* __restrict__ vz) {
  const int m = blockIdx.x;          // b*2048 + l
  const int l = m & 2047;
  const int lane = threadIdx.x & 63;
  const int wvi = threadIdx.x >> 6;  // 0..3
#pragma unroll
  for (int s = 0; s < 4; ++s) {
    const int h = 4 * s + wvi;
    const int c = h * 64 + lane;
    const float4 wk4 = *(const float4*)(convk + (size_t)c * 4);
    const float4 wq4 = *(const float4*)(convq + (size_t)c * 4);
    const float4 wv4 = *(const float4*)(convv + (size_t)c * 4);
    const float wk[4] = {wk4.x, wk4.y, wk4.z, wk4.w};
    const float wq[4] = {wq4.x, wq4.y, wq4.z, wq4.w};
    const float wvv[4] = {wv4.x, wv4.y, wv4.z, wv4.w};
    float kc = 0.f, qc = 0.f, vc = 0.f;
#pragma unroll
    for (int j = 0; j < 4; ++j) {
      const int lj = l - 3 + j;
      if (lj >= 0) {
        const size_t rb = (size_t)(m - l + lj) * 3072 + c;
        kc += wk[j] * qkv[rb];
        qc += wq[j] * qkv[rb + 1024];
        vc += wvv[j] * qkv[rb + 2048];
      }
    }
    float ssk = kc * kc, ssq = qc * qc;
    ssk += __shfl_xor(ssk, 1); ssq += __shfl_xor(ssq, 1);
    ssk += __shfl_xor(ssk, 2); ssq += __shfl_xor(ssq, 2);
    ssk += __shfl_xor(ssk, 4); ssq += __shfl_xor(ssq, 4);
    ssk += __shfl_xor(ssk, 8); ssq += __shfl_xor(ssq, 8);
    ssk += __shfl_xor(ssk, 16); ssq += __shfl_xor(ssq, 16);
    ssk += __shfl_xor(ssk, 32); ssq += __shfl_xor(ssq, 32);
    const float eta = betab[(size_t)m * 16 + h];
    const size_t o = (size_t)m * 1024 + c;
    kn16[o] = f2bf_rne(kc / (sqrtf(ssk) + 1e-6f));
    qn16[o] = f2bf_rne(qc / (sqrtf(ssq) + 1e-6f));
    vz[o] = eta * vc / (1.f + expf(-vc));
  }
}

// ---------------------------------------------------------------------------
// MFMA delta-rule scan, 11 barriers/chunk: ping-pong doubling chain (1 barrier
// per step), refine-end merged with S-compute via dead-buffer retargeting.
// ---------------------------------------------------------------------------
#define LDB 72  // bf16 row stride
#define LDV 68  // f32 row stride

__global__ __launch_bounds__(512, 1) void scan_kernel(
    const unsigned short* __restrict__ kn16, const unsigned short* __restrict__ qn16,
    const float* __restrict__ vz, const float* __restrict__ betab,
    float* __restrict__ O) {
  __shared__ unsigned short Kb[64 * LDB], Qb[64 * LDB], Ktb[64 * LDB];
  __shared__ unsigned short Wtb[64 * LDB], Wavgtb[64 * LDB];
  __shared__ unsigned short Pb[2][64 * LDB], Ptb[2][64 * LDB], Ztb[2][64 * LDB];
  __shared__ unsigned short P1b[64 * LDB], Utwb[64 * LDB];
  __shared__ float Vs[64 * LDV];
  __shared__ float etas[64];

  const int tid = threadIdx.x;
  const int bh = blockIdx.x;
  const int b = bh >> 4, h = bh & 15;
  const int wv = tid >> 6, lane = tid & 63;
  const int fr = lane & 15, og = lane >> 4;
  const int i0 = (wv >> 2) * 2, i1 = i0 + 1, j = wv & 3;
  const int gcol = j * 16 + fr;
  const int row0 = i0 * 16 + og * 4;
  const int row1 = i1 * 16 + og * 4;

  for (int t = tid; t < 64 * LDB; t += 512) { Wtb[t] = 0; Wavgtb[t] = 0; }

  const size_t base = ((size_t)b * 2048) * 1024 + (size_t)h * 64;
  const unsigned short* kp = kn16 + base;
  const unsigned short* qp = qn16 + base;
  const float* vp = vz + base;
  const float* etap = betab + (size_t)b * 2048 * 16 + h;
  float* Op = O + (size_t)bh * 2048 * 64;

  f32x4 Wt[2], Wav[2];
  Wt[0] = Wt[1] = Wav[0] = Wav[1] = (f32x4){0.f, 0.f, 0.f, 0.f};

  const int sr = tid >> 3, sc8 = (tid & 7) * 8;
  __syncthreads();

#pragma unroll 1
  for (int ic = 0; ic < 32; ++ic) {
    const float ts = (float)(ic * 64);

    // ---- A: stage K,Q bf16 (+K^T), V f32, etas ---- (barrier 1)
    {
      const size_t g = (size_t)(ic * 64 + sr) * 1024 + sc8;
      *(ushort4*)&Kb[sr * LDB + sc8] = *(const ushort4*)(kp + g);
      *(ushort4*)&Kb[sr * LDB + sc8 + 4] = *(const ushort4*)(kp + g + 4);
      *(ushort4*)&Qb[sr * LDB + sc8] = *(const ushort4*)(qp + g);
      *(ushort4*)&Qb[sr * LDB + sc8 + 4] = *(const ushort4*)(qp + g + 4);
      *(float4*)&Vs[sr * LDV + sc8] = *(const float4*)(vp + g);
      *(float4*)&Vs[sr * LDV + sc8 + 4] = *(const float4*)(vp + g + 4);
      unsigned short tv[8];
#pragma unroll
      for (int i = 0; i < 8; ++i)
        tv[i] = kp[(size_t)(ic * 64 + sc8 + i) * 1024 + sr];
      ushort4 t0v = {tv[0], tv[1], tv[2], tv[3]}, t1v = {tv[4], tv[5], tv[6], tv[7]};
      *(ushort4*)&Ktb[sr * LDB + sc8] = t0v;
      *(ushort4*)&Ktb[sr * LDB + sc8 + 4] = t1v;
      if (tid < 64) etas[tid] = etap[(size_t)(ic * 64 + tid) * 16];
    }
    __syncthreads();

    // ---- B: T = tril(eta KK^T,-1) -> P=-T ; RHS = V - eta*(K W) ---- (barrier 2)
    f32x4 Zacc[2], RHSs[2];
    {
      bf16x8 aK0[2], aK1[2], bK[2], bW[2];
#pragma unroll
      for (int t = 0; t < 2; ++t) {
        aK0[t] = *(const bf16x8*)&Kb[(i0 * 16 + fr) * LDB + t * 32 + og * 8];
        aK1[t] = *(const bf16x8*)&Kb[(i1 * 16 + fr) * LDB + t * 32 + og * 8];
        bK[t] = *(const bf16x8*)&Kb[(j * 16 + fr) * LDB + t * 32 + og * 8];
        bW[t] = *(const bf16x8*)&Wtb[(j * 16 + fr) * LDB + t * 32 + og * 8];
      }
      f32x4 accT0 = {0, 0, 0, 0}, accT1 = {0, 0, 0, 0};
      f32x4 accR0 = {0, 0, 0, 0}, accR1 = {0, 0, 0, 0};
#pragma unroll
      for (int t = 0; t < 2; ++t) {
        accT0 = MFMA(aK0[t], bK[t], accT0);
        accT1 = MFMA(aK1[t], bK[t], accT1);
        accR0 = MFMA(aK0[t], bW[t], accR0);
        accR1 = MFMA(aK1[t], bW[t], accR1);
      }
#pragma unroll
      for (int s = 0; s < 2; ++s) {
        const int rb = s ? row1 : row0;
        const f32x4 aT = s ? accT1 : accT0;
        const f32x4 aR = s ? accR1 : accR0;
        unsigned short us[4];
        float zv[4];
#pragma unroll
        for (int r = 0; r < 4; ++r) {
          const int grow = rb + r;
          const float eta = etas[grow];
          const float tvv = (gcol < grow) ? -eta * aT[r] : 0.f;
          us[r] = f2bf_rne(tvv);
          zv[r] = Vs[grow * LDV + gcol] - eta * aR[r];
          Pb[0][grow * LDB + gcol] = us[r];
          P1b[grow * LDB + gcol] = us[r];
        }
        ushort4 pp = {us[0], us[1], us[2], us[3]};
        *(ushort4*)&Ptb[0][gcol * LDB + rb] = pp;
        ushort4 zp = {f2bf_rne(zv[0]), f2bf_rne(zv[1]), f2bf_rne(zv[2]), f2bf_rne(zv[3])};
        *(ushort4*)&Ztb[0][gcol * LDB + rb] = zp;
        Zacc[s] = (f32x4){zv[0], zv[1], zv[2], zv[3]};
        RHSs[s] = Zacc[s];
      }
    }
    __syncthreads();

    // ---- C: doubling chain, ping-pong, 1 barrier/step ---- (barriers 3-8)
#pragma unroll
    for (int k = 0; k < 6; ++k) {
      const int cur = k & 1, nxt = cur ^ 1;
      bf16x8 aP0[2], aP1[2], bZ[2];
#pragma unroll
      for (int t = 0; t < 2; ++t) {
        aP0[t] = *(const bf16x8*)&Pb[cur][(i0 * 16 + fr) * LDB + t * 32 + og * 8];
        aP1[t] = *(const bf16x8*)&Pb[cur][(i1 * 16 + fr) * LDB + t * 32 + og * 8];
        bZ[t] = *(const bf16x8*)&Ztb[cur][(j * 16 + fr) * LDB + t * 32 + og * 8];
      }
      f32x4 sq0 = {0, 0, 0, 0}, sq1 = {0, 0, 0, 0};
      if (k < 5) {
#pragma unroll
        for (int t = 0; t < 2; ++t) {
          bf16x8 bPt = *(const bf16x8*)&Ptb[cur][(j * 16 + fr) * LDB + t * 32 + og * 8];
          sq0 = MFMA(aP0[t], bPt, sq0);
          sq1 = MFMA(aP1[t], bPt, sq1);
        }
      }
#pragma unroll
      for (int t = 0; t < 2; ++t) {
        Zacc[0] = MFMA(aP0[t], bZ[t], Zacc[0]);
        Zacc[1] = MFMA(aP1[t], bZ[t], Zacc[1]);
      }
#pragma unroll
      for (int s = 0; s < 2; ++s) {
        const int rb = s ? row1 : row0;
        const f32x4 zz = Zacc[s];
        ushort4 zp = {f2bf_rne(zz[0]), f2bf_rne(zz[1]), f2bf_rne(zz[2]), f2bf_rne(zz[3])};
        *(ushort4*)&Ztb[nxt][gcol * LDB + rb] = zp;
        if (k < 5) {
          const f32x4 sv = s ? sq1 : sq0;
          unsigned short u0 = f2bf_rne(sv[0]), u1 = f2bf_rne(sv[1]);
          unsigned short u2 = f2bf_rne(sv[2]), u3 = f2bf_rne(sv[3]);
          Pb[nxt][(rb + 0) * LDB + gcol] = u0;
          Pb[nxt][(rb + 1) * LDB + gcol] = u1;
          Pb[nxt][(rb + 2) * LDB + gcol] = u2;
          Pb[nxt][(rb + 3) * LDB + gcol] = u3;
          ushort4 pp = {u0, u1, u2, u3};
          *(ushort4*)&Ptb[nxt][gcol * LDB + rb] = pp;
        }
      }
      __syncthreads();
    }
    // final U: bf16 transposed in Ztb[0], f32 in Zacc

    // ---- D1: R = RHS - U + P1*U ; R^T -> Pb[1] (dead) ---- (barrier 9)
    bf16x8 a0[2], a1[2];
    {
#pragma unroll
      for (int t = 0; t < 2; ++t) {
        a0[t] = *(const bf16x8*)&P1b[(i0 * 16 + fr) * LDB + t * 32 + og * 8];
        a1[t] = *(const bf16x8*)&P1b[(i1 * 16 + fr) * LDB + t * 32 + og * 8];
      }
      f32x4 R0 = RHSs[0] - Zacc[0];
      f32x4 R1 = RHSs[1] - Zacc[1];
#pragma unroll
      for (int t = 0; t < 2; ++t) {
        bf16x8 bU = *(const bf16x8*)&Ztb[0][(j * 16 + fr) * LDB + t * 32 + og * 8];
        R0 = MFMA(a0[t], bU, R0);
        R1 = MFMA(a1[t], bU, R1);
      }
      ushort4 r0p = {f2bf_rne(R0[0]), f2bf_rne(R0[1]), f2bf_rne(R0[2]), f2bf_rne(R0[3])};
      ushort4 r1p = {f2bf_rne(R1[0]), f2bf_rne(R1[1]), f2bf_rne(R1[2]), f2bf_rne(R1[3])};
      *(ushort4*)&Pb[1][gcol * LDB + row0] = r0p;
      *(ushort4*)&Pb[1][gcol * LDB + row1] = r1p;
      RHSs[0] = R0;  // carry R f32
      RHSs[1] = R1;
    }
    __syncthreads();

    // ---- D2: U += R + P1*R ; write U^T, Utw^T.  E: S,A,C matmuls ; S -> Ptb[1]
    //      (single merged barrier 10)
    {
      f32x4 dU0 = RHSs[0], dU1 = RHSs[1];
#pragma unroll
      for (int t = 0; t < 2; ++t) {
        bf16x8 bR = *(const bf16x8*)&Pb[1][(j * 16 + fr) * LDB + t * 32 + og * 8];
        dU0 = MFMA(a0[t], bR, dU0);
        dU1 = MFMA(a1[t], bR, dU1);
      }
      Zacc[0] += dU0;
      Zacc[1] += dU1;
      const float invden = 1.f / (0.5f * (ts + 65.f) * (ts + 64.f));
#pragma unroll
      for (int s = 0; s < 2; ++s) {
        const int rb = s ? row1 : row0;
        const f32x4 uu = Zacc[s];
        ushort4 up = {f2bf_rne(uu[0]), f2bf_rne(uu[1]), f2bf_rne(uu[2]), f2bf_rne(uu[3])};
        *(ushort4*)&Ztb[0][gcol * LDB + rb] = up;
        unsigned short uw[4];
#pragma unroll
        for (int r = 0; r < 4; ++r) {
          const float rr = (float)(rb + r);
          const float wr = (ts * (64.f - rr) + (rr + 1.f) + 2080.f -
                            0.5f * (rr + 1.f) * (rr + 2.f)) * invden;
          uw[r] = f2bf_rne(uu[r] * wr);
        }
        ushort4 uwp = {uw[0], uw[1], uw[2], uw[3]};
        *(ushort4*)&Utwb[gcol * LDB + rb] = uwp;
      }
    }
    f32x4 Oacc[2];
    {
      bf16x8 aQ0[2], aQ1[2], bKj[2], bWt2[2], bWa2[2];
#pragma unroll
      for (int t = 0; t < 2; ++t) {
        aQ0[t] = *(const bf16x8*)&Qb[(i0 * 16 + fr) * LDB + t * 32 + og * 8];
        aQ1[t] = *(const bf16x8*)&Qb[(i1 * 16 + fr) * LDB + t * 32 + og * 8];
        bKj[t] = *(const bf16x8*)&Kb[(j * 16 + fr) * LDB + t * 32 + og * 8];
        bWt2[t] = *(const bf16x8*)&Wtb[(j * 16 + fr) * LDB + t * 32 + og * 8];
        bWa2[t] = *(const bf16x8*)&Wavgtb[(j * 16 + fr) * LDB + t * 32 + og * 8];
      }
      f32x4 aS0 = {0, 0, 0, 0}, aS1 = {0, 0, 0, 0};
      f32x4 aA0 = {0, 0, 0, 0}, aA1 = {0, 0, 0, 0};
      f32x4 aC0 = {0, 0, 0, 0}, aC1 = {0, 0, 0, 0};
#pragma unroll
      for (int t = 0; t < 2; ++t) {
        aS0 = MFMA(aQ0[t], bKj[t], aS0);
        aS1 = MFMA(aQ1[t], bKj[t], aS1);
        aA0 = MFMA(aQ0[t], bWa2[t], aA0);
        aA1 = MFMA(aQ1[t], bWa2[t], aA1);
        aC0 = MFMA(aQ0[t], bWt2[t], aC0);
        aC1 = MFMA(aQ1[t], bWt2[t], aC1);
      }
      const float tri0 = 0.5f * ts * (ts + 1.f);
      const float jidx = gcol * ts + 0.5f * gcol * (gcol + 1.f);
#pragma unroll
      for (int s = 0; s < 2; ++s) {
        const int rb = s ? row1 : row0;
        const f32x4 sS = s ? aS1 : aS0;
        const f32x4 sA = s ? aA1 : aA0;
        const f32x4 sC = s ? aC1 : aC0;
        f32x4 oo;
#pragma unroll
        for (int r = 0; r < 4; ++r) {
          const float grow = (float)(rb + r);
          const float csr = (grow + 1.f) * ts + 0.5f * (grow + 1.f) * (grow + 2.f);
          const float rinv = 1.f / (tri0 + csr);
          const float av = tri0 * rinv;
          oo[r] = av * sA[r] + (1.f - av) * sC[r];
          const float svv = (csr >= jidx) ? (csr - jidx) * rinv * sS[r] : 0.f;
          Ptb[1][(rb + r) * LDB + gcol] = f2bf_rne(svv);
        }
        Oacc[s] = oo;
      }
    }
    __syncthreads();

    // ---- F: O += S U ; global store ----
    {
      bf16x8 aS0[2], aS1[2], bU2[2];
#pragma unroll
      for (int t = 0; t < 2; ++t) {
        aS0[t] = *(const bf16x8*)&Ptb[1][(i0 * 16 + fr) * LDB + t * 32 + og * 8];
        aS1[t] = *(const bf16x8*)&Ptb[1][(i1 * 16 + fr) * LDB + t * 32 + og * 8];
        bU2[t] = *(const bf16x8*)&Ztb[0][(j * 16 + fr) * LDB + t * 32 + og * 8];
      }
#pragma unroll
      for (int t = 0; t < 2; ++t) {
        Oacc[0] = MFMA(aS0[t], bU2[t], Oacc[0]);
        Oacc[1] = MFMA(aS1[t], bU2[t], Oacc[1]);
      }
#pragma unroll
      for (int s = 0; s < 2; ++s) {
        const int rb = s ? row1 : row0;
#pragma unroll
        for (int r = 0; r < 4; ++r)
          Op[(size_t)(ic * 64 + rb + r) * 64 + gcol] = Oacc[s][r];
      }
    }

    // ---- G: Wavg = cc1*Wavg + cc2*W + Utw^T K ; W += U^T K ---- (barrier 11)
    {
      bf16x8 aU0[2], aU1[2], aW0[2], aW1[2], bKt2[2];
#pragma unroll
      for (int t = 0; t < 2; ++t) {
        aU0[t] = *(const bf16x8*)&Ztb[0][(i0 * 16 + fr) * LDB + t * 32 + og * 8];
        aU1[t] = *(const bf16x8*)&Ztb[0][(i1 * 16 + fr) * LDB + t * 32 + og * 8];
        aW0[t] = *(const bf16x8*)&Utwb[(i0 * 16 + fr) * LDB + t * 32 + og * 8];
        aW1[t] = *(const bf16x8*)&Utwb[(i1 * 16 + fr) * LDB + t * 32 + og * 8];
        bKt2[t] = *(const bf16x8*)&Ktb[(j * 16 + fr) * LDB + t * 32 + og * 8];
      }
      const float den = (ts + 64.f) * (ts + 65.f);
      const float cc1 = ts * (ts + 1.f) / den;
      const float cc2 = 64.f * (2.f * ts + 65.f) / den;
      f32x4 wn0 = cc1 * Wav[0] + cc2 * Wt[0];
      f32x4 wn1 = cc1 * Wav[1] + cc2 * Wt[1];
#pragma unroll
      for (int t = 0; t < 2; ++t) {
        wn0 = MFMA(aW0[t], bKt2[t], wn0);
        wn1 = MFMA(aW1[t], bKt2[t], wn1);
        Wt[0] = MFMA(aU0[t], bKt2[t], Wt[0]);
        Wt[1] = MFMA(aU1[t], bKt2[t], Wt[1]);
      }
      Wav[0] = wn0;
      Wav[1] = wn1;
#pragma unroll
      for (int s = 0; s < 2; ++s) {
        const int rb = s ? row1 : row0;
        const f32x4 wtv = Wt[s];
        const f32x4 wav2 = Wav[s];
#pragma unroll
        for (int r = 0; r < 4; ++r) {
          Wtb[(rb + r) * LDB + gcol] = f2bf_rne(wtv[r]);
          Wavgtb[(rb + r) * LDB + gcol] = f2bf_rne(wav2[r]);
        }
      }
    }
    __syncthreads();
  }
}

// ---------------------------------------------------------------------------
// RMS norm over head dim + relayout (B,H,L,D) -> (B,L,Dm), bf16 output
// ---------------------------------------------------------------------------
__global__ __launch_bounds__(256) void rms_kernel(const float* __restrict__ O,
                                                  const float* __restrict__ rmsw,
                                                  unsigned short* __restrict__ out16) {
  const int m = blockIdx.x;  // b*2048 + l
  const int b = m >> 11, l = m & 2047;
  const int wv = threadIdx.x >> 6, lane = threadIdx.x & 63;
  const float rw = rmsw[lane];
#pragma unroll
  for (int hh = 0; hh < 4; ++hh) {
    const int h = wv * 4 + hh;
    const float v = O[(((size_t)(b * 16 + h)) * 2048 + l) * 64 + lane];
    float ss = v * v;
    ss += __shfl_xor(ss, 1); ss += __shfl_xor(ss, 2); ss += __shfl_xor(ss, 4);
    ss += __shfl_xor(ss, 8); ss += __shfl_xor(ss, 16); ss += __shfl_xor(ss, 32);
    const float sc = rsqrtf(ss * (1.f / 64.f) + 1e-6f);
    out16[(size_t)m * 1024 + h * 64 + lane] = f2bf_rne(v * sc * rw);
  }
}

// ---------------------------------------------------------------------------
extern "C" void kernel_launch(void* const* d_in, const int* in_sizes, int n_in,
                              void* d_out, int out_size, void* d_ws, size_t ws_size,
                              hipStream_t stream) {
  (void)in_sizes; (void)n_in; (void)out_size; (void)ws_size;
  const float* x     = (const float*)d_in[0];
  const float* Wk    = (const float*)d_in[1];
  const float* bk    = (const float*)d_in[2];
  const float* Wq    = (const float*)d_in[3];
  const float* bq    = (const float*)d_in[4];
  const float* Wv    = (const float*)d_in[5];
  const float* bv    = (const float*)d_in[6];
  const float* Wbeta = (const float*)d_in[7];
  const float* bbeta = (const float*)d_in[8];
  const float* convk = (const float*)d_in[9];
  const float* convq = (const float*)d_in[10];
  const float* convv = (const float*)d_in[11];
  const float* rmsw  = (const float*)d_in[12];
  const float* Wout  = (const float*)d_in[13];
  const float* bout  = (const float*)d_in[14];
  float* out = (float*)d_out;
  float* ws = (float*)d_ws;

  const size_t SZ = (size_t)8192 * 1024;
  float* qkv = ws;             // 8192 x 3072 f32 (dead after prep -> Obuf/normed16)
  float* betab = ws + 3 * SZ;                                      // 131072 f32
  unsigned short* x16 = (unsigned short*)(ws + 3 * SZ + 131072);   // SZ bf16
  unsigned short* wk16 = x16 + SZ;   // wk|wq|wv contiguous = 3072x1024 bf16
  unsigned short* wq16 = wk16 + 1048576;
  unsigned short* wv16 = wq16 + 1048576;
  unsigned short* wo16 = wv16 + 1048576;
  unsigned short* kn16 = wo16 + 1048576;                           // SZ bf16
  unsigned short* qn16 = kn16 + SZ;                                // SZ bf16
  float* b3 = (float*)(qn16 + SZ);                                 // 3072 f32
  float* vzb = out;            // d_out doubles as eta*silu(v) scratch
  float* Obuf = qkv;           // qkv dead after prep
  unsigned short* normed16 = (unsigned short*)(ws + SZ);

  dim3 blk(256);
  hipLaunchKernelGGL(cast_bf16_kernel, dim3(8192), blk, 0, stream, x, x16, (int)(SZ / 4));
  hipLaunchKernelGGL(cast_bf16_kernel, dim3(1024), blk, 0, stream, Wk, wk16, 262144);
  hipLaunchKernelGGL(cast_bf16_kernel, dim3(1024), blk, 0, stream, Wq, wq16, 262144);
  hipLaunchKernelGGL(cast_bf16_kernel, dim3(1024), blk, 0, stream, Wv, wv16, 262144);
  hipLaunchKernelGGL(cast_bf16_kernel, dim3(1024), blk, 0, stream, Wout, wo16, 262144);
  hipLaunchKernelGGL(concat_bias_kernel, dim3(12), blk, 0, stream, bk, bq, bv, b3);

  // fused QKV projection: 8192 x 3072
  hipLaunchKernelGGL(gemm_bf16_nt, dim3(64, 24), blk, 0, stream, x16, wk16, b3,
                     qkv, 8192, 3072, 1024);
  hipLaunchKernelGGL(beta_kernel, dim3(8192), blk, 0, stream, x, Wbeta, bbeta, betab);
  hipLaunchKernelGGL(prep_kernel, dim3(8192), blk, 0, stream, qkv, betab,
                     convk, convq, convv, kn16, qn16, vzb);
  hipLaunchKernelGGL(scan_kernel, dim3(64), dim3(512), 0, stream, kn16, qn16, vzb,
                     betab, Obuf);
  hipLaunchKernelGGL(rms_kernel, dim3(8192), blk, 0, stream, Obuf, rmsw, normed16);
  hipLaunchKernelGGL(gemm_bf16_nt, dim3(64, 8), blk, 0, stream, normed16, wo16, bout, out,
                     8192, 1024, 1024);
}

// Round 8
// 545.962 us; speedup vs baseline: 3.6533x; 1.0735x over previous
//
#include <hip/hip_runtime.h>

typedef __attribute__((ext_vector_type(8))) short bf16x8;
typedef __attribute__((ext_vector_type(4))) float f32x4;

#define MFMA(a, b, c) __builtin_amdgcn_mfma_f32_16x16x32_bf16((a), (b), (c), 0, 0, 0)

__device__ inline unsigned short f2bf_rne(float f) {
  unsigned int u = __float_as_uint(f);
  u += 0x7FFFu + ((u >> 16) & 1u);
  return (unsigned short)(u >> 16);
}

// ---------------------------------------------------------------------------
// prepare: all f32->bf16 casts + bias concat in ONE dispatch
// ---------------------------------------------------------------------------
__global__ __launch_bounds__(256) void prepare_kernel(
    const float* __restrict__ x, const float* __restrict__ Wk,
    const float* __restrict__ Wq, const float* __restrict__ Wv,
    const float* __restrict__ Wout, const float* __restrict__ bk,
    const float* __restrict__ bq, const float* __restrict__ bv,
    unsigned short* __restrict__ x16, unsigned short* __restrict__ wk16,
    unsigned short* __restrict__ wq16, unsigned short* __restrict__ wv16,
    unsigned short* __restrict__ wo16, float* __restrict__ b3) {
  const int gid = blockIdx.x * 256 + threadIdx.x;
  const int stride = gridDim.x * 256;
  for (int i = gid; i < 2097152; i += stride) {
    const float4 v = ((const float4*)x)[i];
    ushort4 o = {f2bf_rne(v.x), f2bf_rne(v.y), f2bf_rne(v.z), f2bf_rne(v.w)};
    ((ushort4*)x16)[i] = o;
  }
  for (int i = gid; i < 262144; i += stride) {
    float4 v = ((const float4*)Wk)[i];
    ushort4 o = {f2bf_rne(v.x), f2bf_rne(v.y), f2bf_rne(v.z), f2bf_rne(v.w)};
    ((ushort4*)wk16)[i] = o;
    v = ((const float4*)Wq)[i];
    o = (ushort4){f2bf_rne(v.x), f2bf_rne(v.y), f2bf_rne(v.z), f2bf_rne(v.w)};
    ((ushort4*)wq16)[i] = o;
    v = ((const float4*)Wv)[i];
    o = (ushort4){f2bf_rne(v.x), f2bf_rne(v.y), f2bf_rne(v.z), f2bf_rne(v.w)};
    ((ushort4*)wv16)[i] = o;
    v = ((const float4*)Wout)[i];
    o = (ushort4){f2bf_rne(v.x), f2bf_rne(v.y), f2bf_rne(v.z), f2bf_rne(v.w)};
    ((ushort4*)wo16)[i] = o;
  }
  if (gid < 3072)
    b3[gid] = gid < 1024 ? bk[gid] : gid < 2048 ? bq[gid - 1024] : bv[gid - 2048];
}

// ---------------------------------------------------------------------------
// bf16 MFMA GEMM (NT): C[m][n] = bias[n] + sum_k A[m][k]*Bw[n][k]
// ---------------------------------------------------------------------------
__global__ __launch_bounds__(256) void gemm_bf16_nt(
    const unsigned short* __restrict__ A, const unsigned short* __restrict__ Bw,
    const float* __restrict__ bias, float* __restrict__ C, int M, int N, int K) {
  __shared__ unsigned short Asl[128 * 32];
  __shared__ unsigned short Bsl[128 * 32];
  const int tid = threadIdx.x;
  const int lane = tid & 63, w = tid >> 6;
  const int bm = blockIdx.x * 128, bn = blockIdx.y * 128;
  const int wr = (w >> 1) * 64, wc = (w & 1) * 64;

  const int li0 = tid, li1 = tid + 256;
  const int ar0 = li0 >> 2, ak0 = (li0 & 3) * 8;
  const int ar1 = li1 >> 2, ak1 = (li1 & 3) * 8;
  const unsigned short* gA0 = A + (size_t)(bm + ar0) * K + ak0;
  const unsigned short* gA1 = A + (size_t)(bm + ar1) * K + ak1;
  const unsigned short* gB0 = Bw + (size_t)(bn + ar0) * K + ak0;
  const unsigned short* gB1 = Bw + (size_t)(bn + ar1) * K + ak1;
  unsigned short* lA0 = &Asl[(size_t)(w * 64) * 8];
  unsigned short* lA1 = &Asl[(size_t)(w * 64 + 256) * 8];
  unsigned short* lB0 = &Bsl[(size_t)(w * 64) * 8];
  unsigned short* lB1 = &Bsl[(size_t)(w * 64 + 256) * 8];

  f32x4 acc[4][4];
#pragma unroll
  for (int i = 0; i < 4; ++i)
#pragma unroll
    for (int j = 0; j < 4; ++j) acc[i][j] = (f32x4){0.f, 0.f, 0.f, 0.f};

  const int fr = lane & 15, kg = lane >> 4;

  for (int k0 = 0; k0 < K; k0 += 32) {
    __syncthreads();
    __builtin_amdgcn_global_load_lds((const __attribute__((address_space(1))) unsigned int*)(gA0 + k0),
                                     (__attribute__((address_space(3))) unsigned int*)lA0, 16, 0, 0);
    __builtin_amdgcn_global_load_lds((const __attribute__((address_space(1))) unsigned int*)(gA1 + k0),
                                     (__attribute__((address_space(3))) unsigned int*)lA1, 16, 0, 0);
    __builtin_amdgcn_global_load_lds((const __attribute__((address_space(1))) unsigned int*)(gB0 + k0),
                                     (__attribute__((address_space(3))) unsigned int*)lB0, 16, 0, 0);
    __builtin_amdgcn_global_load_lds((const __attribute__((address_space(1))) unsigned int*)(gB1 + k0),
                                     (__attribute__((address_space(3))) unsigned int*)lB1, 16, 0, 0);
    __syncthreads();

    bf16x8 af[4], bfr[4];
#pragma unroll
    for (int i = 0; i < 4; ++i) {
      af[i] = *(const bf16x8*)&Asl[(size_t)(wr + i * 16 + fr) * 32 + kg * 8];
      bfr[i] = *(const bf16x8*)&Bsl[(size_t)(wc + i * 16 + fr) * 32 + kg * 8];
    }
#pragma unroll
    for (int i = 0; i < 4; ++i)
#pragma unroll
      for (int j = 0; j < 4; ++j)
        acc[i][j] = MFMA(af[i], bfr[j], acc[i][j]);
  }

  const int og = lane >> 4;
#pragma unroll
  for (int j = 0; j < 4; ++j) {
    const int col = bn + wc + j * 16 + fr;
    const float bs = bias[col];
#pragma unroll
    for (int i = 0; i < 4; ++i) {
#pragma unroll
      for (int r = 0; r < 4; ++r) {
        const int row = bm + wr + i * 16 + og * 4 + r;
        C[(size_t)row * N + col] = acc[i][j][r] + bs;
      }
    }
  }
}

// ---------------------------------------------------------------------------
// prep: beta (sigmoid proj) + causal conv + norms + eta*silu, fused.
// ---------------------------------------------------------------------------
__global__ __launch_bounds__(256) void prep_kernel(
    const float* __restrict__ x, const float* __restrict__ qkv,
    const float* __restrict__ Wbeta, const float* __restrict__ bbeta,
    const float* __restrict__ convk, const float* __restrict__ convq,
    const float* __restrict__ convv, float* __restrict__ betab,
    unsigned short* __restrict__ kn16, unsigned short* __restrict__ qn16,
    float* __restrict__ vz) {
  __shared__ float etas_sm[16];
  const int m = blockIdx.x;          // b*2048 + l
  const int l = m & 2047;
  const int lane = threadIdx.x & 63;
  const int wvi = threadIdx.x >> 6;  // 0..3

  // beta: wave wvi computes heads 4*wvi..4*wvi+3
  {
    const float4* xr = (const float4*)(x + (size_t)m * 1024);
    const float4 xv0 = xr[lane], xv1 = xr[lane + 64];
    const float4 xv2 = xr[lane + 128], xv3 = xr[lane + 192];
#pragma unroll
    for (int hh = 0; hh < 4; ++hh) {
      const int h = wvi * 4 + hh;
      const float4* wr = (const float4*)(Wbeta + (size_t)h * 1024);
      const float4 w0 = wr[lane], w1 = wr[lane + 64];
      const float4 w2 = wr[lane + 128], w3 = wr[lane + 192];
      float acc = xv0.x * w0.x + xv0.y * w0.y + xv0.z * w0.z + xv0.w * w0.w +
                  xv1.x * w1.x + xv1.y * w1.y + xv1.z * w1.z + xv1.w * w1.w +
                  xv2.x * w2.x + xv2.y * w2.y + xv2.z * w2.z + xv2.w * w2.w +
                  xv3.x * w3.x + xv3.y * w3.y + xv3.z * w3.z + xv3.w * w3.w;
      acc += __shfl_xor(acc, 1); acc += __shfl_xor(acc, 2);
      acc += __shfl_xor(acc, 4); acc += __shfl_xor(acc, 8);
      acc += __shfl_xor(acc, 16); acc += __shfl_xor(acc, 32);
      if (lane == 0) {
        const float e = 1.f / (1.f + expf(-(acc + bbeta[h])));
        etas_sm[h] = e;
        betab[(size_t)m * 16 + h] = e;
      }
    }
  }
  __syncthreads();

#pragma unroll
  for (int s = 0; s < 4; ++s) {
    const int h = 4 * s + wvi;
    const int c = h * 64 + lane;
    const float4 wk4 = *(const float4*)(convk + (size_t)c * 4);
    const float4 wq4 = *(const float4*)(convq + (size_t)c * 4);
    const float4 wv4 = *(const float4*)(convv + (size_t)c * 4);
    const float wk[4] = {wk4.x, wk4.y, wk4.z, wk4.w};
    const float wq[4] = {wq4.x, wq4.y, wq4.z, wq4.w};
    const float wvv[4] = {wv4.x, wv4.y, wv4.z, wv4.w};
    float kc = 0.f, qc = 0.f, vc = 0.f;
#pragma unroll
    for (int jj = 0; jj < 4; ++jj) {
      const int lj = l - 3 + jj;
      if (lj >= 0) {
        const size_t rb = (size_t)(m - l + lj) * 3072 + c;
        kc += wk[jj] * qkv[rb];
        qc += wq[jj] * qkv[rb + 1024];
        vc += wvv[jj] * qkv[rb + 2048];
      }
    }
    float ssk = kc * kc, ssq = qc * qc;
    ssk += __shfl_xor(ssk, 1); ssq += __shfl_xor(ssq, 1);
    ssk += __shfl_xor(ssk, 2); ssq += __shfl_xor(ssq, 2);
    ssk += __shfl_xor(ssk, 4); ssq += __shfl_xor(ssq, 4);
    ssk += __shfl_xor(ssk, 8); ssq += __shfl_xor(ssq, 8);
    ssk += __shfl_xor(ssk, 16); ssq += __shfl_xor(ssq, 16);
    ssk += __shfl_xor(ssk, 32); ssq += __shfl_xor(ssq, 32);
    const float eta = etas_sm[h];
    const size_t o = (size_t)m * 1024 + c;
    kn16[o] = f2bf_rne(kc / (sqrtf(ssk) + 1e-6f));
    qn16[o] = f2bf_rne(qc / (sqrtf(ssq) + 1e-6f));
    vz[o] = eta * vc / (1.f + expf(-vc));
  }
}

// ---------------------------------------------------------------------------
// MFMA delta-rule scan v3: 10 barriers/chunk. K/Q double-buffered with
// register prefetch (T14 async split); V/eta direct per-thread register loads
// issued one chunk ahead; Ktb write deferred to next chunk's B phase.
// ---------------------------------------------------------------------------
#define LDB 72  // bf16 row stride (144B: rows 16B-aligned)

__global__ __launch_bounds__(512, 1) void scan_kernel(
    const unsigned short* __restrict__ kn16, const unsigned short* __restrict__ qn16,
    const float* __restrict__ vz, const float* __restrict__ betab,
    float* __restrict__ O) {
  __shared__ unsigned short Kb[2][64 * LDB], Qb[2][64 * LDB], Ktb[64 * LDB];
  __shared__ unsigned short Wtb[64 * LDB], Wavgtb[64 * LDB];
  __shared__ unsigned short Pb[2][64 * LDB], Ptb[2][64 * LDB], Ztb[2][64 * LDB];
  __shared__ unsigned short P1b[64 * LDB], Utwb[64 * LDB];

  const int tid = threadIdx.x;
  const int bh = blockIdx.x;
  const int b = bh >> 4, h = bh & 15;
  const int wv = tid >> 6, lane = tid & 63;
  const int fr = lane & 15, og = lane >> 4;
  const int i0 = (wv >> 2) * 2, i1 = i0 + 1, j = wv & 3;
  const int gcol = j * 16 + fr;
  const int row0 = i0 * 16 + og * 4;
  const int row1 = i1 * 16 + og * 4;

  for (int t = tid; t < 64 * LDB; t += 512) { Wtb[t] = 0; Wavgtb[t] = 0; }

  const size_t base = ((size_t)b * 2048) * 1024 + (size_t)h * 64;
  const unsigned short* kp = kn16 + base;
  const unsigned short* qp = qn16 + base;
  const float* vp = vz + base;
  const float* etap = betab + (size_t)b * 2048 * 16 + h;
  float* Op = O + (size_t)bh * 2048 * 64;

  f32x4 Wt[2], Wav[2];
  Wt[0] = Wt[1] = Wav[0] = Wav[1] = (f32x4){0.f, 0.f, 0.f, 0.f};

  const int sr = tid >> 3, sc8 = (tid & 7) * 8;

  // ---- prologue: stage chunk 0 (K,Q,Kt -> LDS; V,eta -> regs) ----
  {
    const size_t g = (size_t)sr * 1024 + sc8;
    *(ushort4*)&Kb[0][sr * LDB + sc8] = *(const ushort4*)(kp + g);
    *(ushort4*)&Kb[0][sr * LDB + sc8 + 4] = *(const ushort4*)(kp + g + 4);
    *(ushort4*)&Qb[0][sr * LDB + sc8] = *(const ushort4*)(qp + g);
    *(ushort4*)&Qb[0][sr * LDB + sc8 + 4] = *(const ushort4*)(qp + g + 4);
    ushort4 t0v, t1v;
    t0v.x = kp[(size_t)(sc8 + 0) * 1024 + sr];
    t0v.y = kp[(size_t)(sc8 + 1) * 1024 + sr];
    t0v.z = kp[(size_t)(sc8 + 2) * 1024 + sr];
    t0v.w = kp[(size_t)(sc8 + 3) * 1024 + sr];
    t1v.x = kp[(size_t)(sc8 + 4) * 1024 + sr];
    t1v.y = kp[(size_t)(sc8 + 5) * 1024 + sr];
    t1v.z = kp[(size_t)(sc8 + 6) * 1024 + sr];
    t1v.w = kp[(size_t)(sc8 + 7) * 1024 + sr];
    *(ushort4*)&Ktb[sr * LDB + sc8] = t0v;
    *(ushort4*)&Ktb[sr * LDB + sc8 + 4] = t1v;
  }
  float vr0[4], vr1[4], er0[4], er1[4];
#pragma unroll
  for (int r = 0; r < 4; ++r) {
    vr0[r] = vp[(size_t)(row0 + r) * 1024 + gcol];
    vr1[r] = vp[(size_t)(row1 + r) * 1024 + gcol];
    er0[r] = etap[(size_t)(row0 + r) * 16];
    er1[r] = etap[(size_t)(row1 + r) * 16];
  }
  ushort4 pk0, pk1, pq0, pq1, pt0, pt1;
  __syncthreads();

#pragma unroll 1
  for (int ic = 0; ic < 32; ++ic) {
    const int cur = ic & 1, nxt = cur ^ 1;
    const float ts = (float)(ic * 64);
    const int icn = (ic < 31) ? ic + 1 : ic;  // clamp: last-chunk prefetch harmless

    // ---- B: write deferred Ktb; issue K/Q/Kt prefetch; T+RHS ---- (barrier 1)
    f32x4 Zacc[2], RHSs[2];
    {
      if (ic > 0) {
        *(ushort4*)&Ktb[sr * LDB + sc8] = pt0;
        *(ushort4*)&Ktb[sr * LDB + sc8 + 4] = pt1;
      }
      const size_t gn = (size_t)(icn * 64 + sr) * 1024 + sc8;
      pk0 = *(const ushort4*)(kp + gn);
      pk1 = *(const ushort4*)(kp + gn + 4);
      pq0 = *(const ushort4*)(qp + gn);
      pq1 = *(const ushort4*)(qp + gn + 4);
      {
        const size_t cb = (size_t)(icn * 64 + sc8);
        pt0.x = kp[(cb + 0) * 1024 + sr]; pt0.y = kp[(cb + 1) * 1024 + sr];
        pt0.z = kp[(cb + 2) * 1024 + sr]; pt0.w = kp[(cb + 3) * 1024 + sr];
        pt1.x = kp[(cb + 4) * 1024 + sr]; pt1.y = kp[(cb + 5) * 1024 + sr];
        pt1.z = kp[(cb + 6) * 1024 + sr]; pt1.w = kp[(cb + 7) * 1024 + sr];
      }
      bf16x8 aK0[2], aK1[2], bK[2], bW[2];
#pragma unroll
      for (int t = 0; t < 2; ++t) {
        aK0[t] = *(const bf16x8*)&Kb[cur][(i0 * 16 + fr) * LDB + t * 32 + og * 8];
        aK1[t] = *(const bf16x8*)&Kb[cur][(i1 * 16 + fr) * LDB + t * 32 + og * 8];
        bK[t] = *(const bf16x8*)&Kb[cur][(j * 16 + fr) * LDB + t * 32 + og * 8];
        bW[t] = *(const bf16x8*)&Wtb[(j * 16 + fr) * LDB + t * 32 + og * 8];
      }
      f32x4 accT0 = {0, 0, 0, 0}, accT1 = {0, 0, 0, 0};
      f32x4 accR0 = {0, 0, 0, 0}, accR1 = {0, 0, 0, 0};
#pragma unroll
      for (int t = 0; t < 2; ++t) {
        accT0 = MFMA(aK0[t], bK[t], accT0);
        accT1 = MFMA(aK1[t], bK[t], accT1);
        accR0 = MFMA(aK0[t], bW[t], accR0);
        accR1 = MFMA(aK1[t], bW[t], accR1);
      }
#pragma unroll
      for (int s = 0; s < 2; ++s) {
        const int rb = s ? row1 : row0;
        const f32x4 aT = s ? accT1 : accT0;
        const f32x4 aR = s ? accR1 : accR0;
        unsigned short us[4];
        float zv[4];
#pragma unroll
        for (int r = 0; r < 4; ++r) {
          const int grow = rb + r;
          const float eta = s ? er1[r] : er0[r];
          const float vv = s ? vr1[r] : vr0[r];
          const float tvv = (gcol < grow) ? -eta * aT[r] : 0.f;
          us[r] = f2bf_rne(tvv);
          zv[r] = vv - eta * aR[r];
          Pb[0][grow * LDB + gcol] = us[r];
          P1b[grow * LDB + gcol] = us[r];
        }
        ushort4 pp = {us[0], us[1], us[2], us[3]};
        *(ushort4*)&Ptb[0][gcol * LDB + rb] = pp;
        ushort4 zp = {f2bf_rne(zv[0]), f2bf_rne(zv[1]), f2bf_rne(zv[2]), f2bf_rne(zv[3])};
        *(ushort4*)&Ztb[0][gcol * LDB + rb] = zp;
        Zacc[s] = (f32x4){zv[0], zv[1], zv[2], zv[3]};
        RHSs[s] = Zacc[s];
      }
    }
    __syncthreads();

    // ---- C: doubling chain, ping-pong ---- (barriers 2-7)
#pragma unroll
    for (int k = 0; k < 6; ++k) {
      const int pc = k & 1, pn = pc ^ 1;
      bf16x8 aP0[2], aP1[2], bZ[2];
#pragma unroll
      for (int t = 0; t < 2; ++t) {
        aP0[t] = *(const bf16x8*)&Pb[pc][(i0 * 16 + fr) * LDB + t * 32 + og * 8];
        aP1[t] = *(const bf16x8*)&Pb[pc][(i1 * 16 + fr) * LDB + t * 32 + og * 8];
        bZ[t] = *(const bf16x8*)&Ztb[pc][(j * 16 + fr) * LDB + t * 32 + og * 8];
      }
      f32x4 sq0 = {0, 0, 0, 0}, sq1 = {0, 0, 0, 0};
      if (k < 5) {
#pragma unroll
        for (int t = 0; t < 2; ++t) {
          bf16x8 bPt = *(const bf16x8*)&Ptb[pc][(j * 16 + fr) * LDB + t * 32 + og * 8];
          sq0 = MFMA(aP0[t], bPt, sq0);
          sq1 = MFMA(aP1[t], bPt, sq1);
        }
      }
#pragma unroll
      for (int t = 0; t < 2; ++t) {
        Zacc[0] = MFMA(aP0[t], bZ[t], Zacc[0]);
        Zacc[1] = MFMA(aP1[t], bZ[t], Zacc[1]);
      }
#pragma unroll
      for (int s = 0; s < 2; ++s) {
        const int rb = s ? row1 : row0;
        const f32x4 zz = Zacc[s];
        ushort4 zp = {f2bf_rne(zz[0]), f2bf_rne(zz[1]), f2bf_rne(zz[2]), f2bf_rne(zz[3])};
        *(ushort4*)&Ztb[pn][gcol * LDB + rb] = zp;
        if (k < 5) {
          const f32x4 sv = s ? sq1 : sq0;
          unsigned short u0 = f2bf_rne(sv[0]), u1 = f2bf_rne(sv[1]);
          unsigned short u2 = f2bf_rne(sv[2]), u3 = f2bf_rne(sv[3]);
          Pb[pn][(rb + 0) * LDB + gcol] = u0;
          Pb[pn][(rb + 1) * LDB + gcol] = u1;
          Pb[pn][(rb + 2) * LDB + gcol] = u2;
          Pb[pn][(rb + 3) * LDB + gcol] = u3;
          ushort4 pp = {u0, u1, u2, u3};
          *(ushort4*)&Ptb[pn][gcol * LDB + rb] = pp;
        }
      }
      __syncthreads();
    }
    // final U: bf16 transposed in Ztb[0], f32 in Zacc

    // ---- D1: write next-chunk K/Q (dbuf); R = RHS-U+P1*U -> Pb[1] ---- (barrier 8)
    bf16x8 a0[2], a1[2];
    {
      *(ushort4*)&Kb[nxt][sr * LDB + sc8] = pk0;
      *(ushort4*)&Kb[nxt][sr * LDB + sc8 + 4] = pk1;
      *(ushort4*)&Qb[nxt][sr * LDB + sc8] = pq0;
      *(ushort4*)&Qb[nxt][sr * LDB + sc8 + 4] = pq1;
#pragma unroll
      for (int t = 0; t < 2; ++t) {
        a0[t] = *(const bf16x8*)&P1b[(i0 * 16 + fr) * LDB + t * 32 + og * 8];
        a1[t] = *(const bf16x8*)&P1b[(i1 * 16 + fr) * LDB + t * 32 + og * 8];
      }
      f32x4 R0 = RHSs[0] - Zacc[0];
      f32x4 R1 = RHSs[1] - Zacc[1];
#pragma unroll
      for (int t = 0; t < 2; ++t) {
        bf16x8 bU = *(const bf16x8*)&Ztb[0][(j * 16 + fr) * LDB + t * 32 + og * 8];
        R0 = MFMA(a0[t], bU, R0);
        R1 = MFMA(a1[t], bU, R1);
      }
      ushort4 r0p = {f2bf_rne(R0[0]), f2bf_rne(R0[1]), f2bf_rne(R0[2]), f2bf_rne(R0[3])};
      ushort4 r1p = {f2bf_rne(R1[0]), f2bf_rne(R1[1]), f2bf_rne(R1[2]), f2bf_rne(R1[3])};
      *(ushort4*)&Pb[1][gcol * LDB + row0] = r0p;
      *(ushort4*)&Pb[1][gcol * LDB + row1] = r1p;
      RHSs[0] = R0;
      RHSs[1] = R1;
    }
    __syncthreads();

    // ---- D2+E: U += R + P1*R; prefetch V/eta; S,A,C matmuls ---- (barrier 9)
    {
      f32x4 dU0 = RHSs[0], dU1 = RHSs[1];
#pragma unroll
      for (int t = 0; t < 2; ++t) {
        bf16x8 bR = *(const bf16x8*)&Pb[1][(j * 16 + fr) * LDB + t * 32 + og * 8];
        dU0 = MFMA(a0[t], bR, dU0);
        dU1 = MFMA(a1[t], bR, dU1);
      }
      Zacc[0] += dU0;
      Zacc[1] += dU1;
      // prefetch V/eta for next chunk (consumed at next B)
#pragma unroll
      for (int r = 0; r < 4; ++r) {
        vr0[r] = vp[(size_t)(icn * 64 + row0 + r) * 1024 + gcol];
        vr1[r] = vp[(size_t)(icn * 64 + row1 + r) * 1024 + gcol];
        er0[r] = etap[(size_t)(icn * 64 + row0 + r) * 16];
        er1[r] = etap[(size_t)(icn * 64 + row1 + r) * 16];
      }
      const float invden = 1.f / (0.5f * (ts + 65.f) * (ts + 64.f));
#pragma unroll
      for (int s = 0; s < 2; ++s) {
        const int rb = s ? row1 : row0;
        const f32x4 uu = Zacc[s];
        ushort4 up = {f2bf_rne(uu[0]), f2bf_rne(uu[1]), f2bf_rne(uu[2]), f2bf_rne(uu[3])};
        *(ushort4*)&Ztb[0][gcol * LDB + rb] = up;
        unsigned short uw[4];
#pragma unroll
        for (int r = 0; r < 4; ++r) {
          const float rr = (float)(rb + r);
          const float wr = (ts * (64.f - rr) + (rr + 1.f) + 2080.f -
                            0.5f * (rr + 1.f) * (rr + 2.f)) * invden;
          uw[r] = f2bf_rne(uu[r] * wr);
        }
        ushort4 uwp = {uw[0], uw[1], uw[2], uw[3]};
        *(ushort4*)&Utwb[gcol * LDB + rb] = uwp;
      }
    }
    f32x4 Oacc[2];
    {
      bf16x8 aQ0[2], aQ1[2], bKj[2], bWt2[2], bWa2[2];
#pragma unroll
      for (int t = 0; t < 2; ++t) {
        aQ0[t] = *(const bf16x8*)&Qb[cur][(i0 * 16 + fr) * LDB + t * 32 + og * 8];
        aQ1[t] = *(const bf16x8*)&Qb[cur][(i1 * 16 + fr) * LDB + t * 32 + og * 8];
        bKj[t] = *(const bf16x8*)&Kb[cur][(j * 16 + fr) * LDB + t * 32 + og * 8];
        bWt2[t] = *(const bf16x8*)&Wtb[(j * 16 + fr) * LDB + t * 32 + og * 8];
        bWa2[t] = *(const bf16x8*)&Wavgtb[(j * 16 + fr) * LDB + t * 32 + og * 8];
      }
      f32x4 aS0 = {0, 0, 0, 0}, aS1 = {0, 0, 0, 0};
      f32x4 aA0 = {0, 0, 0, 0}, aA1 = {0, 0, 0, 0};
      f32x4 aC0 = {0, 0, 0, 0}, aC1 = {0, 0, 0, 0};
#pragma unroll
      for (int t = 0; t < 2; ++t) {
        aS0 = MFMA(aQ0[t], bKj[t], aS0);
        aS1 = MFMA(aQ1[t], bKj[t], aS1);
        aA0 = MFMA(aQ0[t], bWa2[t], aA0);
        aA1 = MFMA(aQ1[t], bWa2[t], aA1);
        aC0 = MFMA(aQ0[t], bWt2[t], aC0);
        aC1 = MFMA(aQ1[t], bWt2[t], aC1);
      }
      const float tri0 = 0.5f * ts * (ts + 1.f);
      const float jidx = gcol * ts + 0.5f * gcol * (gcol + 1.f);
#pragma unroll
      for (int s = 0; s < 2; ++s) {
        const int rb = s ? row1 : row0;
        const f32x4 sS = s ? aS1 : aS0;
        const f32x4 sA = s ? aA1 : aA0;
        const f32x4 sC = s ? aC1 : aC0;
        f32x4 oo;
#pragma unroll
        for (int r = 0; r < 4; ++r) {
          const float grow = (float)(rb + r);
          const float csr = (grow + 1.f) * ts + 0.5f * (grow + 1.f) * (grow + 2.f);
          const float rinv = 1.f / (tri0 + csr);
          const float av = tri0 * rinv;
          oo[r] = av * sA[r] + (1.f - av) * sC[r];
          const float svv = (csr >= jidx) ? (csr - jidx) * rinv * sS[r] : 0.f;
          Ptb[1][(rb + r) * LDB + gcol] = f2bf_rne(svv);
        }
        Oacc[s] = oo;
      }
    }
    __syncthreads();

    // ---- F: O += S U ; global store ----
    {
      bf16x8 aS0[2], aS1[2], bU2[2];
#pragma unroll
      for (int t = 0; t < 2; ++t) {
        aS0[t] = *(const bf16x8*)&Ptb[1][(i0 * 16 + fr) * LDB + t * 32 + og * 8];
        aS1[t] = *(const bf16x8*)&Ptb[1][(i1 * 16 + fr) * LDB + t * 32 + og * 8];
        bU2[t] = *(const bf16x8*)&Ztb[0][(j * 16 + fr) * LDB + t * 32 + og * 8];
      }
#pragma unroll
      for (int t = 0; t < 2; ++t) {
        Oacc[0] = MFMA(aS0[t], bU2[t], Oacc[0]);
        Oacc[1] = MFMA(aS1[t], bU2[t], Oacc[1]);
      }
#pragma unroll
      for (int s = 0; s < 2; ++s) {
        const int rb = s ? row1 : row0;
#pragma unroll
        for (int r = 0; r < 4; ++r)
          Op[(size_t)(ic * 64 + rb + r) * 64 + gcol] = Oacc[s][r];
      }
    }

    // ---- G: Wavg/W update; refresh LDS ---- (barrier 10)
    {
      bf16x8 aU0[2], aU1[2], aW0[2], aW1[2], bKt2[2];
#pragma unroll
      for (int t = 0; t < 2; ++t) {
        aU0[t] = *(const bf16x8*)&Ztb[0][(i0 * 16 + fr) * LDB + t * 32 + og * 8];
        aU1[t] = *(const bf16x8*)&Ztb[0][(i1 * 16 + fr) * LDB + t * 32 + og * 8];
        aW0[t] = *(const bf16x8*)&Utwb[(i0 * 16 + fr) * LDB + t * 32 + og * 8];
        aW1[t] = *(const bf16x8*)&Utwb[(i1 * 16 + fr) * LDB + t * 32 + og * 8];
        bKt2[t] = *(const bf16x8*)&Ktb[(j * 16 + fr) * LDB + t * 32 + og * 8];
      }
      const float den = (ts + 64.f) * (ts + 65.f);
      const float cc1 = ts * (ts + 1.f) / den;
      const float cc2 = 64.f * (2.f * ts + 65.f) / den;
      f32x4 wn0 = cc1 * Wav[0] + cc2 * Wt[0];
      f32x4 wn1 = cc1 * Wav[1] + cc2 * Wt[1];
#pragma unroll
      for (int t = 0; t < 2; ++t) {
        wn0 = MFMA(aW0[t], bKt2[t], wn0);
        wn1 = MFMA(aW1[t], bKt2[t], wn1);
        Wt[0] = MFMA(aU0[t], bKt2[t], Wt[0]);
        Wt[1] = MFMA(aU1[t], bKt2[t], Wt[1]);
      }
      Wav[0] = wn0;
      Wav[1] = wn1;
#pragma unroll
      for (int s = 0; s < 2; ++s) {
        const int rb = s ? row1 : row0;
        const f32x4 wtv = Wt[s];
        const f32x4 wav2 = Wav[s];
#pragma unroll
        for (int r = 0; r < 4; ++r) {
          Wtb[(rb + r) * LDB + gcol] = f2bf_rne(wtv[r]);
          Wavgtb[(rb + r) * LDB + gcol] = f2bf_rne(wav2[r]);
        }
      }
    }
    __syncthreads();
  }
}

// ---------------------------------------------------------------------------
// RMS norm over head dim + relayout (B,H,L,D) -> (B,L,Dm), bf16 output
// ---------------------------------------------------------------------------
__global__ __launch_bounds__(256) void rms_kernel(const float* __restrict__ O,
                                                  const float* __restrict__ rmsw,
                                                  unsigned short* __restrict__ out16) {
  const int m = blockIdx.x;  // b*2048 + l
  const int b = m >> 11, l = m & 2047;
  const int wv = threadIdx.x >> 6, lane = threadIdx.x & 63;
  const float rw = rmsw[lane];
#pragma unroll
  for (int hh = 0; hh < 4; ++hh) {
    const int h = wv * 4 + hh;
    const float v = O[(((size_t)(b * 16 + h)) * 2048 + l) * 64 + lane];
    float ss = v * v;
    ss += __shfl_xor(ss, 1); ss += __shfl_xor(ss, 2); ss += __shfl_xor(ss, 4);
    ss += __shfl_xor(ss, 8); ss += __shfl_xor(ss, 16); ss += __shfl_xor(ss, 32);
    const float sc = rsqrtf(ss * (1.f / 64.f) + 1e-6f);
    out16[(size_t)m * 1024 + h * 64 + lane] = f2bf_rne(v * sc * rw);
  }
}

// ---------------------------------------------------------------------------
extern "C" void kernel_launch(void* const* d_in, const int* in_sizes, int n_in,
                              void* d_out, int out_size, void* d_ws, size_t ws_size,
                              hipStream_t stream) {
  (void)in_sizes; (void)n_in; (void)out_size; (void)ws_size;
  const float* x     = (const float*)d_in[0];
  const float* Wk    = (const float*)d_in[1];
  const float* bk    = (const float*)d_in[2];
  const float* Wq    = (const float*)d_in[3];
  const float* bq    = (const float*)d_in[4];
  const float* Wv    = (const float*)d_in[5];
  const float* bv    = (const float*)d_in[6];
  const float* Wbeta = (const float*)d_in[7];
  const float* bbeta = (const float*)d_in[8];
  const float* convk = (const float*)d_in[9];
  const float* convq = (const float*)d_in[10];
  const float* convv = (const float*)d_in[11];
  const float* rmsw  = (const float*)d_in[12];
  const float* Wout  = (const float*)d_in[13];
  const float* bout  = (const float*)d_in[14];
  float* out = (float*)d_out;
  float* ws = (float*)d_ws;

  const size_t SZ = (size_t)8192 * 1024;
  float* qkv = ws;             // 8192 x 3072 f32 (dead after prep -> Obuf/normed16)
  float* betab = ws + 3 * SZ;                                      // 131072 f32
  unsigned short* x16 = (unsigned short*)(ws + 3 * SZ + 131072);   // SZ bf16
  unsigned short* wk16 = x16 + SZ;   // wk|wq|wv contiguous = 3072x1024 bf16
  unsigned short* wq16 = wk16 + 1048576;
  unsigned short* wv16 = wq16 + 1048576;
  unsigned short* wo16 = wv16 + 1048576;
  unsigned short* kn16 = wo16 + 1048576;                           // SZ bf16
  unsigned short* qn16 = kn16 + SZ;                                // SZ bf16
  float* b3 = (float*)(qn16 + SZ);                                 // 3072 f32
  float* vzb = out;            // d_out doubles as eta*silu(v) scratch
  float* Obuf = qkv;           // qkv dead after prep
  unsigned short* normed16 = (unsigned short*)(ws + SZ);

  dim3 blk(256);
  hipLaunchKernelGGL(prepare_kernel, dim3(2048), blk, 0, stream, x, Wk, Wq, Wv, Wout,
                     bk, bq, bv, x16, wk16, wq16, wv16, wo16, b3);
  // fused QKV projection: 8192 x 3072
  hipLaunchKernelGGL(gemm_bf16_nt, dim3(64, 24), blk, 0, stream, x16, wk16, b3,
                     qkv, 8192, 3072, 1024);
  hipLaunchKernelGGL(prep_kernel, dim3(8192), blk, 0, stream, x, qkv, Wbeta, bbeta,
                     convk, convq, convv, betab, kn16, qn16, vzb);
  hipLaunchKernelGGL(scan_kernel, dim3(64), dim3(512), 0, stream, kn16, qn16, vzb,
                     betab, Obuf);
  hipLaunchKernelGGL(rms_kernel, dim3(8192), blk, 0, stream, Obuf, rmsw, normed16);
  hipLaunchKernelGGL(gemm_bf16_nt, dim3(64, 8), blk, 0, stream, normed16, wo16, bout, out,
                     8192, 1024, 1024);
}

// Round 9
// 529.476 us; speedup vs baseline: 3.7671x; 1.0311x over previous
//
#include <hip/hip_runtime.h>

typedef __attribute__((ext_vector_type(8))) short bf16x8;
typedef __attribute__((ext_vector_type(4))) float f32x4;

#define MFMA(a, b, c) __builtin_amdgcn_mfma_f32_16x16x32_bf16((a), (b), (c), 0, 0, 0)

__device__ inline unsigned short f2bf_rne(float f) {
  unsigned int u = __float_as_uint(f);
  u += 0x7FFFu + ((u >> 16) & 1u);
  return (unsigned short)(u >> 16);
}
__device__ inline float bf2f(unsigned short u) {
  return __uint_as_float(((unsigned int)u) << 16);
}

// ---------------------------------------------------------------------------
// prepare: all f32->bf16 casts + bias concat in ONE dispatch
// ---------------------------------------------------------------------------
__global__ __launch_bounds__(256) void prepare_kernel(
    const float* __restrict__ x, const float* __restrict__ Wk,
    const float* __restrict__ Wq, const float* __restrict__ Wv,
    const float* __restrict__ Wout, const float* __restrict__ bk,
    const float* __restrict__ bq, const float* __restrict__ bv,
    unsigned short* __restrict__ x16, unsigned short* __restrict__ wk16,
    unsigned short* __restrict__ wq16, unsigned short* __restrict__ wv16,
    unsigned short* __restrict__ wo16, float* __restrict__ b3) {
  const int gid = blockIdx.x * 256 + threadIdx.x;
  const int stride = gridDim.x * 256;
  for (int i = gid; i < 2097152; i += stride) {
    const float4 v = ((const float4*)x)[i];
    ushort4 o = {f2bf_rne(v.x), f2bf_rne(v.y), f2bf_rne(v.z), f2bf_rne(v.w)};
    ((ushort4*)x16)[i] = o;
  }
  for (int i = gid; i < 262144; i += stride) {
    float4 v = ((const float4*)Wk)[i];
    ushort4 o = {f2bf_rne(v.x), f2bf_rne(v.y), f2bf_rne(v.z), f2bf_rne(v.w)};
    ((ushort4*)wk16)[i] = o;
    v = ((const float4*)Wq)[i];
    o = (ushort4){f2bf_rne(v.x), f2bf_rne(v.y), f2bf_rne(v.z), f2bf_rne(v.w)};
    ((ushort4*)wq16)[i] = o;
    v = ((const float4*)Wv)[i];
    o = (ushort4){f2bf_rne(v.x), f2bf_rne(v.y), f2bf_rne(v.z), f2bf_rne(v.w)};
    ((ushort4*)wv16)[i] = o;
    v = ((const float4*)Wout)[i];
    o = (ushort4){f2bf_rne(v.x), f2bf_rne(v.y), f2bf_rne(v.z), f2bf_rne(v.w)};
    ((ushort4*)wo16)[i] = o;
  }
  if (gid < 3072)
    b3[gid] = gid < 1024 ? bk[gid] : gid < 2048 ? bq[gid - 1024] : bv[gid - 2048];
}

// ---------------------------------------------------------------------------
// bf16 MFMA GEMM (NT): C[m][n] = bias[n] + sum_k A[m][k]*Bw[n][k]
// ---------------------------------------------------------------------------
__global__ __launch_bounds__(256) void gemm_bf16_nt(
    const unsigned short* __restrict__ A, const unsigned short* __restrict__ Bw,
    const float* __restrict__ bias, float* __restrict__ C, int M, int N, int K) {
  __shared__ unsigned short Asl[128 * 32];
  __shared__ unsigned short Bsl[128 * 32];
  const int tid = threadIdx.x;
  const int lane = tid & 63, w = tid >> 6;
  const int bm = blockIdx.x * 128, bn = blockIdx.y * 128;
  const int wr = (w >> 1) * 64, wc = (w & 1) * 64;

  const int li0 = tid, li1 = tid + 256;
  const int ar0 = li0 >> 2, ak0 = (li0 & 3) * 8;
  const int ar1 = li1 >> 2, ak1 = (li1 & 3) * 8;
  const unsigned short* gA0 = A + (size_t)(bm + ar0) * K + ak0;
  const unsigned short* gA1 = A + (size_t)(bm + ar1) * K + ak1;
  const unsigned short* gB0 = Bw + (size_t)(bn + ar0) * K + ak0;
  const unsigned short* gB1 = Bw + (size_t)(bn + ar1) * K + ak1;
  unsigned short* lA0 = &Asl[(size_t)(w * 64) * 8];
  unsigned short* lA1 = &Asl[(size_t)(w * 64 + 256) * 8];
  unsigned short* lB0 = &Bsl[(size_t)(w * 64) * 8];
  unsigned short* lB1 = &Bsl[(size_t)(w * 64 + 256) * 8];

  f32x4 acc[4][4];
#pragma unroll
  for (int i = 0; i < 4; ++i)
#pragma unroll
    for (int j = 0; j < 4; ++j) acc[i][j] = (f32x4){0.f, 0.f, 0.f, 0.f};

  const int fr = lane & 15, kg = lane >> 4;

  for (int k0 = 0; k0 < K; k0 += 32) {
    __syncthreads();
    __builtin_amdgcn_global_load_lds((const __attribute__((address_space(1))) unsigned int*)(gA0 + k0),
                                     (__attribute__((address_space(3))) unsigned int*)lA0, 16, 0, 0);
    __builtin_amdgcn_global_load_lds((const __attribute__((address_space(1))) unsigned int*)(gA1 + k0),
                                     (__attribute__((address_space(3))) unsigned int*)lA1, 16, 0, 0);
    __builtin_amdgcn_global_load_lds((const __attribute__((address_space(1))) unsigned int*)(gB0 + k0),
                                     (__attribute__((address_space(3))) unsigned int*)lB0, 16, 0, 0);
    __builtin_amdgcn_global_load_lds((const __attribute__((address_space(1))) unsigned int*)(gB1 + k0),
                                     (__attribute__((address_space(3))) unsigned int*)lB1, 16, 0, 0);
    __syncthreads();

    bf16x8 af[4], bfr[4];
#pragma unroll
    for (int i = 0; i < 4; ++i) {
      af[i] = *(const bf16x8*)&Asl[(size_t)(wr + i * 16 + fr) * 32 + kg * 8];
      bfr[i] = *(const bf16x8*)&Bsl[(size_t)(wc + i * 16 + fr) * 32 + kg * 8];
    }
#pragma unroll
    for (int i = 0; i < 4; ++i)
#pragma unroll
      for (int j = 0; j < 4; ++j)
        acc[i][j] = MFMA(af[i], bfr[j], acc[i][j]);
  }

  const int og = lane >> 4;
#pragma unroll
  for (int j = 0; j < 4; ++j) {
    const int col = bn + wc + j * 16 + fr;
    const float bs = bias[col];
#pragma unroll
    for (int i = 0; i < 4; ++i) {
#pragma unroll
      for (int r = 0; r < 4; ++r) {
        const int row = bm + wr + i * 16 + og * 4 + r;
        C[(size_t)row * N + col] = acc[i][j][r] + bs;
      }
    }
  }
}

// ---------------------------------------------------------------------------
// prep: beta (sigmoid proj) + causal conv + norms + eta*silu, fused.
// ---------------------------------------------------------------------------
__global__ __launch_bounds__(256) void prep_kernel(
    const float* __restrict__ x, const float* __restrict__ qkv,
    const float* __restrict__ Wbeta, const float* __restrict__ bbeta,
    const float* __restrict__ convk, const float* __restrict__ convq,
    const float* __restrict__ convv, float* __restrict__ betab,
    unsigned short* __restrict__ kn16, unsigned short* __restrict__ qn16,
    float* __restrict__ vz) {
  __shared__ float etas_sm[16];
  const int m = blockIdx.x;          // b*2048 + l
  const int l = m & 2047;
  const int lane = threadIdx.x & 63;
  const int wvi = threadIdx.x >> 6;  // 0..3

  {
    const float4* xr = (const float4*)(x + (size_t)m * 1024);
    const float4 xv0 = xr[lane], xv1 = xr[lane + 64];
    const float4 xv2 = xr[lane + 128], xv3 = xr[lane + 192];
#pragma unroll
    for (int hh = 0; hh < 4; ++hh) {
      const int h = wvi * 4 + hh;
      const float4* wr = (const float4*)(Wbeta + (size_t)h * 1024);
      const float4 w0 = wr[lane], w1 = wr[lane + 64];
      const float4 w2 = wr[lane + 128], w3 = wr[lane + 192];
      float acc = xv0.x * w0.x + xv0.y * w0.y + xv0.z * w0.z + xv0.w * w0.w +
                  xv1.x * w1.x + xv1.y * w1.y + xv1.z * w1.z + xv1.w * w1.w +
                  xv2.x * w2.x + xv2.y * w2.y + xv2.z * w2.z + xv2.w * w2.w +
                  xv3.x * w3.x + xv3.y * w3.y + xv3.z * w3.z + xv3.w * w3.w;
      acc += __shfl_xor(acc, 1); acc += __shfl_xor(acc, 2);
      acc += __shfl_xor(acc, 4); acc += __shfl_xor(acc, 8);
      acc += __shfl_xor(acc, 16); acc += __shfl_xor(acc, 32);
      if (lane == 0) {
        const float e = 1.f / (1.f + expf(-(acc + bbeta[h])));
        etas_sm[h] = e;
        betab[(size_t)m * 16 + h] = e;
      }
    }
  }
  __syncthreads();

#pragma unroll
  for (int s = 0; s < 4; ++s) {
    const int h = 4 * s + wvi;
    const int c = h * 64 + lane;
    const float4 wk4 = *(const float4*)(convk + (size_t)c * 4);
    const float4 wq4 = *(const float4*)(convq + (size_t)c * 4);
    const float4 wv4 = *(const float4*)(convv + (size_t)c * 4);
    const float wk[4] = {wk4.x, wk4.y, wk4.z, wk4.w};
    const float wq[4] = {wq4.x, wq4.y, wq4.z, wq4.w};
    const float wvv[4] = {wv4.x, wv4.y, wv4.z, wv4.w};
    float kc = 0.f, qc = 0.f, vc = 0.f;
#pragma unroll
    for (int jj = 0; jj < 4; ++jj) {
      const int lj = l - 3 + jj;
      if (lj >= 0) {
        const size_t rb = (size_t)(m - l + lj) * 3072 + c;
        kc += wk[jj] * qkv[rb];
        qc += wq[jj] * qkv[rb + 1024];
        vc += wvv[jj] * qkv[rb + 2048];
      }
    }
    float ssk = kc * kc, ssq = qc * qc;
    ssk += __shfl_xor(ssk, 1); ssq += __shfl_xor(ssq, 1);
    ssk += __shfl_xor(ssk, 2); ssq += __shfl_xor(ssq, 2);
    ssk += __shfl_xor(ssk, 4); ssq += __shfl_xor(ssq, 4);
    ssk += __shfl_xor(ssk, 8); ssq += __shfl_xor(ssq, 8);
    ssk += __shfl_xor(ssk, 16); ssq += __shfl_xor(ssq, 16);
    ssk += __shfl_xor(ssk, 32); ssq += __shfl_xor(ssq, 32);
    const float eta = etas_sm[h];
    const size_t o = (size_t)m * 1024 + c;
    kn16[o] = f2bf_rne(kc / (sqrtf(ssk) + 1e-6f));
    qn16[o] = f2bf_rne(qc / (sqrtf(ssq) + 1e-6f));
    vz[o] = eta * vc / (1.f + expf(-vc));
  }
}

#define LDB 72  // bf16 row stride (144B: rows 16B-aligned)

// ---------------------------------------------------------------------------
// chunk_kernel: per (b,h,chunk) tile, fully parallel (2048 blocks).
// Computes Y = inv(I+T)V', Gm = -inv(I+T)(etaK), S = Tmat.*(Q K^T).
// Doubling chain + one f32 refinement for Y and G.  Outputs:
//   Yg: f32 per-thread-frag order (tile*4096 + tid*8)
//   Gg, Sg: bf16 row-major 64x64 per tile
// ---------------------------------------------------------------------------
__global__ __launch_bounds__(512, 1) void chunk_kernel(
    const unsigned short* __restrict__ kn16, const unsigned short* __restrict__ qn16,
    const float* __restrict__ vz, const float* __restrict__ betab,
    unsigned short* __restrict__ Gg, unsigned short* __restrict__ Sg,
    float* __restrict__ Yg) {
  __shared__ unsigned short Kb[64 * LDB], Qb[64 * LDB], P1b[64 * LDB];
  __shared__ unsigned short Pb[2][64 * LDB], Ptb[2][64 * LDB];
  __shared__ unsigned short ZYb[2][64 * LDB], ZG0b[64 * LDB];
  unsigned short* const ZG[2] = {ZG0b, Kb};  // ZG[1] aliases Kb (dead after P1)
  unsigned short* const Sb = Qb;             // S written at chain k=0 (Qb dead)

  const int tid = threadIdx.x;
  const int tile = blockIdx.x, bh = tile >> 5, ic = tile & 31;
  const int b = bh >> 4, h = bh & 15;
  const float ts = (float)(ic * 64);
  const int wv = tid >> 6, lane = tid & 63;
  const int fr = lane & 15, og = lane >> 4;
  const int i0 = (wv >> 2) * 2, i1 = i0 + 1, j = wv & 3;
  const int gcol = j * 16 + fr;
  const int row0 = i0 * 16 + og * 4;
  const int row1 = i1 * 16 + og * 4;
  const int sr = tid >> 3, sc8 = (tid & 7) * 8;

  const size_t base = ((size_t)b * 2048) * 1024 + (size_t)h * 64;
  const unsigned short* kp = kn16 + base;
  const unsigned short* qp = qn16 + base;
  const float* vp = vz + base;
  const float* etap = betab + (size_t)b * 2048 * 16 + h;

  // ---- P0: stage K,Q; load V', eta ----
  {
    const size_t g = (size_t)(ic * 64 + sr) * 1024 + sc8;
    *(ushort4*)&Kb[sr * LDB + sc8] = *(const ushort4*)(kp + g);
    *(ushort4*)&Kb[sr * LDB + sc8 + 4] = *(const ushort4*)(kp + g + 4);
    *(ushort4*)&Qb[sr * LDB + sc8] = *(const ushort4*)(qp + g);
    *(ushort4*)&Qb[sr * LDB + sc8 + 4] = *(const ushort4*)(qp + g + 4);
  }
  float vr0[4], vr1[4], er0[4], er1[4];
#pragma unroll
  for (int r = 0; r < 4; ++r) {
    vr0[r] = vp[(size_t)(ic * 64 + row0 + r) * 1024 + gcol];
    vr1[r] = vp[(size_t)(ic * 64 + row1 + r) * 1024 + gcol];
    er0[r] = etap[(size_t)(ic * 64 + row0 + r) * 16];
    er1[r] = etap[(size_t)(ic * 64 + row1 + r) * 16];
  }
  __syncthreads();

  // ---- P1: T, S (regs), P buffers, init Y/G ----
  f32x4 ZaccY[2], ZaccG[2], sSv[2];
  float G0s[2][4];
  {
    bf16x8 aK0[2], aK1[2], aQ0[2], aQ1[2], bK[2];
#pragma unroll
    for (int t = 0; t < 2; ++t) {
      aK0[t] = *(const bf16x8*)&Kb[(i0 * 16 + fr) * LDB + t * 32 + og * 8];
      aK1[t] = *(const bf16x8*)&Kb[(i1 * 16 + fr) * LDB + t * 32 + og * 8];
      aQ0[t] = *(const bf16x8*)&Qb[(i0 * 16 + fr) * LDB + t * 32 + og * 8];
      aQ1[t] = *(const bf16x8*)&Qb[(i1 * 16 + fr) * LDB + t * 32 + og * 8];
      bK[t] = *(const bf16x8*)&Kb[(j * 16 + fr) * LDB + t * 32 + og * 8];
    }
    f32x4 accT0 = {0, 0, 0, 0}, accT1 = {0, 0, 0, 0};
    f32x4 accS0 = {0, 0, 0, 0}, accS1 = {0, 0, 0, 0};
#pragma unroll
    for (int t = 0; t < 2; ++t) {
      accT0 = MFMA(aK0[t], bK[t], accT0);
      accT1 = MFMA(aK1[t], bK[t], accT1);
      accS0 = MFMA(aQ0[t], bK[t], accS0);
      accS1 = MFMA(aQ1[t], bK[t], accS1);
    }
    const float tri0 = 0.5f * ts * (ts + 1.f);
    const float jidx = gcol * ts + 0.5f * gcol * (gcol + 1.f);
#pragma unroll
    for (int s = 0; s < 2; ++s) {
      const int rb = s ? row1 : row0;
      const f32x4 aT = s ? accT1 : accT0;
      const f32x4 aS = s ? accS1 : accS0;
      unsigned short us[4];
      f32x4 sv;
#pragma unroll
      for (int r = 0; r < 4; ++r) {
        const int grow = rb + r;
        const float eta = s ? er1[r] : er0[r];
        const float tvv = (gcol < grow) ? -eta * aT[r] : 0.f;
        us[r] = f2bf_rne(tvv);
        Pb[0][grow * LDB + gcol] = us[r];
        P1b[grow * LDB + gcol] = us[r];
        const float csr = (grow + 1.f) * ts + 0.5f * (grow + 1.f) * (grow + 2.f);
        const float rinv = 1.f / (tri0 + csr);
        sv[r] = (csr >= jidx) ? (csr - jidx) * rinv * aS[r] : 0.f;
        const float kv = bf2f(Kb[grow * LDB + gcol]);
        G0s[s][r] = eta * kv;
      }
      sSv[s] = sv;
      ushort4 pp = {us[0], us[1], us[2], us[3]};
      *(ushort4*)&Ptb[0][gcol * LDB + rb] = pp;
      const float* vr = s ? vr1 : vr0;
      ZaccY[s] = (f32x4){vr[0], vr[1], vr[2], vr[3]};
      ushort4 yp = {f2bf_rne(vr[0]), f2bf_rne(vr[1]), f2bf_rne(vr[2]), f2bf_rne(vr[3])};
      *(ushort4*)&ZYb[0][gcol * LDB + rb] = yp;
      ZaccG[s] = (f32x4){G0s[s][0], G0s[s][1], G0s[s][2], G0s[s][3]};
      ushort4 gp = {f2bf_rne(G0s[s][0]), f2bf_rne(G0s[s][1]),
                    f2bf_rne(G0s[s][2]), f2bf_rne(G0s[s][3])};
      *(ushort4*)&ZG[0][gcol * LDB + rb] = gp;
    }
  }
  __syncthreads();

  // ---- chain k=0..5 (ping-pong, 1 barrier/step); k==0 also writes S ----
#pragma unroll
  for (int k = 0; k < 6; ++k) {
    const int pc = k & 1, pn = pc ^ 1;
    bf16x8 aP0[2], aP1v[2], bZy[2], bZg[2];
#pragma unroll
    for (int t = 0; t < 2; ++t) {
      aP0[t] = *(const bf16x8*)&Pb[pc][(i0 * 16 + fr) * LDB + t * 32 + og * 8];
      aP1v[t] = *(const bf16x8*)&Pb[pc][(i1 * 16 + fr) * LDB + t * 32 + og * 8];
      bZy[t] = *(const bf16x8*)&ZYb[pc][(j * 16 + fr) * LDB + t * 32 + og * 8];
      bZg[t] = *(const bf16x8*)&ZG[pc][(j * 16 + fr) * LDB + t * 32 + og * 8];
    }
    f32x4 sq0 = {0, 0, 0, 0}, sq1 = {0, 0, 0, 0};
    if (k < 5) {
#pragma unroll
      for (int t = 0; t < 2; ++t) {
        bf16x8 bPt = *(const bf16x8*)&Ptb[pc][(j * 16 + fr) * LDB + t * 32 + og * 8];
        sq0 = MFMA(aP0[t], bPt, sq0);
        sq1 = MFMA(aP1v[t], bPt, sq1);
      }
    }
#pragma unroll
    for (int t = 0; t < 2; ++t) {
      ZaccY[0] = MFMA(aP0[t], bZy[t], ZaccY[0]);
      ZaccY[1] = MFMA(aP1v[t], bZy[t], ZaccY[1]);
      ZaccG[0] = MFMA(aP0[t], bZg[t], ZaccG[0]);
      ZaccG[1] = MFMA(aP1v[t], bZg[t], ZaccG[1]);
    }
#pragma unroll
    for (int s = 0; s < 2; ++s) {
      const int rb = s ? row1 : row0;
      if (k == 0) {
#pragma unroll
        for (int r = 0; r < 4; ++r) Sb[(rb + r) * LDB + gcol] = f2bf_rne(sSv[s][r]);
      }
      const f32x4 zy = ZaccY[s];
      ushort4 yp = {f2bf_rne(zy[0]), f2bf_rne(zy[1]), f2bf_rne(zy[2]), f2bf_rne(zy[3])};
      *(ushort4*)&ZYb[pn][gcol * LDB + rb] = yp;
      const f32x4 zg = ZaccG[s];
      ushort4 gp = {f2bf_rne(zg[0]), f2bf_rne(zg[1]), f2bf_rne(zg[2]), f2bf_rne(zg[3])};
      *(ushort4*)&ZG[pn][gcol * LDB + rb] = gp;
      if (k < 5) {
        const f32x4 sv = s ? sq1 : sq0;
        unsigned short u0 = f2bf_rne(sv[0]), u1 = f2bf_rne(sv[1]);
        unsigned short u2 = f2bf_rne(sv[2]), u3 = f2bf_rne(sv[3]);
        Pb[pn][(rb + 0) * LDB + gcol] = u0;
        Pb[pn][(rb + 1) * LDB + gcol] = u1;
        Pb[pn][(rb + 2) * LDB + gcol] = u2;
        Pb[pn][(rb + 3) * LDB + gcol] = u3;
        ushort4 pp = {u0, u1, u2, u3};
        *(ushort4*)&Ptb[pn][gcol * LDB + rb] = pp;
      }
    }
    __syncthreads();
  }
  // final bf16 in ZYb[0]/ZG[0]; f32 in ZaccY/ZaccG

  // ---- P8: residuals RY = V' - (I+T)Y ; RG = G0 - (I+T)G ----
  bf16x8 a10[2], a11[2];
  f32x4 RY[2], RG[2];
  {
#pragma unroll
    for (int t = 0; t < 2; ++t) {
      a10[t] = *(const bf16x8*)&P1b[(i0 * 16 + fr) * LDB + t * 32 + og * 8];
      a11[t] = *(const bf16x8*)&P1b[(i1 * 16 + fr) * LDB + t * 32 + og * 8];
    }
    RY[0] = (f32x4){vr0[0], vr0[1], vr0[2], vr0[3]} - ZaccY[0];
    RY[1] = (f32x4){vr1[0], vr1[1], vr1[2], vr1[3]} - ZaccY[1];
    RG[0] = (f32x4){G0s[0][0], G0s[0][1], G0s[0][2], G0s[0][3]} - ZaccG[0];
    RG[1] = (f32x4){G0s[1][0], G0s[1][1], G0s[1][2], G0s[1][3]} - ZaccG[1];
#pragma unroll
    for (int t = 0; t < 2; ++t) {
      bf16x8 bY = *(const bf16x8*)&ZYb[0][(j * 16 + fr) * LDB + t * 32 + og * 8];
      bf16x8 bG = *(const bf16x8*)&ZG[0][(j * 16 + fr) * LDB + t * 32 + og * 8];
      RY[0] = MFMA(a10[t], bY, RY[0]);
      RY[1] = MFMA(a11[t], bY, RY[1]);
      RG[0] = MFMA(a10[t], bG, RG[0]);
      RG[1] = MFMA(a11[t], bG, RG[1]);
    }
#pragma unroll
    for (int s = 0; s < 2; ++s) {
      const int rb = s ? row1 : row0;
      ushort4 ryp = {f2bf_rne(RY[s][0]), f2bf_rne(RY[s][1]), f2bf_rne(RY[s][2]), f2bf_rne(RY[s][3])};
      *(ushort4*)&ZYb[1][gcol * LDB + rb] = ryp;
      ushort4 rgp = {f2bf_rne(RG[s][0]), f2bf_rne(RG[s][1]), f2bf_rne(RG[s][2]), f2bf_rne(RG[s][3])};
      *(ushort4*)&ZG[1][gcol * LDB + rb] = rgp;
    }
  }
  __syncthreads();

  // ---- P9: Y += R + P1 R ; G += ... ; writeout Y (f32), -G -> Pb[0] ----
  {
    f32x4 dY0 = RY[0], dY1 = RY[1], dG0 = RG[0], dG1 = RG[1];
#pragma unroll
    for (int t = 0; t < 2; ++t) {
      bf16x8 bRY = *(const bf16x8*)&ZYb[1][(j * 16 + fr) * LDB + t * 32 + og * 8];
      bf16x8 bRG = *(const bf16x8*)&ZG[1][(j * 16 + fr) * LDB + t * 32 + og * 8];
      dY0 = MFMA(a10[t], bRY, dY0);
      dY1 = MFMA(a11[t], bRY, dY1);
      dG0 = MFMA(a10[t], bRG, dG0);
      dG1 = MFMA(a11[t], bRG, dG1);
    }
    ZaccY[0] += dY0; ZaccY[1] += dY1;
    ZaccG[0] += dG0; ZaccG[1] += dG1;
    float4* yo = (float4*)(Yg + (size_t)tile * 4096 + (size_t)tid * 8);
    yo[0] = (float4){ZaccY[0][0], ZaccY[0][1], ZaccY[0][2], ZaccY[0][3]};
    yo[1] = (float4){ZaccY[1][0], ZaccY[1][1], ZaccY[1][2], ZaccY[1][3]};
#pragma unroll
    for (int s = 0; s < 2; ++s) {
      const int rb = s ? row1 : row0;
#pragma unroll
      for (int r = 0; r < 4; ++r)
        Pb[0][(rb + r) * LDB + gcol] = f2bf_rne(-ZaccG[s][r]);
    }
  }
  __syncthreads();

  // ---- P10: coalesced copyout S, -G ----
  {
    unsigned short* So = Sg + (size_t)tile * 4096 + sr * 64 + sc8;
    unsigned short* Go = Gg + (size_t)tile * 4096 + sr * 64 + sc8;
    *(ushort4*)So = *(const ushort4*)&Sb[sr * LDB + sc8];
    *(ushort4*)(So + 4) = *(const ushort4*)&Sb[sr * LDB + sc8 + 4];
    *(ushort4*)Go = *(const ushort4*)&Pb[0][sr * LDB + sc8];
    *(ushort4*)(Go + 4) = *(const ushort4*)&Pb[0][sr * LDB + sc8 + 4];
  }
}

// ---------------------------------------------------------------------------
// scan2: light serial pass, 2 barriers/chunk.
//   B: U = Y + (-G)W ; QW, QWavg ; write U^T, Utw^T
//   F: O += S U, store ; W/Wavg rank-64 updates
// ---------------------------------------------------------------------------
__global__ __launch_bounds__(512, 1) void scan2_kernel(
    const unsigned short* __restrict__ kn16, const unsigned short* __restrict__ qn16,
    const unsigned short* __restrict__ Gg, const unsigned short* __restrict__ Sg,
    const float* __restrict__ Yg, float* __restrict__ O) {
  __shared__ unsigned short Wtb[64 * LDB], Wavgtb[64 * LDB];
  __shared__ unsigned short Ztb[64 * LDB], Utwb[64 * LDB], Ktb[64 * LDB];

  const int tid = threadIdx.x;
  const int bh = blockIdx.x;
  const int b = bh >> 4, h = bh & 15;
  const int wv = tid >> 6, lane = tid & 63;
  const int fr = lane & 15, og = lane >> 4;
  const int i0 = (wv >> 2) * 2, i1 = i0 + 1, j = wv & 3;
  const int gcol = j * 16 + fr;
  const int row0 = i0 * 16 + og * 4;
  const int row1 = i1 * 16 + og * 4;
  const int sr = tid >> 3, sc8 = (tid & 7) * 8;

  for (int t = tid; t < 64 * LDB; t += 512) { Wtb[t] = 0; Wavgtb[t] = 0; }

  const size_t base = ((size_t)b * 2048) * 1024 + (size_t)h * 64;
  const unsigned short* kp = kn16 + base;
  const unsigned short* qp = qn16 + base;
  float* Op = O + (size_t)bh * 2048 * 64;

  f32x4 Wt[2], Wav[2];
  Wt[0] = Wt[1] = Wav[0] = Wav[1] = (f32x4){0.f, 0.f, 0.f, 0.f};

  // prologue: stage K^T chunk 0
  {
    ushort4 t0v, t1v;
    t0v.x = kp[(size_t)(sc8 + 0) * 1024 + sr];
    t0v.y = kp[(size_t)(sc8 + 1) * 1024 + sr];
    t0v.z = kp[(size_t)(sc8 + 2) * 1024 + sr];
    t0v.w = kp[(size_t)(sc8 + 3) * 1024 + sr];
    t1v.x = kp[(size_t)(sc8 + 4) * 1024 + sr];
    t1v.y = kp[(size_t)(sc8 + 5) * 1024 + sr];
    t1v.z = kp[(size_t)(sc8 + 6) * 1024 + sr];
    t1v.w = kp[(size_t)(sc8 + 7) * 1024 + sr];
    *(ushort4*)&Ktb[sr * LDB + sc8] = t0v;
    *(ushort4*)&Ktb[sr * LDB + sc8 + 4] = t1v;
  }
  ushort4 pt0, pt1;
  __syncthreads();

#pragma unroll 1
  for (int ic = 0; ic < 32; ++ic) {
    const float ts = (float)(ic * 64);
    const int icn = (ic < 31) ? ic + 1 : ic;
    const size_t tile = (size_t)bh * 32 + ic;
    f32x4 Oacc[2];
    bf16x8 aS[2][2];

    // ---- B ---- (barrier 1)
    {
      if (ic > 0) {
        *(ushort4*)&Ktb[sr * LDB + sc8] = pt0;
        *(ushort4*)&Ktb[sr * LDB + sc8 + 4] = pt1;
      }
      {
        const size_t cb = (size_t)(icn * 64 + sc8);
        pt0.x = kp[(cb + 0) * 1024 + sr]; pt0.y = kp[(cb + 1) * 1024 + sr];
        pt0.z = kp[(cb + 2) * 1024 + sr]; pt0.w = kp[(cb + 3) * 1024 + sr];
        pt1.x = kp[(cb + 4) * 1024 + sr]; pt1.y = kp[(cb + 5) * 1024 + sr];
        pt1.z = kp[(cb + 6) * 1024 + sr]; pt1.w = kp[(cb + 7) * 1024 + sr];
      }
      const unsigned short* Gt = Gg + tile * 4096;
      const unsigned short* St = Sg + tile * 4096;
      bf16x8 aG[2][2], aQ[2][2];
#pragma unroll
      for (int t = 0; t < 2; ++t) {
        aG[0][t] = *(const bf16x8*)(Gt + (i0 * 16 + fr) * 64 + t * 32 + og * 8);
        aG[1][t] = *(const bf16x8*)(Gt + (i1 * 16 + fr) * 64 + t * 32 + og * 8);
        aS[0][t] = *(const bf16x8*)(St + (i0 * 16 + fr) * 64 + t * 32 + og * 8);
        aS[1][t] = *(const bf16x8*)(St + (i1 * 16 + fr) * 64 + t * 32 + og * 8);
        aQ[0][t] = *(const bf16x8*)(qp + (size_t)(ic * 64 + i0 * 16 + fr) * 1024 + t * 32 + og * 8);
        aQ[1][t] = *(const bf16x8*)(qp + (size_t)(ic * 64 + i1 * 16 + fr) * 1024 + t * 32 + og * 8);
      }
      const float4* yp = (const float4*)(Yg + tile * 4096 + (size_t)tid * 8);
      const float4 ya = yp[0], yb = yp[1];
      f32x4 U0 = {ya.x, ya.y, ya.z, ya.w};
      f32x4 U1 = {yb.x, yb.y, yb.z, yb.w};
      f32x4 aA0 = {0, 0, 0, 0}, aA1 = {0, 0, 0, 0};
      f32x4 aC0 = {0, 0, 0, 0}, aC1 = {0, 0, 0, 0};
      bf16x8 bW[2], bWa[2];
#pragma unroll
      for (int t = 0; t < 2; ++t) {
        bW[t] = *(const bf16x8*)&Wtb[(j * 16 + fr) * LDB + t * 32 + og * 8];
        bWa[t] = *(const bf16x8*)&Wavgtb[(j * 16 + fr) * LDB + t * 32 + og * 8];
      }
#pragma unroll
      for (int t = 0; t < 2; ++t) {
        U0 = MFMA(aG[0][t], bW[t], U0);   // G stored negated -> subtracts
        U1 = MFMA(aG[1][t], bW[t], U1);
        aA0 = MFMA(aQ[0][t], bWa[t], aA0);
        aA1 = MFMA(aQ[1][t], bWa[t], aA1);
        aC0 = MFMA(aQ[0][t], bW[t], aC0);
        aC1 = MFMA(aQ[1][t], bW[t], aC1);
      }
      const float tri0 = 0.5f * ts * (ts + 1.f);
      const float invden = 1.f / (0.5f * (ts + 65.f) * (ts + 64.f));
#pragma unroll
      for (int s = 0; s < 2; ++s) {
        const int rb = s ? row1 : row0;
        const f32x4 sA = s ? aA1 : aA0;
        const f32x4 sC = s ? aC1 : aC0;
        const f32x4 uu = s ? U1 : U0;
        f32x4 oo;
        unsigned short uw[4];
#pragma unroll
        for (int r = 0; r < 4; ++r) {
          const float grow = (float)(rb + r);
          const float csr = (grow + 1.f) * ts + 0.5f * (grow + 1.f) * (grow + 2.f);
          const float rinv = 1.f / (tri0 + csr);
          const float av = tri0 * rinv;
          oo[r] = av * sA[r] + (1.f - av) * sC[r];
          const float wr = (ts * (64.f - grow) + (grow + 1.f) + 2080.f -
                            0.5f * (grow + 1.f) * (grow + 2.f)) * invden;
          uw[r] = f2bf_rne(uu[r] * wr);
        }
        Oacc[s] = oo;
        ushort4 up = {f2bf_rne(uu[0]), f2bf_rne(uu[1]), f2bf_rne(uu[2]), f2bf_rne(uu[3])};
        *(ushort4*)&Ztb[gcol * LDB + rb] = up;
        ushort4 uwp = {uw[0], uw[1], uw[2], uw[3]};
        *(ushort4*)&Utwb[gcol * LDB + rb] = uwp;
      }
    }
    __syncthreads();

    // ---- F ---- (barrier 2)
    {
      bf16x8 bU[2];
#pragma unroll
      for (int t = 0; t < 2; ++t)
        bU[t] = *(const bf16x8*)&Ztb[(j * 16 + fr) * LDB + t * 32 + og * 8];
#pragma unroll
      for (int t = 0; t < 2; ++t) {
        Oacc[0] = MFMA(aS[0][t], bU[t], Oacc[0]);
        Oacc[1] = MFMA(aS[1][t], bU[t], Oacc[1]);
      }
#pragma unroll
      for (int s = 0; s < 2; ++s) {
        const int rb = s ? row1 : row0;
#pragma unroll
        for (int r = 0; r < 4; ++r)
          Op[(size_t)(ic * 64 + rb + r) * 64 + gcol] = Oacc[s][r];
      }
      bf16x8 aU0[2], aU1[2], aW0[2], aW1[2], bKt[2];
#pragma unroll
      for (int t = 0; t < 2; ++t) {
        aU0[t] = *(const bf16x8*)&Ztb[(i0 * 16 + fr) * LDB + t * 32 + og * 8];
        aU1[t] = *(const bf16x8*)&Ztb[(i1 * 16 + fr) * LDB + t * 32 + og * 8];
        aW0[t] = *(const bf16x8*)&Utwb[(i0 * 16 + fr) * LDB + t * 32 + og * 8];
        aW1[t] = *(const bf16x8*)&Utwb[(i1 * 16 + fr) * LDB + t * 32 + og * 8];
        bKt[t] = *(const bf16x8*)&Ktb[(j * 16 + fr) * LDB + t * 32 + og * 8];
      }
      const float den = (ts + 64.f) * (ts + 65.f);
      const float cc1 = ts * (ts + 1.f) / den;
      const float cc2 = 64.f * (2.f * ts + 65.f) / den;
      f32x4 wn0 = cc1 * Wav[0] + cc2 * Wt[0];
      f32x4 wn1 = cc1 * Wav[1] + cc2 * Wt[1];
#pragma unroll
      for (int t = 0; t < 2; ++t) {
        wn0 = MFMA(aW0[t], bKt[t], wn0);
        wn1 = MFMA(aW1[t], bKt[t], wn1);
        Wt[0] = MFMA(aU0[t], bKt[t], Wt[0]);
        Wt[1] = MFMA(aU1[t], bKt[t], Wt[1]);
      }
      Wav[0] = wn0;
      Wav[1] = wn1;
#pragma unroll
      for (int s = 0; s < 2; ++s) {
        const int rb = s ? row1 : row0;
        const f32x4 wtv = Wt[s];
        const f32x4 wav2 = Wav[s];
#pragma unroll
        for (int r = 0; r < 4; ++r) {
          Wtb[(rb + r) * LDB + gcol] = f2bf_rne(wtv[r]);
          Wavgtb[(rb + r) * LDB + gcol] = f2bf_rne(wav2[r]);
        }
      }
    }
    __syncthreads();
  }
}

// ---------------------------------------------------------------------------
// RMS norm over head dim + relayout (B,H,L,D) -> (B,L,Dm), bf16 output
// ---------------------------------------------------------------------------
__global__ __launch_bounds__(256) void rms_kernel(const float* __restrict__ O,
                                                  const float* __restrict__ rmsw,
                                                  unsigned short* __restrict__ out16) {
  const int m = blockIdx.x;  // b*2048 + l
  const int b = m >> 11, l = m & 2047;
  const int wv = threadIdx.x >> 6, lane = threadIdx.x & 63;
  const float rw = rmsw[lane];
#pragma unroll
  for (int hh = 0; hh < 4; ++hh) {
    const int h = wv * 4 + hh;
    const float v = O[(((size_t)(b * 16 + h)) * 2048 + l) * 64 + lane];
    float ss = v * v;
    ss += __shfl_xor(ss, 1); ss += __shfl_xor(ss, 2); ss += __shfl_xor(ss, 4);
    ss += __shfl_xor(ss, 8); ss += __shfl_xor(ss, 16); ss += __shfl_xor(ss, 32);
    const float sc = rsqrtf(ss * (1.f / 64.f) + 1e-6f);
    out16[(size_t)m * 1024 + h * 64 + lane] = f2bf_rne(v * sc * rw);
  }
}

// ---------------------------------------------------------------------------
extern "C" void kernel_launch(void* const* d_in, const int* in_sizes, int n_in,
                              void* d_out, int out_size, void* d_ws, size_t ws_size,
                              hipStream_t stream) {
  (void)in_sizes; (void)n_in; (void)out_size; (void)ws_size;
  const float* x     = (const float*)d_in[0];
  const float* Wk    = (const float*)d_in[1];
  const float* bk    = (const float*)d_in[2];
  const float* Wq    = (const float*)d_in[3];
  const float* bq    = (const float*)d_in[4];
  const float* Wv    = (const float*)d_in[5];
  const float* bv    = (const float*)d_in[6];
  const float* Wbeta = (const float*)d_in[7];
  const float* bbeta = (const float*)d_in[8];
  const float* convk = (const float*)d_in[9];
  const float* convq = (const float*)d_in[10];
  const float* convv = (const float*)d_in[11];
  const float* rmsw  = (const float*)d_in[12];
  const float* Wout  = (const float*)d_in[13];
  const float* bout  = (const float*)d_in[14];
  float* out = (float*)d_out;
  float* ws = (float*)d_ws;

  const size_t SZ = (size_t)8192 * 1024;
  // region [0,3SZ): qkv during prep; after: Obuf [0,SZ), Yg [SZ,2SZ),
  //                 Gg bf16 [2SZ,2.5SZ), Sg bf16 [2.5SZ,3SZ)
  float* qkv = ws;
  float* Obuf = ws;
  float* Yg = ws + SZ;
  unsigned short* Gg = (unsigned short*)(ws + 2 * SZ);
  unsigned short* Sg = Gg + SZ;
  float* betab = ws + 3 * SZ;                                      // 131072 f32
  unsigned short* x16 = (unsigned short*)(ws + 3 * SZ + 131072);   // SZ bf16
  unsigned short* wk16 = x16 + SZ;   // wk|wq|wv contiguous = 3072x1024 bf16
  unsigned short* wq16 = wk16 + 1048576;
  unsigned short* wv16 = wq16 + 1048576;
  unsigned short* wo16 = wv16 + 1048576;
  unsigned short* kn16 = wo16 + 1048576;                           // SZ bf16
  unsigned short* qn16 = kn16 + SZ;                                // SZ bf16
  float* b3 = (float*)(qn16 + SZ);                                 // 3072 f32
  float* vzb = out;                  // d_out doubles as eta*silu(v) scratch
  unsigned short* normed16 = x16;    // x16 dead after QKV GEMM

  dim3 blk(256);
  hipLaunchKernelGGL(prepare_kernel, dim3(2048), blk, 0, stream, x, Wk, Wq, Wv, Wout,
                     bk, bq, bv, x16, wk16, wq16, wv16, wo16, b3);
  hipLaunchKernelGGL(gemm_bf16_nt, dim3(64, 24), blk, 0, stream, x16, wk16, b3,
                     qkv, 8192, 3072, 1024);
  hipLaunchKernelGGL(prep_kernel, dim3(8192), blk, 0, stream, x, qkv, Wbeta, bbeta,
                     convk, convq, convv, betab, kn16, qn16, vzb);
  hipLaunchKernelGGL(chunk_kernel, dim3(2048), dim3(512), 0, stream, kn16, qn16, vzb,
                     betab, Gg, Sg, Yg);
  hipLaunchKernelGGL(scan2_kernel, dim3(64), dim3(512), 0, stream, kn16, qn16,
                     Gg, Sg, Yg, Obuf);
  hipLaunchKernelGGL(rms_kernel, dim3(8192), blk, 0, stream, Obuf, rmsw, normed16);
  hipLaunchKernelGGL(gemm_bf16_nt, dim3(64, 8), blk, 0, stream, normed16, wo16, bout, out,
                     8192, 1024, 1024);
}